// Round 7
// baseline (627.463 us; speedup 1.0000x reference)
//
#include <hip/hip_runtime.h>
#include <hip/hip_bf16.h>
#include <cstdint>
#include <cstddef>

typedef __hip_bfloat16 bf16;
typedef __attribute__((ext_vector_type(8))) short short8;   // 8 bf16 (MFMA A/B frag)
typedef __attribute__((ext_vector_type(4))) float f32x4;    // MFMA C/D frag

#define NSF 128
#define BN_EPS 1e-3f
#define NR 4            // src ranges per node for L2 locality

// ---------------- graph-norm prep ----------------

// zero deg[n], cnt[n*NR], fill[n*NR]
__global__ void zero_kernel(float* __restrict__ deg, int* __restrict__ cnt,
                            int* __restrict__ fill, int n) {
    int i = blockIdx.x * blockDim.x + threadIdx.x;
    if (i < n) deg[i] = 0.0f;
    if (i < n * NR) { cnt[i] = 0; fill[i] = 0; }
}

// deg[col] += w ; cnt[col*NR + range(src)] += 1  for E edges + N self loops
__global__ void count_kernel(const int* __restrict__ ei, const float* __restrict__ ea,
                             float* __restrict__ deg, int* __restrict__ cnt,
                             int E, int n, int rsize) {
    int idx = blockIdx.x * blockDim.x + threadIdx.x;
    if (idx < E) {
        int r = ei[idx];
        int c = ei[E + idx];
        atomicAdd(&deg[c], ea[idx]);
        atomicAdd(&cnt[c * NR + r / rsize], 1);
    } else if (idx < E + n) {
        int i = idx - E;
        atomicAdd(&deg[i], 1.0f);
        atomicAdd(&cnt[i * NR + i / rsize], 1);
    }
}

__global__ void dinv_kernel(const float* __restrict__ deg, float* __restrict__ dinv, int n) {
    int i = blockIdx.x * blockDim.x + threadIdx.x;
    if (i < n) {
        float d = deg[i];
        dinv[i] = (d > 0.0f) ? rsqrtf(d) : 0.0f;
    }
}

// single-block exclusive scan of cnt[0..total) -> row_ptr[0..total]
__global__ void scan_kernel(const int* __restrict__ cnt, int* __restrict__ row_ptr, int total) {
    __shared__ int part[256];
    int tid = threadIdx.x;
    int chunk = (total + 255) / 256;
    int start = tid * chunk;
    int end = min(start + chunk, total);
    int s = 0;
    for (int i = start; i < end; ++i) s += cnt[i];
    part[tid] = s;
    __syncthreads();
    for (int off = 1; off < 256; off <<= 1) {
        int v = (tid >= off) ? part[tid - off] : 0;
        __syncthreads();
        part[tid] += v;
        __syncthreads();
    }
    int run = (tid == 0) ? 0 : part[tid - 1];
    for (int i = start; i < end; ++i) { row_ptr[i] = run; run += cnt[i]; }
    if (tid == 255) row_ptr[total] = part[255];
}

// scatter edges into range-segmented CSR slots; csr_w = dinv[row]*w*dinv[col]
__global__ void fill_kernel(const int* __restrict__ ei, const float* __restrict__ ea,
                            const float* __restrict__ dinv,
                            const int* __restrict__ row_ptr, int* __restrict__ fill,
                            int* __restrict__ csr_src, float* __restrict__ csr_w,
                            int E, int n, int rsize) {
    int idx = blockIdx.x * blockDim.x + threadIdx.x;
    if (idx < E) {
        int r = ei[idx];
        int c = ei[E + idx];
        int slot = c * NR + r / rsize;
        int p = row_ptr[slot] + atomicAdd(&fill[slot], 1);
        csr_src[p] = r;
        csr_w[p] = dinv[r] * ea[idx] * dinv[c];
    } else if (idx < E + n) {
        int i = idx - E;
        int slot = i * NR + i / rsize;
        int p = row_ptr[slot] + atomicAdd(&fill[slot], 1);
        csr_src[p] = i;
        csr_w[p] = dinv[i] * dinv[i];
    }
}

// ---------------- dtype prep ----------------

__global__ void cvt_kernel(const float* __restrict__ x, bf16* __restrict__ y, int count) {
    int i = blockIdx.x * blockDim.x + threadIdx.x;
    if (i < count) y[i] = __float2bfloat16(x[i]);
}

// Wt[n*K + k] = bf16(W[k*N + n])
__global__ void wt_kernel(const float* __restrict__ W, bf16* __restrict__ Wt, int K, int N) {
    int idx = blockIdx.x * blockDim.x + threadIdx.x;
    if (idx < K * N) {
        int nn = idx / K, kk = idx % K;
        Wt[idx] = __float2bfloat16(W[(size_t)kk * N + nn]);
    }
}

// ---------------- MFMA GEMM: C[M,N] = A[M,K] @ Wt[N,K]^T, fused epilogue ----------------
// mode 0: raw store; mode 1: sigmoid(BN(acc+bias))
#define GPAD 8

__global__ __launch_bounds__(256) void mfma_gemm_kernel(
    const bf16* __restrict__ A, const bf16* __restrict__ Wt,
    bf16* __restrict__ C, int M, int K, int N, int mode,
    const float* __restrict__ bias, const float* __restrict__ g,
    const float* __restrict__ be, const float* __restrict__ m,
    const float* __restrict__ v) {
    __shared__ bf16 As[64][32 + GPAD];
    __shared__ bf16 Bs[128][32 + GPAD];
    int m0 = blockIdx.x * 64;
    int n0 = blockIdx.y * 128;
    int tid = threadIdx.x;
    int wave = tid >> 6, lane = tid & 63;
    int lrow = lane & 15, quad = lane >> 4;

    f32x4 acc[8] = {};

    int r = tid >> 2;      // 0..63
    int seg = tid & 3;     // 0..3

    for (int k0 = 0; k0 < K; k0 += 32) {
        uint4 av; av.x = av.y = av.z = av.w = 0u;
        int gm = m0 + r;
        if (gm < M) av = *(const uint4*)(A + (size_t)gm * K + k0 + seg * 8);
        *(uint4*)(&As[r][seg * 8]) = av;
        *(uint4*)(&Bs[r][seg * 8]) =
            *(const uint4*)(Wt + (size_t)(n0 + r) * K + k0 + seg * 8);
        *(uint4*)(&Bs[r + 64][seg * 8]) =
            *(const uint4*)(Wt + (size_t)(n0 + r + 64) * K + k0 + seg * 8);
        __syncthreads();

        short8 afrag = *(const short8*)(&As[wave * 16 + lrow][quad * 8]);
        #pragma unroll
        for (int t = 0; t < 8; ++t) {
            short8 bfrag = *(const short8*)(&Bs[t * 16 + lrow][quad * 8]);
            acc[t] = __builtin_amdgcn_mfma_f32_16x16x32_bf16(afrag, bfrag, acc[t], 0, 0, 0);
        }
        __syncthreads();
    }
    // C/D: col = lane&15, row = quad*4 + reg
    #pragma unroll
    for (int t = 0; t < 8; ++t) {
        int gn = n0 + t * 16 + lrow;
        float bsc = 0.0f, scale = 1.0f, mean = 0.0f, beta = 0.0f;
        if (mode == 1) {
            bsc = bias[gn];
            scale = g[gn] * rsqrtf(v[gn] + BN_EPS);
            mean = m[gn];
            beta = be[gn];
        }
        #pragma unroll
        for (int rr = 0; rr < 4; ++rr) {
            int gm = m0 + wave * 16 + quad * 4 + rr;
            if (gm < M) {
                float a = acc[t][rr];
                if (mode == 1) {
                    a = (a + bsc - mean) * scale + beta;
                    a = 1.0f / (1.0f + __expf(-a));
                }
                C[(size_t)gm * N + gn] = __float2bfloat16(a);
            }
        }
    }
}

// ---------------- vectorized aggregation (round-5 proven shape) ----------------

__device__ inline float bfu(unsigned int u16) {
    union { unsigned int u; float f; } c; c.u = u16 << 16; return c.f;
}
__device__ inline void fma_unpack(unsigned int q, float w, float* acc) {
    acc[0] += w * bfu(q & 0xffffu);
    acc[1] += w * bfu(q >> 16);
}
__device__ inline void fma_unpack(uint2 q, float w, float* acc) {
    fma_unpack(q.x, w, acc); fma_unpack(q.y, w, acc + 2);
}
__device__ inline void fma_unpack(uint4 q, float w, float* acc) {
    fma_unpack(q.x, w, acc);     fma_unpack(q.y, w, acc + 2);
    fma_unpack(q.z, w, acc + 4); fma_unpack(q.w, w, acc + 6);
}

template <int VEC> struct UVec;
template <> struct UVec<2> { typedef unsigned int T; };
template <> struct UVec<4> { typedef uint2 T; };
template <> struct UVec<8> { typedef uint4 T; };

// wave per node; lane owns VEC consecutive features (dfeat = 64*VEC)
// mode 0: plain weighted sum (agg-first); 1: bias+BN+sigmoid; 2: bias+sigmoid
// row_ptr is range-segmented: node's edges span [row_ptr[node*NR], row_ptr[(node+1)*NR])
template <int VEC>
__global__ __launch_bounds__(256) void agg_vec_kernel(
    const bf16* __restrict__ hw,
    const int* __restrict__ row_ptr,
    const int* __restrict__ csr_src, const float* __restrict__ csr_w,
    const float* __restrict__ bias,
    const float* __restrict__ g, const float* __restrict__ be,
    const float* __restrict__ m, const float* __restrict__ v,
    bf16* __restrict__ out, int n, int mode) {
    typedef typename UVec<VEC>::T T;
    const int dfeat = VEC * 64;
    int wave = threadIdx.x >> 6;
    int lane = threadIdx.x & 63;
    int node = blockIdx.x * 4 + wave;
    if (node >= n) return;
    int s = row_ptr[node * NR], e = row_ptr[(node + 1) * NR];
    float acc[VEC];
    #pragma unroll
    for (int i = 0; i < VEC; ++i) acc[i] = 0.0f;
    const size_t base = (size_t)lane * VEC;

    int j = s;
    for (; j + 3 < e; j += 4) {
        int s0 = csr_src[j],     s1 = csr_src[j + 1];
        int s2 = csr_src[j + 2], s3 = csr_src[j + 3];
        float w0 = csr_w[j],     w1 = csr_w[j + 1];
        float w2 = csr_w[j + 2], w3 = csr_w[j + 3];
        T q0 = *(const T*)(hw + (size_t)s0 * dfeat + base);
        T q1 = *(const T*)(hw + (size_t)s1 * dfeat + base);
        T q2 = *(const T*)(hw + (size_t)s2 * dfeat + base);
        T q3 = *(const T*)(hw + (size_t)s3 * dfeat + base);
        fma_unpack(q0, w0, acc);
        fma_unpack(q1, w1, acc);
        fma_unpack(q2, w2, acc);
        fma_unpack(q3, w3, acc);
    }
    for (; j < e; ++j) {
        int s0 = csr_src[j];
        float w0 = csr_w[j];
        T q0 = *(const T*)(hw + (size_t)s0 * dfeat + base);
        fma_unpack(q0, w0, acc);
    }

    #pragma unroll
    for (int i = 0; i < VEC; ++i) {
        int f = (int)base + i;
        float a = acc[i];
        if (mode != 0) {
            a += bias[f];
            if (mode == 1) {
                float scale = g[f] * rsqrtf(v[f] + BN_EPS);
                a = (a - m[f]) * scale + be[f];
            }
            a = 1.0f / (1.0f + __expf(-a));
        }
        out[(size_t)node * dfeat + f] = __float2bfloat16(a);
    }
}

// ---------------- final h^T h via MFMA ----------------
#define TPAD 8

__global__ __launch_bounds__(256) void htht_mfma_kernel(
    const bf16* __restrict__ h, float* __restrict__ partial, int n) {
    __shared__ bf16 hsT[128][32 + TPAD];
    int b = blockIdx.x;
    int tid = threadIdx.x;
    int wave = tid >> 6, lane = tid & 63;
    int lrow = lane & 15, quad = lane >> 4;

    f32x4 acc[2][8] = {};

    int kk = tid >> 3;       // 0..31
    int seg = tid & 7;       // 0..7

    for (int kt = 0; kt < 8; ++kt) {
        int k0 = b * 256 + kt * 32;
        #pragma unroll
        for (int s2 = 0; s2 < 2; ++s2) {
            int fs = (seg + s2 * 8) * 8;
            int gk = k0 + kk;
            uint4 q; q.x = q.y = q.z = q.w = 0u;
            if (gk < n) q = *(const uint4*)(h + (size_t)gk * 128 + fs);
            const unsigned short* u = (const unsigned short*)&q;
            #pragma unroll
            for (int i = 0; i < 8; ++i)
                *((unsigned short*)&hsT[fs + i][kk]) = u[i];
        }
        __syncthreads();
        short8 af0 = *(const short8*)(&hsT[wave * 32 + lrow][quad * 8]);
        short8 af1 = *(const short8*)(&hsT[wave * 32 + 16 + lrow][quad * 8]);
        #pragma unroll
        for (int t = 0; t < 8; ++t) {
            short8 bfrag = *(const short8*)(&hsT[t * 16 + lrow][quad * 8]);
            acc[0][t] = __builtin_amdgcn_mfma_f32_16x16x32_bf16(af0, bfrag, acc[0][t], 0, 0, 0);
            acc[1][t] = __builtin_amdgcn_mfma_f32_16x16x32_bf16(af1, bfrag, acc[1][t], 0, 0, 0);
        }
        __syncthreads();
    }
    float* p = partial + (size_t)b * 16384;
    #pragma unroll
    for (int a_ = 0; a_ < 2; ++a_) {
        #pragma unroll
        for (int t = 0; t < 8; ++t) {
            #pragma unroll
            for (int rr = 0; rr < 4; ++rr) {
                int gm = wave * 32 + a_ * 16 + quad * 4 + rr;
                int gn = t * 16 + lrow;
                p[gm * 128 + gn] = acc[a_][t][rr];
            }
        }
    }
}

__global__ void reduce_kernel(const float* __restrict__ partial, float* __restrict__ out, int nchunks) {
    int idx = blockIdx.x * blockDim.x + threadIdx.x;   // 16384 total
    float s = 0.0f;
    for (int c = 0; c < nchunks; ++c) s += partial[(size_t)c * 16384 + idx];
    int i = idx / 128, j = idx % 128;
    out[idx] = (i == j) ? 0.0f : s;
}

// ---------------- launch ----------------
extern "C" void kernel_launch(void* const* d_in, const int* in_sizes, int n_in,
                              void* d_out, int out_size, void* d_ws, size_t ws_size,
                              hipStream_t stream) {
    const float* x  = (const float*)d_in[0];
    const int*   ei = (const int*)d_in[1];
    const float* ea = (const float*)d_in[2];
    const float* W[5];  const float* bvec[5];
    for (int l = 0; l < 5; ++l) { W[l] = (const float*)d_in[3 + 2 * l]; bvec[l] = (const float*)d_in[4 + 2 * l]; }
    const float* g[4]; const float* be[4]; const float* mm[4]; const float* vv[4];
    for (int l = 0; l < 4; ++l) {
        g[l]  = (const float*)d_in[13 + 4 * l];
        be[l] = (const float*)d_in[14 + 4 * l];
        mm[l] = (const float*)d_in[15 + 4 * l];
        vv[l] = (const float*)d_in[16 + 4 * l];
    }
    const int n = in_sizes[0] / NSF;        // 20000
    const int E = in_sizes[1] / 2;          // 500000
    const int EN = E + n;
    const int rsize = (n + NR - 1) / NR;    // 5000
    const int dims[6] = {128, 256, 512, 256, 128, 128};
    const int wtoff[5] = {0, 32768, 163840, 294912, 327680};
    const int wtelems = 344064;

    // workspace layout (256B aligned); ~67 MB
    auto align = [](size_t o) { return (o + 255) & ~(size_t)255; };
    size_t off = 0;
    float* deg     = (float*)((char*)d_ws + off); off = align(off + (size_t)n * 4);
    float* dinv    = (float*)((char*)d_ws + off); off = align(off + (size_t)n * 4);
    int*   cnt     = (int*)  ((char*)d_ws + off); off = align(off + (size_t)n * NR * 4);
    int*   fill    = (int*)  ((char*)d_ws + off); off = align(off + (size_t)n * NR * 4);
    int*   row_ptr = (int*)  ((char*)d_ws + off); off = align(off + ((size_t)n * NR + 1) * 4);
    int*   csr_src = (int*)  ((char*)d_ws + off); off = align(off + (size_t)EN * 4);
    float* csr_w   = (float*)((char*)d_ws + off); off = align(off + (size_t)EN * 4);
    bf16*  wtbuf   = (bf16*) ((char*)d_ws + off); off = align(off + (size_t)wtelems * 2);
    bf16*  hbuf    = (bf16*) ((char*)d_ws + off); off = align(off + (size_t)n * 512 * 2);
    bf16*  abuf    = (bf16*) ((char*)d_ws + off); off = align(off + (size_t)n * 512 * 2);
    const int KCH = (20000 + 255) / 256;    // 79
    float* partial = (float*)((char*)d_ws + off); off = align(off + (size_t)KCH * 16384 * 4);

    // graph prep (range-segmented CSR for L2 locality in the gather)
    zero_kernel<<<(n * NR + 255) / 256, 256, 0, stream>>>(deg, cnt, fill, n);
    count_kernel<<<(EN + 255) / 256, 256, 0, stream>>>(ei, ea, deg, cnt, E, n, rsize);
    dinv_kernel<<<(n + 255) / 256, 256, 0, stream>>>(deg, dinv, n);
    scan_kernel<<<1, 256, 0, stream>>>(cnt, row_ptr, n * NR);
    fill_kernel<<<(EN + 255) / 256, 256, 0, stream>>>(ei, ea, dinv, row_ptr, fill, csr_src, csr_w, E, n, rsize);

    // dtype prep
    cvt_kernel<<<(n * 128 + 255) / 256, 256, 0, stream>>>(x, hbuf, n * 128);
    for (int l = 0; l < 5; ++l) {
        int K = dims[l], N = dims[l + 1];
        wt_kernel<<<(K * N + 255) / 256, 256, 0, stream>>>(W[l], wtbuf + wtoff[l], K, N);
    }

    int ablocks = (n + 3) / 4;
    auto gemm = [&](const bf16* A, int l, bf16* C, int mode) {
        int K = dims[l], N = dims[l + 1];
        dim3 gg((n + 63) / 64, N / 128);
        int bi = (l < 4) ? l : 0;
        mfma_gemm_kernel<<<gg, 256, 0, stream>>>(A, wtbuf + wtoff[l], C, n, K, N, mode,
                                                 bvec[l], g[bi], be[bi], mm[bi], vv[bi]);
    };

    // L1 (128->256): agg-first in 128-dim, GEMM fused bias+BN+sigmoid
    agg_vec_kernel<2><<<ablocks, 256, 0, stream>>>(hbuf, row_ptr, csr_src, csr_w,
        bvec[0], bvec[0], bvec[0], bvec[0], bvec[0], abuf, n, 0);
    gemm(abuf, 0, hbuf, 1);
    // L2 (256->512): agg-first in 256-dim
    agg_vec_kernel<4><<<ablocks, 256, 0, stream>>>(hbuf, row_ptr, csr_src, csr_w,
        bvec[1], bvec[1], bvec[1], bvec[1], bvec[1], abuf, n, 0);
    gemm(abuf, 1, hbuf, 1);
    // L3 (512->256): GEMM raw, agg-last in 256-dim with bias+BN+sigmoid
    gemm(hbuf, 2, abuf, 0);
    agg_vec_kernel<4><<<ablocks, 256, 0, stream>>>(abuf, row_ptr, csr_src, csr_w,
        bvec[2], g[2], be[2], mm[2], vv[2], hbuf, n, 1);
    // L4 (256->128): GEMM raw, agg-last with bias+BN+sigmoid
    gemm(hbuf, 3, abuf, 0);
    agg_vec_kernel<2><<<ablocks, 256, 0, stream>>>(abuf, row_ptr, csr_src, csr_w,
        bvec[3], g[3], be[3], mm[3], vv[3], hbuf, n, 1);
    // L5 (128->128): GEMM raw, agg-last with bias+sigmoid (no BN)
    gemm(hbuf, 4, abuf, 0);
    agg_vec_kernel<2><<<ablocks, 256, 0, stream>>>(abuf, row_ptr, csr_src, csr_w,
        bvec[4], bvec[4], bvec[4], bvec[4], bvec[4], hbuf, n, 2);

    // final h^T h with zeroed diagonal (MFMA)
    htht_mfma_kernel<<<KCH, 256, 0, stream>>>(hbuf, partial, n);
    reduce_kernel<<<16384 / 256, 256, 0, stream>>>(partial, (float*)d_out, KCH);
}

// Round 8
// 501.583 us; speedup vs baseline: 1.2510x; 1.2510x over previous
//
#include <hip/hip_runtime.h>
#include <hip/hip_bf16.h>
#include <cstdint>
#include <cstddef>

typedef __hip_bfloat16 bf16;
typedef __attribute__((ext_vector_type(8))) short short8;   // 8 bf16 (MFMA A/B frag)
typedef __attribute__((ext_vector_type(4))) float f32x4;    // MFMA C/D frag

#define NSF 128
#define BN_EPS 1e-3f
#define NR 4            // src ranges per node for L2 locality
#define SCK 2048        // elements per scan block (256 thr x 8)

// ---------------- graph-norm prep ----------------

// zero deg[n], cnt[n*NR], fill[n*NR]
__global__ void zero_kernel(float* __restrict__ deg, int* __restrict__ cnt,
                            int* __restrict__ fill, int n) {
    int i = blockIdx.x * blockDim.x + threadIdx.x;
    if (i < n) deg[i] = 0.0f;
    if (i < n * NR) { cnt[i] = 0; fill[i] = 0; }
}

// deg[col] += w ; cnt[col*NR + range(src)] += 1  for E edges + N self loops
__global__ void count_kernel(const int* __restrict__ ei, const float* __restrict__ ea,
                             float* __restrict__ deg, int* __restrict__ cnt,
                             int E, int n, int rsize) {
    int idx = blockIdx.x * blockDim.x + threadIdx.x;
    if (idx < E) {
        int r = ei[idx];
        int c = ei[E + idx];
        atomicAdd(&deg[c], ea[idx]);
        atomicAdd(&cnt[c * NR + r / rsize], 1);
    } else if (idx < E + n) {
        int i = idx - E;
        atomicAdd(&deg[i], 1.0f);
        atomicAdd(&cnt[i * NR + i / rsize], 1);
    }
}

__global__ void dinv_kernel(const float* __restrict__ deg, float* __restrict__ dinv, int n) {
    int i = blockIdx.x * blockDim.x + threadIdx.x;
    if (i < n) {
        float d = deg[i];
        dinv[i] = (d > 0.0f) ? rsqrtf(d) : 0.0f;
    }
}

// ---- hierarchical exclusive scan of cnt[0..total) -> row_ptr[0..total] ----

// phase 1: per-block sums
__global__ void scan1_kernel(const int* __restrict__ cnt, int* __restrict__ blksum, int total) {
    __shared__ int red[256];
    int base = blockIdx.x * SCK + threadIdx.x * 8;
    int s = 0;
    #pragma unroll
    for (int i = 0; i < 8; ++i) {
        int idx = base + i;
        if (idx < total) s += cnt[idx];
    }
    red[threadIdx.x] = s;
    __syncthreads();
    for (int off2 = 128; off2 > 0; off2 >>= 1) {
        if (threadIdx.x < off2) red[threadIdx.x] += red[threadIdx.x + off2];
        __syncthreads();
    }
    if (threadIdx.x == 0) blksum[blockIdx.x] = red[0];
}

// phase 2: single small block scans block sums (nblk <= 256), writes row_ptr[total]
__global__ void scan2_kernel(int* __restrict__ blksum, int* __restrict__ row_ptr,
                             int nblk, int total) {
    __shared__ int part[256];
    int tid = threadIdx.x;
    int v = (tid < nblk) ? blksum[tid] : 0;
    part[tid] = v;
    __syncthreads();
    for (int off2 = 1; off2 < 256; off2 <<= 1) {
        int t = (tid >= off2) ? part[tid - off2] : 0;
        __syncthreads();
        part[tid] += t;
        __syncthreads();
    }
    if (tid < nblk) blksum[tid] = part[tid] - v;   // exclusive block offset
    if (tid == 255) row_ptr[total] = part[255];    // grand total
}

// phase 3: local scan + block offset
__global__ void scan3_kernel(const int* __restrict__ cnt, const int* __restrict__ blkoff,
                             int* __restrict__ row_ptr, int total) {
    __shared__ int part[256];
    int tid = threadIdx.x;
    int base = blockIdx.x * SCK + tid * 8;
    int loc[8]; int s = 0;
    #pragma unroll
    for (int i = 0; i < 8; ++i) {
        int idx = base + i;
        loc[i] = (idx < total) ? cnt[idx] : 0;
        s += loc[i];
    }
    part[tid] = s;
    __syncthreads();
    for (int off2 = 1; off2 < 256; off2 <<= 1) {
        int t = (tid >= off2) ? part[tid - off2] : 0;
        __syncthreads();
        part[tid] += t;
        __syncthreads();
    }
    int run = blkoff[blockIdx.x] + part[tid] - s;
    #pragma unroll
    for (int i = 0; i < 8; ++i) {
        int idx = base + i;
        if (idx < total) { row_ptr[idx] = run; run += loc[i]; }
    }
}

// scatter edges into range-segmented CSR slots; csr_w = dinv[row]*w*dinv[col]
__global__ void fill_kernel(const int* __restrict__ ei, const float* __restrict__ ea,
                            const float* __restrict__ dinv,
                            const int* __restrict__ row_ptr, int* __restrict__ fill,
                            int* __restrict__ csr_src, float* __restrict__ csr_w,
                            int E, int n, int rsize) {
    int idx = blockIdx.x * blockDim.x + threadIdx.x;
    if (idx < E) {
        int r = ei[idx];
        int c = ei[E + idx];
        int slot = c * NR + r / rsize;
        int p = row_ptr[slot] + atomicAdd(&fill[slot], 1);
        csr_src[p] = r;
        csr_w[p] = dinv[r] * ea[idx] * dinv[c];
    } else if (idx < E + n) {
        int i = idx - E;
        int slot = i * NR + i / rsize;
        int p = row_ptr[slot] + atomicAdd(&fill[slot], 1);
        csr_src[p] = i;
        csr_w[p] = dinv[i] * dinv[i];
    }
}

// ---------------- dtype prep ----------------

__global__ void cvt_kernel(const float* __restrict__ x, bf16* __restrict__ y, int count) {
    int i = blockIdx.x * blockDim.x + threadIdx.x;
    if (i < count) y[i] = __float2bfloat16(x[i]);
}

// Wt[n*K + k] = bf16(W[k*N + n])
__global__ void wt_kernel(const float* __restrict__ W, bf16* __restrict__ Wt, int K, int N) {
    int idx = blockIdx.x * blockDim.x + threadIdx.x;
    if (idx < K * N) {
        int nn = idx / K, kk = idx % K;
        Wt[idx] = __float2bfloat16(W[(size_t)kk * N + nn]);
    }
}

// ---------------- MFMA GEMM: C[M,N] = A[M,K] @ Wt[N,K]^T, fused epilogue ----------------
// mode 0: raw store; mode 1: sigmoid(BN(acc+bias))
#define GPAD 8

__global__ __launch_bounds__(256) void mfma_gemm_kernel(
    const bf16* __restrict__ A, const bf16* __restrict__ Wt,
    bf16* __restrict__ C, int M, int K, int N, int mode,
    const float* __restrict__ bias, const float* __restrict__ g,
    const float* __restrict__ be, const float* __restrict__ m,
    const float* __restrict__ v) {
    __shared__ bf16 As[64][32 + GPAD];
    __shared__ bf16 Bs[128][32 + GPAD];
    int m0 = blockIdx.x * 64;
    int n0 = blockIdx.y * 128;
    int tid = threadIdx.x;
    int wave = tid >> 6, lane = tid & 63;
    int lrow = lane & 15, quad = lane >> 4;

    f32x4 acc[8] = {};

    int r = tid >> 2;      // 0..63
    int seg = tid & 3;     // 0..3

    for (int k0 = 0; k0 < K; k0 += 32) {
        uint4 av; av.x = av.y = av.z = av.w = 0u;
        int gm = m0 + r;
        if (gm < M) av = *(const uint4*)(A + (size_t)gm * K + k0 + seg * 8);
        *(uint4*)(&As[r][seg * 8]) = av;
        *(uint4*)(&Bs[r][seg * 8]) =
            *(const uint4*)(Wt + (size_t)(n0 + r) * K + k0 + seg * 8);
        *(uint4*)(&Bs[r + 64][seg * 8]) =
            *(const uint4*)(Wt + (size_t)(n0 + r + 64) * K + k0 + seg * 8);
        __syncthreads();

        short8 afrag = *(const short8*)(&As[wave * 16 + lrow][quad * 8]);
        #pragma unroll
        for (int t = 0; t < 8; ++t) {
            short8 bfrag = *(const short8*)(&Bs[t * 16 + lrow][quad * 8]);
            acc[t] = __builtin_amdgcn_mfma_f32_16x16x32_bf16(afrag, bfrag, acc[t], 0, 0, 0);
        }
        __syncthreads();
    }
    // C/D: col = lane&15, row = quad*4 + reg
    #pragma unroll
    for (int t = 0; t < 8; ++t) {
        int gn = n0 + t * 16 + lrow;
        float bsc = 0.0f, scale = 1.0f, mean = 0.0f, beta = 0.0f;
        if (mode == 1) {
            bsc = bias[gn];
            scale = g[gn] * rsqrtf(v[gn] + BN_EPS);
            mean = m[gn];
            beta = be[gn];
        }
        #pragma unroll
        for (int rr = 0; rr < 4; ++rr) {
            int gm = m0 + wave * 16 + quad * 4 + rr;
            if (gm < M) {
                float a = acc[t][rr];
                if (mode == 1) {
                    a = (a + bsc - mean) * scale + beta;
                    a = 1.0f / (1.0f + __expf(-a));
                }
                C[(size_t)gm * N + gn] = __float2bfloat16(a);
            }
        }
    }
}

// ---------------- vectorized aggregation ----------------

__device__ inline float bfu(unsigned int u16) {
    union { unsigned int u; float f; } c; c.u = u16 << 16; return c.f;
}
__device__ inline void fma_unpack(unsigned int q, float w, float* acc) {
    acc[0] += w * bfu(q & 0xffffu);
    acc[1] += w * bfu(q >> 16);
}
__device__ inline void fma_unpack(uint2 q, float w, float* acc) {
    fma_unpack(q.x, w, acc); fma_unpack(q.y, w, acc + 2);
}
__device__ inline void fma_unpack(uint4 q, float w, float* acc) {
    fma_unpack(q.x, w, acc);     fma_unpack(q.y, w, acc + 2);
    fma_unpack(q.z, w, acc + 4); fma_unpack(q.w, w, acc + 6);
}

template <int VEC> struct UVec;
template <> struct UVec<2> { typedef unsigned int T; };
template <> struct UVec<4> { typedef uint2 T; };
template <> struct UVec<8> { typedef uint4 T; };

// wave per node; lane owns VEC consecutive features (dfeat = 64*VEC)
// mode 0: plain weighted sum (agg-first); 1: bias+BN+sigmoid; 2: bias+sigmoid
// row_ptr is range-segmented: node's edges span [row_ptr[node*NR], row_ptr[(node+1)*NR])
template <int VEC>
__global__ __launch_bounds__(256) void agg_vec_kernel(
    const bf16* __restrict__ hw,
    const int* __restrict__ row_ptr,
    const int* __restrict__ csr_src, const float* __restrict__ csr_w,
    const float* __restrict__ bias,
    const float* __restrict__ g, const float* __restrict__ be,
    const float* __restrict__ m, const float* __restrict__ v,
    bf16* __restrict__ out, int n, int mode) {
    typedef typename UVec<VEC>::T T;
    const int dfeat = VEC * 64;
    int wave = threadIdx.x >> 6;
    int lane = threadIdx.x & 63;
    int node = blockIdx.x * 4 + wave;
    if (node >= n) return;
    int s = row_ptr[node * NR], e = row_ptr[(node + 1) * NR];
    float acc[VEC];
    #pragma unroll
    for (int i = 0; i < VEC; ++i) acc[i] = 0.0f;
    const size_t base = (size_t)lane * VEC;

    int j = s;
    for (; j + 3 < e; j += 4) {
        int s0 = csr_src[j],     s1 = csr_src[j + 1];
        int s2 = csr_src[j + 2], s3 = csr_src[j + 3];
        float w0 = csr_w[j],     w1 = csr_w[j + 1];
        float w2 = csr_w[j + 2], w3 = csr_w[j + 3];
        T q0 = *(const T*)(hw + (size_t)s0 * dfeat + base);
        T q1 = *(const T*)(hw + (size_t)s1 * dfeat + base);
        T q2 = *(const T*)(hw + (size_t)s2 * dfeat + base);
        T q3 = *(const T*)(hw + (size_t)s3 * dfeat + base);
        fma_unpack(q0, w0, acc);
        fma_unpack(q1, w1, acc);
        fma_unpack(q2, w2, acc);
        fma_unpack(q3, w3, acc);
    }
    for (; j < e; ++j) {
        int s0 = csr_src[j];
        float w0 = csr_w[j];
        T q0 = *(const T*)(hw + (size_t)s0 * dfeat + base);
        fma_unpack(q0, w0, acc);
    }

    #pragma unroll
    for (int i = 0; i < VEC; ++i) {
        int f = (int)base + i;
        float a = acc[i];
        if (mode != 0) {
            a += bias[f];
            if (mode == 1) {
                float scale = g[f] * rsqrtf(v[f] + BN_EPS);
                a = (a - m[f]) * scale + be[f];
            }
            a = 1.0f / (1.0f + __expf(-a));
        }
        out[(size_t)node * dfeat + f] = __float2bfloat16(a);
    }
}

// ---------------- final h^T h via MFMA ----------------
#define TPAD 8

__global__ __launch_bounds__(256) void htht_mfma_kernel(
    const bf16* __restrict__ h, float* __restrict__ partial, int n) {
    __shared__ bf16 hsT[128][32 + TPAD];
    int b = blockIdx.x;
    int tid = threadIdx.x;
    int wave = tid >> 6, lane = tid & 63;
    int lrow = lane & 15, quad = lane >> 4;

    f32x4 acc[2][8] = {};

    int kk = tid >> 3;       // 0..31
    int seg = tid & 7;       // 0..7

    for (int kt = 0; kt < 8; ++kt) {
        int k0 = b * 256 + kt * 32;
        #pragma unroll
        for (int s2 = 0; s2 < 2; ++s2) {
            int fs = (seg + s2 * 8) * 8;
            int gk = k0 + kk;
            uint4 q; q.x = q.y = q.z = q.w = 0u;
            if (gk < n) q = *(const uint4*)(h + (size_t)gk * 128 + fs);
            const unsigned short* u = (const unsigned short*)&q;
            #pragma unroll
            for (int i = 0; i < 8; ++i)
                *((unsigned short*)&hsT[fs + i][kk]) = u[i];
        }
        __syncthreads();
        short8 af0 = *(const short8*)(&hsT[wave * 32 + lrow][quad * 8]);
        short8 af1 = *(const short8*)(&hsT[wave * 32 + 16 + lrow][quad * 8]);
        #pragma unroll
        for (int t = 0; t < 8; ++t) {
            short8 bfrag = *(const short8*)(&hsT[t * 16 + lrow][quad * 8]);
            acc[0][t] = __builtin_amdgcn_mfma_f32_16x16x32_bf16(af0, bfrag, acc[0][t], 0, 0, 0);
            acc[1][t] = __builtin_amdgcn_mfma_f32_16x16x32_bf16(af1, bfrag, acc[1][t], 0, 0, 0);
        }
        __syncthreads();
    }
    float* p = partial + (size_t)b * 16384;
    #pragma unroll
    for (int a_ = 0; a_ < 2; ++a_) {
        #pragma unroll
        for (int t = 0; t < 8; ++t) {
            #pragma unroll
            for (int rr = 0; rr < 4; ++rr) {
                int gm = wave * 32 + a_ * 16 + quad * 4 + rr;
                int gn = t * 16 + lrow;
                p[gm * 128 + gn] = acc[a_][t][rr];
            }
        }
    }
}

__global__ void reduce_kernel(const float* __restrict__ partial, float* __restrict__ out, int nchunks) {
    int idx = blockIdx.x * blockDim.x + threadIdx.x;   // 16384 total
    float s = 0.0f;
    for (int c = 0; c < nchunks; ++c) s += partial[(size_t)c * 16384 + idx];
    int i = idx / 128, j = idx % 128;
    out[idx] = (i == j) ? 0.0f : s;
}

// ---------------- launch ----------------
extern "C" void kernel_launch(void* const* d_in, const int* in_sizes, int n_in,
                              void* d_out, int out_size, void* d_ws, size_t ws_size,
                              hipStream_t stream) {
    const float* x  = (const float*)d_in[0];
    const int*   ei = (const int*)d_in[1];
    const float* ea = (const float*)d_in[2];
    const float* W[5];  const float* bvec[5];
    for (int l = 0; l < 5; ++l) { W[l] = (const float*)d_in[3 + 2 * l]; bvec[l] = (const float*)d_in[4 + 2 * l]; }
    const float* g[4]; const float* be[4]; const float* mm[4]; const float* vv[4];
    for (int l = 0; l < 4; ++l) {
        g[l]  = (const float*)d_in[13 + 4 * l];
        be[l] = (const float*)d_in[14 + 4 * l];
        mm[l] = (const float*)d_in[15 + 4 * l];
        vv[l] = (const float*)d_in[16 + 4 * l];
    }
    const int n = in_sizes[0] / NSF;        // 20000
    const int E = in_sizes[1] / 2;          // 500000
    const int EN = E + n;
    const int rsize = (n + NR - 1) / NR;    // 5000
    const int total = n * NR;               // 80000
    const int nscan = (total + SCK - 1) / SCK;  // 40
    const int dims[6] = {128, 256, 512, 256, 128, 128};
    const int wtoff[5] = {0, 32768, 163840, 294912, 327680};
    const int wtelems = 344064;

    // workspace layout (256B aligned); ~67 MB
    auto align = [](size_t o) { return (o + 255) & ~(size_t)255; };
    size_t off = 0;
    float* deg     = (float*)((char*)d_ws + off); off = align(off + (size_t)n * 4);
    float* dinv    = (float*)((char*)d_ws + off); off = align(off + (size_t)n * 4);
    int*   cnt     = (int*)  ((char*)d_ws + off); off = align(off + (size_t)total * 4);
    int*   fill    = (int*)  ((char*)d_ws + off); off = align(off + (size_t)total * 4);
    int*   row_ptr = (int*)  ((char*)d_ws + off); off = align(off + ((size_t)total + 1) * 4);
    int*   blksum  = (int*)  ((char*)d_ws + off); off = align(off + (size_t)256 * 4);
    int*   csr_src = (int*)  ((char*)d_ws + off); off = align(off + (size_t)EN * 4);
    float* csr_w   = (float*)((char*)d_ws + off); off = align(off + (size_t)EN * 4);
    bf16*  wtbuf   = (bf16*) ((char*)d_ws + off); off = align(off + (size_t)wtelems * 2);
    bf16*  hbuf    = (bf16*) ((char*)d_ws + off); off = align(off + (size_t)n * 512 * 2);
    bf16*  abuf    = (bf16*) ((char*)d_ws + off); off = align(off + (size_t)n * 512 * 2);
    const int KCH = (20000 + 255) / 256;    // 79
    float* partial = (float*)((char*)d_ws + off); off = align(off + (size_t)KCH * 16384 * 4);

    // graph prep (range-segmented CSR; hierarchical scan)
    zero_kernel<<<(total + 255) / 256, 256, 0, stream>>>(deg, cnt, fill, n);
    count_kernel<<<(EN + 255) / 256, 256, 0, stream>>>(ei, ea, deg, cnt, E, n, rsize);
    dinv_kernel<<<(n + 255) / 256, 256, 0, stream>>>(deg, dinv, n);
    scan1_kernel<<<nscan, 256, 0, stream>>>(cnt, blksum, total);
    scan2_kernel<<<1, 256, 0, stream>>>(blksum, row_ptr, nscan, total);
    scan3_kernel<<<nscan, 256, 0, stream>>>(cnt, blksum, row_ptr, total);
    fill_kernel<<<(EN + 255) / 256, 256, 0, stream>>>(ei, ea, dinv, row_ptr, fill, csr_src, csr_w, E, n, rsize);

    // dtype prep
    cvt_kernel<<<(n * 128 + 255) / 256, 256, 0, stream>>>(x, hbuf, n * 128);
    for (int l = 0; l < 5; ++l) {
        int K = dims[l], N = dims[l + 1];
        wt_kernel<<<(K * N + 255) / 256, 256, 0, stream>>>(W[l], wtbuf + wtoff[l], K, N);
    }

    int ablocks = (n + 3) / 4;
    auto gemm = [&](const bf16* A, int l, bf16* C, int mode) {
        int K = dims[l], N = dims[l + 1];
        dim3 gg((n + 63) / 64, N / 128);
        int bi = (l < 4) ? l : 0;
        mfma_gemm_kernel<<<gg, 256, 0, stream>>>(A, wtbuf + wtoff[l], C, n, K, N, mode,
                                                 bvec[l], g[bi], be[bi], mm[bi], vv[bi]);
    };

    // L1 (128->256): agg-first in 128-dim, GEMM fused bias+BN+sigmoid
    agg_vec_kernel<2><<<ablocks, 256, 0, stream>>>(hbuf, row_ptr, csr_src, csr_w,
        bvec[0], bvec[0], bvec[0], bvec[0], bvec[0], abuf, n, 0);
    gemm(abuf, 0, hbuf, 1);
    // L2 (256->512): agg-first in 256-dim
    agg_vec_kernel<4><<<ablocks, 256, 0, stream>>>(hbuf, row_ptr, csr_src, csr_w,
        bvec[1], bvec[1], bvec[1], bvec[1], bvec[1], abuf, n, 0);
    gemm(abuf, 1, hbuf, 1);
    // L3 (512->256): GEMM raw, agg-last in 256-dim with bias+BN+sigmoid
    gemm(hbuf, 2, abuf, 0);
    agg_vec_kernel<4><<<ablocks, 256, 0, stream>>>(abuf, row_ptr, csr_src, csr_w,
        bvec[2], g[2], be[2], mm[2], vv[2], hbuf, n, 1);
    // L4 (256->128): GEMM raw, agg-last with bias+BN+sigmoid
    gemm(hbuf, 3, abuf, 0);
    agg_vec_kernel<2><<<ablocks, 256, 0, stream>>>(abuf, row_ptr, csr_src, csr_w,
        bvec[3], g[3], be[3], mm[3], vv[3], hbuf, n, 1);
    // L5 (128->128): GEMM raw, agg-last with bias+sigmoid (no BN)
    gemm(hbuf, 4, abuf, 0);
    agg_vec_kernel<2><<<ablocks, 256, 0, stream>>>(abuf, row_ptr, csr_src, csr_w,
        bvec[4], bvec[4], bvec[4], bvec[4], bvec[4], hbuf, n, 2);

    // final h^T h with zeroed diagonal (MFMA)
    htht_mfma_kernel<<<KCH, 256, 0, stream>>>(hbuf, partial, n);
    reduce_kernel<<<16384 / 256, 256, 0, stream>>>(partial, (float*)d_out, KCH);
}

// Round 9
// 487.676 us; speedup vs baseline: 1.2866x; 1.0285x over previous
//
#include <hip/hip_runtime.h>
#include <hip/hip_bf16.h>
#include <hip/hip_fp8.h>
#include <cstdint>
#include <cstddef>

typedef __hip_bfloat16 bf16;
typedef unsigned char fp8;                                  // e4m3 storage
typedef __attribute__((ext_vector_type(8))) short short8;   // 8 bf16 (MFMA A/B frag)
typedef __attribute__((ext_vector_type(4))) float f32x4;    // MFMA C/D frag

#define NSF 128
#define BN_EPS 1e-3f
#define NR 4            // src ranges per node (kept; costless with hierarchical scan)
#define SCK 2048        // elements per scan block

// ---------------- graph-norm prep ----------------

__global__ void zero_kernel(float* __restrict__ deg, int* __restrict__ cnt,
                            int* __restrict__ fill, int n) {
    int i = blockIdx.x * blockDim.x + threadIdx.x;
    if (i < n) deg[i] = 0.0f;
    if (i < n * NR) { cnt[i] = 0; fill[i] = 0; }
}

__global__ void count_kernel(const int* __restrict__ ei, const float* __restrict__ ea,
                             float* __restrict__ deg, int* __restrict__ cnt,
                             int E, int n, int rsize) {
    int idx = blockIdx.x * blockDim.x + threadIdx.x;
    if (idx < E) {
        int r = ei[idx];
        int c = ei[E + idx];
        atomicAdd(&deg[c], ea[idx]);
        atomicAdd(&cnt[c * NR + r / rsize], 1);
    } else if (idx < E + n) {
        int i = idx - E;
        atomicAdd(&deg[i], 1.0f);
        atomicAdd(&cnt[i * NR + i / rsize], 1);
    }
}

__global__ void dinv_kernel(const float* __restrict__ deg, float* __restrict__ dinv, int n) {
    int i = blockIdx.x * blockDim.x + threadIdx.x;
    if (i < n) {
        float d = deg[i];
        dinv[i] = (d > 0.0f) ? rsqrtf(d) : 0.0f;
    }
}

// ---- hierarchical exclusive scan ----

__global__ void scan1_kernel(const int* __restrict__ cnt, int* __restrict__ blksum, int total) {
    __shared__ int red[256];
    int base = blockIdx.x * SCK + threadIdx.x * 8;
    int s = 0;
    #pragma unroll
    for (int i = 0; i < 8; ++i) {
        int idx = base + i;
        if (idx < total) s += cnt[idx];
    }
    red[threadIdx.x] = s;
    __syncthreads();
    for (int off2 = 128; off2 > 0; off2 >>= 1) {
        if (threadIdx.x < off2) red[threadIdx.x] += red[threadIdx.x + off2];
        __syncthreads();
    }
    if (threadIdx.x == 0) blksum[blockIdx.x] = red[0];
}

__global__ void scan2_kernel(int* __restrict__ blksum, int* __restrict__ row_ptr,
                             int nblk, int total) {
    __shared__ int part[256];
    int tid = threadIdx.x;
    int v = (tid < nblk) ? blksum[tid] : 0;
    part[tid] = v;
    __syncthreads();
    for (int off2 = 1; off2 < 256; off2 <<= 1) {
        int t = (tid >= off2) ? part[tid - off2] : 0;
        __syncthreads();
        part[tid] += t;
        __syncthreads();
    }
    if (tid < nblk) blksum[tid] = part[tid] - v;
    if (tid == 255) row_ptr[total] = part[255];
}

__global__ void scan3_kernel(const int* __restrict__ cnt, const int* __restrict__ blkoff,
                             int* __restrict__ row_ptr, int total) {
    __shared__ int part[256];
    int tid = threadIdx.x;
    int base = blockIdx.x * SCK + tid * 8;
    int loc[8]; int s = 0;
    #pragma unroll
    for (int i = 0; i < 8; ++i) {
        int idx = base + i;
        loc[i] = (idx < total) ? cnt[idx] : 0;
        s += loc[i];
    }
    part[tid] = s;
    __syncthreads();
    for (int off2 = 1; off2 < 256; off2 <<= 1) {
        int t = (tid >= off2) ? part[tid - off2] : 0;
        __syncthreads();
        part[tid] += t;
        __syncthreads();
    }
    int run = blkoff[blockIdx.x] + part[tid] - s;
    #pragma unroll
    for (int i = 0; i < 8; ++i) {
        int idx = base + i;
        if (idx < total) { row_ptr[idx] = run; run += loc[i]; }
    }
}

__global__ void fill_kernel(const int* __restrict__ ei, const float* __restrict__ ea,
                            const float* __restrict__ dinv,
                            const int* __restrict__ row_ptr, int* __restrict__ fill,
                            int* __restrict__ csr_src, float* __restrict__ csr_w,
                            int E, int n, int rsize) {
    int idx = blockIdx.x * blockDim.x + threadIdx.x;
    if (idx < E) {
        int r = ei[idx];
        int c = ei[E + idx];
        int slot = c * NR + r / rsize;
        int p = row_ptr[slot] + atomicAdd(&fill[slot], 1);
        csr_src[p] = r;
        csr_w[p] = dinv[r] * ea[idx] * dinv[c];
    } else if (idx < E + n) {
        int i = idx - E;
        int slot = i * NR + i / rsize;
        int p = row_ptr[slot] + atomicAdd(&fill[slot], 1);
        csr_src[p] = i;
        csr_w[p] = dinv[i] * dinv[i];
    }
}

// ---------------- dtype prep ----------------

__global__ void cvt_kernel(const float* __restrict__ x, bf16* __restrict__ y, int count) {
    int i = blockIdx.x * blockDim.x + threadIdx.x;
    if (i < count) y[i] = __float2bfloat16(x[i]);
}

__global__ void wt_kernel(const float* __restrict__ W, bf16* __restrict__ Wt, int K, int N) {
    int idx = blockIdx.x * blockDim.x + threadIdx.x;
    if (idx < K * N) {
        int nn = idx / K, kk = idx % K;
        Wt[idx] = __float2bfloat16(W[(size_t)kk * N + nn]);
    }
}

// ---------------- output-type helpers ----------------

__device__ inline void store_val(bf16* C, size_t idx, float a) {
    C[idx] = __float2bfloat16(a);
}
__device__ inline void store_val(fp8* C, size_t idx, float a) {
    __hip_fp8_e4m3 t(a);
    C[idx] = (fp8)t.__x;
}
__device__ inline float f8f(unsigned int b) {
    __hip_fp8_e4m3 v; v.__x = (__hip_fp8_storage_t)b; return (float)v;
}

// ---------------- MFMA GEMM: C[M,N] = A[M,K] @ Wt[N,K]^T, fused epilogue ----------------
// mode 0: raw store; mode 1: sigmoid(BN(acc+bias))
#define GPAD 8

template <typename OT>
__global__ __launch_bounds__(256) void mfma_gemm_kernel(
    const bf16* __restrict__ A, const bf16* __restrict__ Wt,
    OT* __restrict__ C, int M, int K, int N, int mode,
    const float* __restrict__ bias, const float* __restrict__ g,
    const float* __restrict__ be, const float* __restrict__ m,
    const float* __restrict__ v) {
    __shared__ bf16 As[64][32 + GPAD];
    __shared__ bf16 Bs[128][32 + GPAD];
    int m0 = blockIdx.x * 64;
    int n0 = blockIdx.y * 128;
    int tid = threadIdx.x;
    int wave = tid >> 6, lane = tid & 63;
    int lrow = lane & 15, quad = lane >> 4;

    f32x4 acc[8] = {};

    int r = tid >> 2;
    int seg = tid & 3;

    for (int k0 = 0; k0 < K; k0 += 32) {
        uint4 av; av.x = av.y = av.z = av.w = 0u;
        int gm = m0 + r;
        if (gm < M) av = *(const uint4*)(A + (size_t)gm * K + k0 + seg * 8);
        *(uint4*)(&As[r][seg * 8]) = av;
        *(uint4*)(&Bs[r][seg * 8]) =
            *(const uint4*)(Wt + (size_t)(n0 + r) * K + k0 + seg * 8);
        *(uint4*)(&Bs[r + 64][seg * 8]) =
            *(const uint4*)(Wt + (size_t)(n0 + r + 64) * K + k0 + seg * 8);
        __syncthreads();

        short8 afrag = *(const short8*)(&As[wave * 16 + lrow][quad * 8]);
        #pragma unroll
        for (int t = 0; t < 8; ++t) {
            short8 bfrag = *(const short8*)(&Bs[t * 16 + lrow][quad * 8]);
            acc[t] = __builtin_amdgcn_mfma_f32_16x16x32_bf16(afrag, bfrag, acc[t], 0, 0, 0);
        }
        __syncthreads();
    }
    #pragma unroll
    for (int t = 0; t < 8; ++t) {
        int gn = n0 + t * 16 + lrow;
        float bsc = 0.0f, scale = 1.0f, mean = 0.0f, beta = 0.0f;
        if (mode == 1) {
            bsc = bias[gn];
            scale = g[gn] * rsqrtf(v[gn] + BN_EPS);
            mean = m[gn];
            beta = be[gn];
        }
        #pragma unroll
        for (int rr = 0; rr < 4; ++rr) {
            int gm = m0 + wave * 16 + quad * 4 + rr;
            if (gm < M) {
                float a = acc[t][rr];
                if (mode == 1) {
                    a = (a + bsc - mean) * scale + beta;
                    a = 1.0f / (1.0f + __expf(-a));
                }
                store_val(C, (size_t)gm * N + gn, a);
            }
        }
    }
}

// ---------------- bf16 vectorized aggregation ----------------

__device__ inline float bfu(unsigned int u16) {
    union { unsigned int u; float f; } c; c.u = u16 << 16; return c.f;
}
__device__ inline void fma_unpack(unsigned int q, float w, float* acc) {
    acc[0] += w * bfu(q & 0xffffu);
    acc[1] += w * bfu(q >> 16);
}
__device__ inline void fma_unpack(uint2 q, float w, float* acc) {
    fma_unpack(q.x, w, acc); fma_unpack(q.y, w, acc + 2);
}

template <int VEC> struct UVec;
template <> struct UVec<2> { typedef unsigned int T; };
template <> struct UVec<4> { typedef uint2 T; };

// wave per node; lane owns VEC consecutive features (dfeat = 64*VEC)
// mode 0: plain weighted sum; 1: bias+BN+sigmoid; 2: bias+sigmoid
template <int VEC>
__global__ __launch_bounds__(256) void agg_vec_kernel(
    const bf16* __restrict__ hw,
    const int* __restrict__ row_ptr,
    const int* __restrict__ csr_src, const float* __restrict__ csr_w,
    const float* __restrict__ bias,
    const float* __restrict__ g, const float* __restrict__ be,
    const float* __restrict__ m, const float* __restrict__ v,
    bf16* __restrict__ out, int n, int mode) {
    typedef typename UVec<VEC>::T T;
    const int dfeat = VEC * 64;
    int wave = threadIdx.x >> 6;
    int lane = threadIdx.x & 63;
    int node = blockIdx.x * 4 + wave;
    if (node >= n) return;
    int s = row_ptr[node * NR], e = row_ptr[(node + 1) * NR];
    float acc[VEC];
    #pragma unroll
    for (int i = 0; i < VEC; ++i) acc[i] = 0.0f;
    const size_t base = (size_t)lane * VEC;

    int j = s;
    for (; j + 3 < e; j += 4) {
        int s0 = csr_src[j],     s1 = csr_src[j + 1];
        int s2 = csr_src[j + 2], s3 = csr_src[j + 3];
        float w0 = csr_w[j],     w1 = csr_w[j + 1];
        float w2 = csr_w[j + 2], w3 = csr_w[j + 3];
        T q0 = *(const T*)(hw + (size_t)s0 * dfeat + base);
        T q1 = *(const T*)(hw + (size_t)s1 * dfeat + base);
        T q2 = *(const T*)(hw + (size_t)s2 * dfeat + base);
        T q3 = *(const T*)(hw + (size_t)s3 * dfeat + base);
        fma_unpack(q0, w0, acc);
        fma_unpack(q1, w1, acc);
        fma_unpack(q2, w2, acc);
        fma_unpack(q3, w3, acc);
    }
    for (; j < e; ++j) {
        int s0 = csr_src[j];
        float w0 = csr_w[j];
        T q0 = *(const T*)(hw + (size_t)s0 * dfeat + base);
        fma_unpack(q0, w0, acc);
    }

    #pragma unroll
    for (int i = 0; i < VEC; ++i) {
        int f = (int)base + i;
        float a = acc[i];
        if (mode != 0) {
            a += bias[f];
            if (mode == 1) {
                float scale = g[f] * rsqrtf(v[f] + BN_EPS);
                a = (a - m[f]) * scale + be[f];
            }
            a = 1.0f / (1.0f + __expf(-a));
        }
        out[(size_t)node * dfeat + f] = __float2bfloat16(a);
    }
}

// ---------------- fp8 aggregation (DF=256): lane loads uint = 4 fp8 ----------------

__device__ inline void fma_unpack_f8(unsigned int q, float w, float* acc) {
    acc[0] += w * f8f(q & 0xffu);
    acc[1] += w * f8f((q >> 8) & 0xffu);
    acc[2] += w * f8f((q >> 16) & 0xffu);
    acc[3] += w * f8f(q >> 24);
}

__global__ __launch_bounds__(256) void agg_fp8_kernel(
    const fp8* __restrict__ hw,
    const int* __restrict__ row_ptr,
    const int* __restrict__ csr_src, const float* __restrict__ csr_w,
    const float* __restrict__ bias,
    const float* __restrict__ g, const float* __restrict__ be,
    const float* __restrict__ m, const float* __restrict__ v,
    bf16* __restrict__ out, int n, int mode) {
    const int dfeat = 256;
    int wave = threadIdx.x >> 6;
    int lane = threadIdx.x & 63;
    int node = blockIdx.x * 4 + wave;
    if (node >= n) return;
    int s = row_ptr[node * NR], e = row_ptr[(node + 1) * NR];
    float acc[4] = {0.0f, 0.0f, 0.0f, 0.0f};
    const size_t base = (size_t)lane * 4;

    int j = s;
    for (; j + 3 < e; j += 4) {
        int s0 = csr_src[j],     s1 = csr_src[j + 1];
        int s2 = csr_src[j + 2], s3 = csr_src[j + 3];
        float w0 = csr_w[j],     w1 = csr_w[j + 1];
        float w2 = csr_w[j + 2], w3 = csr_w[j + 3];
        unsigned int q0 = *(const unsigned int*)(hw + (size_t)s0 * dfeat + base);
        unsigned int q1 = *(const unsigned int*)(hw + (size_t)s1 * dfeat + base);
        unsigned int q2 = *(const unsigned int*)(hw + (size_t)s2 * dfeat + base);
        unsigned int q3 = *(const unsigned int*)(hw + (size_t)s3 * dfeat + base);
        fma_unpack_f8(q0, w0, acc);
        fma_unpack_f8(q1, w1, acc);
        fma_unpack_f8(q2, w2, acc);
        fma_unpack_f8(q3, w3, acc);
    }
    for (; j < e; ++j) {
        int s0 = csr_src[j];
        float w0 = csr_w[j];
        unsigned int q0 = *(const unsigned int*)(hw + (size_t)s0 * dfeat + base);
        fma_unpack_f8(q0, w0, acc);
    }

    #pragma unroll
    for (int i = 0; i < 4; ++i) {
        int f = (int)base + i;
        float a = acc[i];
        if (mode != 0) {
            a += bias[f];
            if (mode == 1) {
                float scale = g[f] * rsqrtf(v[f] + BN_EPS);
                a = (a - m[f]) * scale + be[f];
            }
            a = 1.0f / (1.0f + __expf(-a));
        }
        out[(size_t)node * dfeat + f] = __float2bfloat16(a);
    }
}

// ---------------- final h^T h via MFMA ----------------
#define TPAD 8

__global__ __launch_bounds__(256) void htht_mfma_kernel(
    const bf16* __restrict__ h, float* __restrict__ partial, int n) {
    __shared__ bf16 hsT[128][32 + TPAD];
    int b = blockIdx.x;
    int tid = threadIdx.x;
    int wave = tid >> 6, lane = tid & 63;
    int lrow = lane & 15, quad = lane >> 4;

    f32x4 acc[2][8] = {};

    int kk = tid >> 3;
    int seg = tid & 7;

    for (int kt = 0; kt < 8; ++kt) {
        int k0 = b * 256 + kt * 32;
        #pragma unroll
        for (int s2 = 0; s2 < 2; ++s2) {
            int fs = (seg + s2 * 8) * 8;
            int gk = k0 + kk;
            uint4 q; q.x = q.y = q.z = q.w = 0u;
            if (gk < n) q = *(const uint4*)(h + (size_t)gk * 128 + fs);
            const unsigned short* u = (const unsigned short*)&q;
            #pragma unroll
            for (int i = 0; i < 8; ++i)
                *((unsigned short*)&hsT[fs + i][kk]) = u[i];
        }
        __syncthreads();
        short8 af0 = *(const short8*)(&hsT[wave * 32 + lrow][quad * 8]);
        short8 af1 = *(const short8*)(&hsT[wave * 32 + 16 + lrow][quad * 8]);
        #pragma unroll
        for (int t = 0; t < 8; ++t) {
            short8 bfrag = *(const short8*)(&hsT[t * 16 + lrow][quad * 8]);
            acc[0][t] = __builtin_amdgcn_mfma_f32_16x16x32_bf16(af0, bfrag, acc[0][t], 0, 0, 0);
            acc[1][t] = __builtin_amdgcn_mfma_f32_16x16x32_bf16(af1, bfrag, acc[1][t], 0, 0, 0);
        }
        __syncthreads();
    }
    float* p = partial + (size_t)b * 16384;
    #pragma unroll
    for (int a_ = 0; a_ < 2; ++a_) {
        #pragma unroll
        for (int t = 0; t < 8; ++t) {
            #pragma unroll
            for (int rr = 0; rr < 4; ++rr) {
                int gm = wave * 32 + a_ * 16 + quad * 4 + rr;
                int gn = t * 16 + lrow;
                p[gm * 128 + gn] = acc[a_][t][rr];
            }
        }
    }
}

__global__ void reduce_kernel(const float* __restrict__ partial, float* __restrict__ out, int nchunks) {
    int idx = blockIdx.x * blockDim.x + threadIdx.x;
    float s = 0.0f;
    for (int c = 0; c < nchunks; ++c) s += partial[(size_t)c * 16384 + idx];
    int i = idx / 128, j = idx % 128;
    out[idx] = (i == j) ? 0.0f : s;
}

// ---------------- launch ----------------
extern "C" void kernel_launch(void* const* d_in, const int* in_sizes, int n_in,
                              void* d_out, int out_size, void* d_ws, size_t ws_size,
                              hipStream_t stream) {
    const float* x  = (const float*)d_in[0];
    const int*   ei = (const int*)d_in[1];
    const float* ea = (const float*)d_in[2];
    const float* W[5];  const float* bvec[5];
    for (int l = 0; l < 5; ++l) { W[l] = (const float*)d_in[3 + 2 * l]; bvec[l] = (const float*)d_in[4 + 2 * l]; }
    const float* g[4]; const float* be[4]; const float* mm[4]; const float* vv[4];
    for (int l = 0; l < 4; ++l) {
        g[l]  = (const float*)d_in[13 + 4 * l];
        be[l] = (const float*)d_in[14 + 4 * l];
        mm[l] = (const float*)d_in[15 + 4 * l];
        vv[l] = (const float*)d_in[16 + 4 * l];
    }
    const int n = in_sizes[0] / NSF;        // 20000
    const int E = in_sizes[1] / 2;          // 500000
    const int EN = E + n;
    const int rsize = (n + NR - 1) / NR;
    const int total = n * NR;
    const int nscan = (total + SCK - 1) / SCK;
    const int dims[6] = {128, 256, 512, 256, 128, 128};
    const int wtoff[5] = {0, 32768, 163840, 294912, 327680};
    const int wtelems = 344064;

    // workspace layout (256B aligned); ~62 MB
    auto align = [](size_t o) { return (o + 255) & ~(size_t)255; };
    size_t off = 0;
    float* deg     = (float*)((char*)d_ws + off); off = align(off + (size_t)n * 4);
    float* dinv    = (float*)((char*)d_ws + off); off = align(off + (size_t)n * 4);
    int*   cnt     = (int*)  ((char*)d_ws + off); off = align(off + (size_t)total * 4);
    int*   fill    = (int*)  ((char*)d_ws + off); off = align(off + (size_t)total * 4);
    int*   row_ptr = (int*)  ((char*)d_ws + off); off = align(off + ((size_t)total + 1) * 4);
    int*   blksum  = (int*)  ((char*)d_ws + off); off = align(off + (size_t)256 * 4);
    int*   csr_src = (int*)  ((char*)d_ws + off); off = align(off + (size_t)EN * 4);
    float* csr_w   = (float*)((char*)d_ws + off); off = align(off + (size_t)EN * 4);
    bf16*  wtbuf   = (bf16*) ((char*)d_ws + off); off = align(off + (size_t)wtelems * 2);
    bf16*  hbuf    = (bf16*) ((char*)d_ws + off); off = align(off + (size_t)n * 512 * 2);
    bf16*  abuf    = (bf16*) ((char*)d_ws + off); off = align(off + (size_t)n * 512 * 2);
    fp8*   f8buf   = (fp8*)  ((char*)d_ws + off); off = align(off + (size_t)n * 256);
    const int KCH = (20000 + 255) / 256;    // 79
    float* partial = (float*)((char*)d_ws + off); off = align(off + (size_t)KCH * 16384 * 4);

    // graph prep
    zero_kernel<<<(total + 255) / 256, 256, 0, stream>>>(deg, cnt, fill, n);
    count_kernel<<<(EN + 255) / 256, 256, 0, stream>>>(ei, ea, deg, cnt, E, n, rsize);
    dinv_kernel<<<(n + 255) / 256, 256, 0, stream>>>(deg, dinv, n);
    scan1_kernel<<<nscan, 256, 0, stream>>>(cnt, blksum, total);
    scan2_kernel<<<1, 256, 0, stream>>>(blksum, row_ptr, nscan, total);
    scan3_kernel<<<nscan, 256, 0, stream>>>(cnt, blksum, row_ptr, total);
    fill_kernel<<<(EN + 255) / 256, 256, 0, stream>>>(ei, ea, dinv, row_ptr, fill, csr_src, csr_w, E, n, rsize);

    // dtype prep
    cvt_kernel<<<(n * 128 + 255) / 256, 256, 0, stream>>>(x, hbuf, n * 128);
    for (int l = 0; l < 5; ++l) {
        int K = dims[l], N = dims[l + 1];
        wt_kernel<<<(K * N + 255) / 256, 256, 0, stream>>>(W[l], wtbuf + wtoff[l], K, N);
    }

    int ablocks = (n + 3) / 4;
    auto gemm_bf16 = [&](const bf16* A, int l, bf16* C, int mode) {
        int K = dims[l], N = dims[l + 1];
        dim3 gg((n + 63) / 64, N / 128);
        int bi = (l < 4) ? l : 0;
        mfma_gemm_kernel<bf16><<<gg, 256, 0, stream>>>(A, wtbuf + wtoff[l], C, n, K, N, mode,
                                                       bvec[l], g[bi], be[bi], mm[bi], vv[bi]);
    };
    auto gemm_fp8 = [&](const bf16* A, int l, fp8* C, int mode) {
        int K = dims[l], N = dims[l + 1];
        dim3 gg((n + 63) / 64, N / 128);
        int bi = (l < 4) ? l : 0;
        mfma_gemm_kernel<fp8><<<gg, 256, 0, stream>>>(A, wtbuf + wtoff[l], C, n, K, N, mode,
                                                      bvec[l], g[bi], be[bi], mm[bi], vv[bi]);
    };

    // L1 (128->256): agg-first bf16 128 (x), GEMM1 fused act -> fp8 h1
    agg_vec_kernel<2><<<ablocks, 256, 0, stream>>>(hbuf, row_ptr, csr_src, csr_w,
        bvec[0], bvec[0], bvec[0], bvec[0], bvec[0], abuf, n, 0);
    gemm_fp8(abuf, 0, f8buf, 1);
    // L2 (256->512): agg-first fp8 256 (h1), GEMM2 fused act -> bf16 h2 (512)
    agg_fp8_kernel<<<ablocks, 256, 0, stream>>>(f8buf, row_ptr, csr_src, csr_w,
        bvec[1], bvec[1], bvec[1], bvec[1], bvec[1], abuf, n, 0);
    gemm_bf16(abuf, 1, hbuf, 1);
    // L3 (512->256): GEMM3 raw -> fp8 hw3, agg-last fp8 256 with bias+BN+sigmoid -> bf16 h3
    gemm_fp8(hbuf, 2, f8buf, 0);
    agg_fp8_kernel<<<ablocks, 256, 0, stream>>>(f8buf, row_ptr, csr_src, csr_w,
        bvec[2], g[2], be[2], mm[2], vv[2], abuf, n, 1);
    // L4 (256->128): GEMM4 raw bf16 -> hw4, agg-last bf16 with bias+BN+sigmoid -> h4
    gemm_bf16(abuf, 3, hbuf, 0);
    agg_vec_kernel<2><<<ablocks, 256, 0, stream>>>(hbuf, row_ptr, csr_src, csr_w,
        bvec[3], g[3], be[3], mm[3], vv[3], abuf, n, 1);
    // L5 (128->128): GEMM5 raw bf16 -> hw5, agg-last with bias+sigmoid -> h5
    gemm_bf16(abuf, 4, hbuf, 0);
    agg_vec_kernel<2><<<ablocks, 256, 0, stream>>>(hbuf, row_ptr, csr_src, csr_w,
        bvec[4], bvec[4], bvec[4], bvec[4], bvec[4], abuf, n, 2);

    // final h^T h with zeroed diagonal (MFMA)
    htht_mfma_kernel<<<KCH, 256, 0, stream>>>(abuf, partial, n);
    reduce_kernel<<<16384 / 256, 256, 0, stream>>>(partial, (float*)d_out, KCH);
}

// Round 10
// 453.659 us; speedup vs baseline: 1.3831x; 1.0750x over previous
//
#include <hip/hip_runtime.h>
#include <hip/hip_bf16.h>
#include <hip/hip_fp8.h>
#include <cstdint>
#include <cstddef>

typedef __hip_bfloat16 bf16;
typedef unsigned char fp8;                                  // e4m3 storage
typedef __attribute__((ext_vector_type(8))) short short8;   // 8 bf16 (MFMA A/B frag)
typedef __attribute__((ext_vector_type(4))) float f32x4;    // MFMA C/D frag

#define NSF 128
#define BN_EPS 1e-3f
#define NR 4            // src ranges per node
#define SCK 2048        // elements per scan block

// ---------------- CSR build: 1 atomic per edge ----------------

__global__ void zero_fill_kernel(int* __restrict__ fill, int total) {
    int i = blockIdx.x * blockDim.x + threadIdx.x;
    if (i < total) fill[i] = 0;
}

// passA: the only atomic pass. loc[idx] = slot-local position.
__global__ void passA_kernel(const int* __restrict__ ei, int* __restrict__ fill,
                             int* __restrict__ loc, int E, int n, int rsize) {
    int idx = blockIdx.x * blockDim.x + threadIdx.x;
    if (idx < E) {
        int r = ei[idx];
        int c = ei[E + idx];
        int slot = c * NR + r / rsize;
        loc[idx] = atomicAdd(&fill[slot], 1);
    } else if (idx < E + n) {
        int i = idx - E;
        int slot = i * NR + i / rsize;
        loc[idx] = atomicAdd(&fill[slot], 1);
    }
}

// ---- hierarchical exclusive scan of fill -> row_ptr ----

__global__ void scan1_kernel(const int* __restrict__ cnt, int* __restrict__ blksum, int total) {
    __shared__ int red[256];
    int base = blockIdx.x * SCK + threadIdx.x * 8;
    int s = 0;
    #pragma unroll
    for (int i = 0; i < 8; ++i) {
        int idx = base + i;
        if (idx < total) s += cnt[idx];
    }
    red[threadIdx.x] = s;
    __syncthreads();
    for (int off2 = 128; off2 > 0; off2 >>= 1) {
        if (threadIdx.x < off2) red[threadIdx.x] += red[threadIdx.x + off2];
        __syncthreads();
    }
    if (threadIdx.x == 0) blksum[blockIdx.x] = red[0];
}

__global__ void scan2_kernel(int* __restrict__ blksum, int* __restrict__ row_ptr,
                             int nblk, int total) {
    __shared__ int part[256];
    int tid = threadIdx.x;
    int v = (tid < nblk) ? blksum[tid] : 0;
    part[tid] = v;
    __syncthreads();
    for (int off2 = 1; off2 < 256; off2 <<= 1) {
        int t = (tid >= off2) ? part[tid - off2] : 0;
        __syncthreads();
        part[tid] += t;
        __syncthreads();
    }
    if (tid < nblk) blksum[tid] = part[tid] - v;
    if (tid == 255) row_ptr[total] = part[255];
}

__global__ void scan3_kernel(const int* __restrict__ cnt, const int* __restrict__ blkoff,
                             int* __restrict__ row_ptr, int total) {
    __shared__ int part[256];
    int tid = threadIdx.x;
    int base = blockIdx.x * SCK + tid * 8;
    int loc[8]; int s = 0;
    #pragma unroll
    for (int i = 0; i < 8; ++i) {
        int idx = base + i;
        loc[i] = (idx < total) ? cnt[idx] : 0;
        s += loc[i];
    }
    part[tid] = s;
    __syncthreads();
    for (int off2 = 1; off2 < 256; off2 <<= 1) {
        int t = (tid >= off2) ? part[tid - off2] : 0;
        __syncthreads();
        part[tid] += t;
        __syncthreads();
    }
    int run = blkoff[blockIdx.x] + part[tid] - s;
    #pragma unroll
    for (int i = 0; i < 8; ++i) {
        int idx = base + i;
        if (idx < total) { row_ptr[idx] = run; run += loc[i]; }
    }
}

// passB: scatter without atomics (p unique by construction)
__global__ void passB_kernel(const int* __restrict__ ei, const float* __restrict__ ea,
                             const int* __restrict__ row_ptr, const int* __restrict__ loc,
                             int* __restrict__ csr_src, float* __restrict__ csr_w,
                             int* __restrict__ csr_col, int E, int n, int rsize) {
    int idx = blockIdx.x * blockDim.x + threadIdx.x;
    if (idx < E) {
        int r = ei[idx];
        int c = ei[E + idx];
        int slot = c * NR + r / rsize;
        int p = row_ptr[slot] + loc[idx];
        csr_src[p] = r;
        csr_w[p] = ea[idx];          // raw weight; normalized later
        csr_col[p] = c;
    } else if (idx < E + n) {
        int i = idx - E;
        int slot = i * NR + i / rsize;
        int p = row_ptr[slot] + loc[idx];
        csr_src[p] = i;
        csr_w[p] = 1.0f;
        csr_col[p] = i;
    }
}

// per-node degree from contiguous CSR range (no atomics) -> dinv
__global__ void degdinv_kernel(const int* __restrict__ row_ptr, const float* __restrict__ csr_w,
                               float* __restrict__ dinv, int n) {
    int node = blockIdx.x * blockDim.x + threadIdx.x;
    if (node < n) {
        int s = row_ptr[node * NR], e = row_ptr[(node + 1) * NR];
        float d = 0.0f;
        for (int j = s; j < e; ++j) d += csr_w[j];
        dinv[node] = (d > 0.0f) ? rsqrtf(d) : 0.0f;
    }
}

// per-entry symmetric normalization (in-place)
__global__ void normw_kernel(const float* __restrict__ dinv, const int* __restrict__ csr_src,
                             const int* __restrict__ csr_col, float* __restrict__ csr_w,
                             int EN) {
    int p = blockIdx.x * blockDim.x + threadIdx.x;
    if (p < EN) csr_w[p] = dinv[csr_src[p]] * csr_w[p] * dinv[csr_col[p]];
}

// ---------------- dtype prep ----------------

__global__ void cvt_kernel(const float* __restrict__ x, bf16* __restrict__ y, int count) {
    int i = blockIdx.x * blockDim.x + threadIdx.x;
    if (i < count) y[i] = __float2bfloat16(x[i]);
}

__global__ void wt_kernel(const float* __restrict__ W, bf16* __restrict__ Wt, int K, int N) {
    int idx = blockIdx.x * blockDim.x + threadIdx.x;
    if (idx < K * N) {
        int nn = idx / K, kk = idx % K;
        Wt[idx] = __float2bfloat16(W[(size_t)kk * N + nn]);
    }
}

// ---------------- output-type helpers ----------------

__device__ inline void store_val(bf16* C, size_t idx, float a) {
    C[idx] = __float2bfloat16(a);
}
__device__ inline void store_val(fp8* C, size_t idx, float a) {
    __hip_fp8_e4m3 t(a);
    C[idx] = (fp8)t.__x;
}
__device__ inline float f8f(unsigned int b) {
    __hip_fp8_e4m3 v; v.__x = (__hip_fp8_storage_t)b; return (float)v;
}

// ---------------- MFMA GEMM: C[M,N] = A[M,K] @ Wt[N,K]^T, fused epilogue ----------------
// mode 0: raw store; mode 1: sigmoid(BN(acc+bias))
#define GPAD 8

template <typename OT>
__global__ __launch_bounds__(256) void mfma_gemm_kernel(
    const bf16* __restrict__ A, const bf16* __restrict__ Wt,
    OT* __restrict__ C, int M, int K, int N, int mode,
    const float* __restrict__ bias, const float* __restrict__ g,
    const float* __restrict__ be, const float* __restrict__ m,
    const float* __restrict__ v) {
    __shared__ bf16 As[64][32 + GPAD];
    __shared__ bf16 Bs[128][32 + GPAD];
    int m0 = blockIdx.x * 64;
    int n0 = blockIdx.y * 128;
    int tid = threadIdx.x;
    int wave = tid >> 6, lane = tid & 63;
    int lrow = lane & 15, quad = lane >> 4;

    f32x4 acc[8] = {};

    int r = tid >> 2;
    int seg = tid & 3;

    for (int k0 = 0; k0 < K; k0 += 32) {
        uint4 av; av.x = av.y = av.z = av.w = 0u;
        int gm = m0 + r;
        if (gm < M) av = *(const uint4*)(A + (size_t)gm * K + k0 + seg * 8);
        *(uint4*)(&As[r][seg * 8]) = av;
        *(uint4*)(&Bs[r][seg * 8]) =
            *(const uint4*)(Wt + (size_t)(n0 + r) * K + k0 + seg * 8);
        *(uint4*)(&Bs[r + 64][seg * 8]) =
            *(const uint4*)(Wt + (size_t)(n0 + r + 64) * K + k0 + seg * 8);
        __syncthreads();

        short8 afrag = *(const short8*)(&As[wave * 16 + lrow][quad * 8]);
        #pragma unroll
        for (int t = 0; t < 8; ++t) {
            short8 bfrag = *(const short8*)(&Bs[t * 16 + lrow][quad * 8]);
            acc[t] = __builtin_amdgcn_mfma_f32_16x16x32_bf16(afrag, bfrag, acc[t], 0, 0, 0);
        }
        __syncthreads();
    }
    #pragma unroll
    for (int t = 0; t < 8; ++t) {
        int gn = n0 + t * 16 + lrow;
        float bsc = 0.0f, scale = 1.0f, mean = 0.0f, beta = 0.0f;
        if (mode == 1) {
            bsc = bias[gn];
            scale = g[gn] * rsqrtf(v[gn] + BN_EPS);
            mean = m[gn];
            beta = be[gn];
        }
        #pragma unroll
        for (int rr = 0; rr < 4; ++rr) {
            int gm = m0 + wave * 16 + quad * 4 + rr;
            if (gm < M) {
                float a = acc[t][rr];
                if (mode == 1) {
                    a = (a + bsc - mean) * scale + beta;
                    a = 1.0f / (1.0f + __expf(-a));
                }
                store_val(C, (size_t)gm * N + gn, a);
            }
        }
    }
}

// ---------------- bf16 vectorized aggregation ----------------

__device__ inline float bfu(unsigned int u16) {
    union { unsigned int u; float f; } c; c.u = u16 << 16; return c.f;
}
__device__ inline void fma_unpack(unsigned int q, float w, float* acc) {
    acc[0] += w * bfu(q & 0xffffu);
    acc[1] += w * bfu(q >> 16);
}
__device__ inline void fma_unpack(uint2 q, float w, float* acc) {
    fma_unpack(q.x, w, acc); fma_unpack(q.y, w, acc + 2);
}

template <int VEC> struct UVec;
template <> struct UVec<2> { typedef unsigned int T; };
template <> struct UVec<4> { typedef uint2 T; };

template <int VEC>
__global__ __launch_bounds__(256) void agg_vec_kernel(
    const bf16* __restrict__ hw,
    const int* __restrict__ row_ptr,
    const int* __restrict__ csr_src, const float* __restrict__ csr_w,
    const float* __restrict__ bias,
    const float* __restrict__ g, const float* __restrict__ be,
    const float* __restrict__ m, const float* __restrict__ v,
    bf16* __restrict__ out, int n, int mode) {
    typedef typename UVec<VEC>::T T;
    const int dfeat = VEC * 64;
    int wave = threadIdx.x >> 6;
    int lane = threadIdx.x & 63;
    int node = blockIdx.x * 4 + wave;
    if (node >= n) return;
    int s = row_ptr[node * NR], e = row_ptr[(node + 1) * NR];
    float acc[VEC];
    #pragma unroll
    for (int i = 0; i < VEC; ++i) acc[i] = 0.0f;
    const size_t base = (size_t)lane * VEC;

    int j = s;
    for (; j + 3 < e; j += 4) {
        int s0 = csr_src[j],     s1 = csr_src[j + 1];
        int s2 = csr_src[j + 2], s3 = csr_src[j + 3];
        float w0 = csr_w[j],     w1 = csr_w[j + 1];
        float w2 = csr_w[j + 2], w3 = csr_w[j + 3];
        T q0 = *(const T*)(hw + (size_t)s0 * dfeat + base);
        T q1 = *(const T*)(hw + (size_t)s1 * dfeat + base);
        T q2 = *(const T*)(hw + (size_t)s2 * dfeat + base);
        T q3 = *(const T*)(hw + (size_t)s3 * dfeat + base);
        fma_unpack(q0, w0, acc);
        fma_unpack(q1, w1, acc);
        fma_unpack(q2, w2, acc);
        fma_unpack(q3, w3, acc);
    }
    for (; j < e; ++j) {
        int s0 = csr_src[j];
        float w0 = csr_w[j];
        T q0 = *(const T*)(hw + (size_t)s0 * dfeat + base);
        fma_unpack(q0, w0, acc);
    }

    #pragma unroll
    for (int i = 0; i < VEC; ++i) {
        int f = (int)base + i;
        float a = acc[i];
        if (mode != 0) {
            a += bias[f];
            if (mode == 1) {
                float scale = g[f] * rsqrtf(v[f] + BN_EPS);
                a = (a - m[f]) * scale + be[f];
            }
            a = 1.0f / (1.0f + __expf(-a));
        }
        out[(size_t)node * dfeat + f] = __float2bfloat16(a);
    }
}

// ---------------- fp8 aggregation: lane loads VEC fp8 (dfeat = 64*VEC) ----------------

template <int VEC> struct F8Vec;
template <> struct F8Vec<2> { typedef unsigned short T; };
template <> struct F8Vec<4> { typedef unsigned int T; };

__device__ inline void fma_f8(unsigned short q, float w, float* acc) {
    acc[0] += w * f8f(q & 0xffu);
    acc[1] += w * f8f(q >> 8);
}
__device__ inline void fma_f8(unsigned int q, float w, float* acc) {
    acc[0] += w * f8f(q & 0xffu);
    acc[1] += w * f8f((q >> 8) & 0xffu);
    acc[2] += w * f8f((q >> 16) & 0xffu);
    acc[3] += w * f8f(q >> 24);
}

template <int VEC>
__global__ __launch_bounds__(256) void agg_fp8_kernel(
    const fp8* __restrict__ hw,
    const int* __restrict__ row_ptr,
    const int* __restrict__ csr_src, const float* __restrict__ csr_w,
    const float* __restrict__ bias,
    const float* __restrict__ g, const float* __restrict__ be,
    const float* __restrict__ m, const float* __restrict__ v,
    bf16* __restrict__ out, int n, int mode) {
    typedef typename F8Vec<VEC>::T T;
    const int dfeat = VEC * 64;
    int wave = threadIdx.x >> 6;
    int lane = threadIdx.x & 63;
    int node = blockIdx.x * 4 + wave;
    if (node >= n) return;
    int s = row_ptr[node * NR], e = row_ptr[(node + 1) * NR];
    float acc[VEC];
    #pragma unroll
    for (int i = 0; i < VEC; ++i) acc[i] = 0.0f;
    const size_t base = (size_t)lane * VEC;

    int j = s;
    for (; j + 3 < e; j += 4) {
        int s0 = csr_src[j],     s1 = csr_src[j + 1];
        int s2 = csr_src[j + 2], s3 = csr_src[j + 3];
        float w0 = csr_w[j],     w1 = csr_w[j + 1];
        float w2 = csr_w[j + 2], w3 = csr_w[j + 3];
        T q0 = *(const T*)(hw + (size_t)s0 * dfeat + base);
        T q1 = *(const T*)(hw + (size_t)s1 * dfeat + base);
        T q2 = *(const T*)(hw + (size_t)s2 * dfeat + base);
        T q3 = *(const T*)(hw + (size_t)s3 * dfeat + base);
        fma_f8(q0, w0, acc);
        fma_f8(q1, w1, acc);
        fma_f8(q2, w2, acc);
        fma_f8(q3, w3, acc);
    }
    for (; j < e; ++j) {
        int s0 = csr_src[j];
        float w0 = csr_w[j];
        T q0 = *(const T*)(hw + (size_t)s0 * dfeat + base);
        fma_f8(q0, w0, acc);
    }

    #pragma unroll
    for (int i = 0; i < VEC; ++i) {
        int f = (int)base + i;
        float a = acc[i];
        if (mode != 0) {
            a += bias[f];
            if (mode == 1) {
                float scale = g[f] * rsqrtf(v[f] + BN_EPS);
                a = (a - m[f]) * scale + be[f];
            }
            a = 1.0f / (1.0f + __expf(-a));
        }
        out[(size_t)node * dfeat + f] = __float2bfloat16(a);
    }
}

// ---------------- final h^T h via MFMA ----------------
#define TPAD 8

__global__ __launch_bounds__(256) void htht_mfma_kernel(
    const bf16* __restrict__ h, float* __restrict__ partial, int n) {
    __shared__ bf16 hsT[128][32 + TPAD];
    int b = blockIdx.x;
    int tid = threadIdx.x;
    int wave = tid >> 6, lane = tid & 63;
    int lrow = lane & 15, quad = lane >> 4;

    f32x4 acc[2][8] = {};

    int kk = tid >> 3;
    int seg = tid & 7;

    for (int kt = 0; kt < 8; ++kt) {
        int k0 = b * 256 + kt * 32;
        #pragma unroll
        for (int s2 = 0; s2 < 2; ++s2) {
            int fs = (seg + s2 * 8) * 8;
            int gk = k0 + kk;
            uint4 q; q.x = q.y = q.z = q.w = 0u;
            if (gk < n) q = *(const uint4*)(h + (size_t)gk * 128 + fs);
            const unsigned short* u = (const unsigned short*)&q;
            #pragma unroll
            for (int i = 0; i < 8; ++i)
                *((unsigned short*)&hsT[fs + i][kk]) = u[i];
        }
        __syncthreads();
        short8 af0 = *(const short8*)(&hsT[wave * 32 + lrow][quad * 8]);
        short8 af1 = *(const short8*)(&hsT[wave * 32 + 16 + lrow][quad * 8]);
        #pragma unroll
        for (int t = 0; t < 8; ++t) {
            short8 bfrag = *(const short8*)(&hsT[t * 16 + lrow][quad * 8]);
            acc[0][t] = __builtin_amdgcn_mfma_f32_16x16x32_bf16(af0, bfrag, acc[0][t], 0, 0, 0);
            acc[1][t] = __builtin_amdgcn_mfma_f32_16x16x32_bf16(af1, bfrag, acc[1][t], 0, 0, 0);
        }
        __syncthreads();
    }
    float* p = partial + (size_t)b * 16384;
    #pragma unroll
    for (int a_ = 0; a_ < 2; ++a_) {
        #pragma unroll
        for (int t = 0; t < 8; ++t) {
            #pragma unroll
            for (int rr = 0; rr < 4; ++rr) {
                int gm = wave * 32 + a_ * 16 + quad * 4 + rr;
                int gn = t * 16 + lrow;
                p[gm * 128 + gn] = acc[a_][t][rr];
            }
        }
    }
}

__global__ void reduce_kernel(const float* __restrict__ partial, float* __restrict__ out, int nchunks) {
    int idx = blockIdx.x * blockDim.x + threadIdx.x;
    float s = 0.0f;
    for (int c = 0; c < nchunks; ++c) s += partial[(size_t)c * 16384 + idx];
    int i = idx / 128, j = idx % 128;
    out[idx] = (i == j) ? 0.0f : s;
}

// ---------------- launch ----------------
extern "C" void kernel_launch(void* const* d_in, const int* in_sizes, int n_in,
                              void* d_out, int out_size, void* d_ws, size_t ws_size,
                              hipStream_t stream) {
    const float* x  = (const float*)d_in[0];
    const int*   ei = (const int*)d_in[1];
    const float* ea = (const float*)d_in[2];
    const float* W[5];  const float* bvec[5];
    for (int l = 0; l < 5; ++l) { W[l] = (const float*)d_in[3 + 2 * l]; bvec[l] = (const float*)d_in[4 + 2 * l]; }
    const float* g[4]; const float* be[4]; const float* mm[4]; const float* vv[4];
    for (int l = 0; l < 4; ++l) {
        g[l]  = (const float*)d_in[13 + 4 * l];
        be[l] = (const float*)d_in[14 + 4 * l];
        mm[l] = (const float*)d_in[15 + 4 * l];
        vv[l] = (const float*)d_in[16 + 4 * l];
    }
    const int n = in_sizes[0] / NSF;        // 20000
    const int E = in_sizes[1] / 2;          // 500000
    const int EN = E + n;
    const int rsize = (n + NR - 1) / NR;
    const int total = n * NR;
    const int nscan = (total + SCK - 1) / SCK;
    const int dims[6] = {128, 256, 512, 256, 128, 128};
    const int wtoff[5] = {0, 32768, 163840, 294912, 327680};
    const int wtelems = 344064;

    // workspace layout (256B aligned); ~66 MB
    auto align = [](size_t o) { return (o + 255) & ~(size_t)255; };
    size_t off = 0;
    float* dinv    = (float*)((char*)d_ws + off); off = align(off + (size_t)n * 4);
    int*   fill    = (int*)  ((char*)d_ws + off); off = align(off + (size_t)total * 4);
    int*   row_ptr = (int*)  ((char*)d_ws + off); off = align(off + ((size_t)total + 1) * 4);
    int*   blksum  = (int*)  ((char*)d_ws + off); off = align(off + (size_t)256 * 4);
    int*   locb    = (int*)  ((char*)d_ws + off); off = align(off + (size_t)EN * 4);
    int*   csr_src = (int*)  ((char*)d_ws + off); off = align(off + (size_t)EN * 4);
    int*   csr_col = (int*)  ((char*)d_ws + off); off = align(off + (size_t)EN * 4);
    float* csr_w   = (float*)((char*)d_ws + off); off = align(off + (size_t)EN * 4);
    bf16*  wtbuf   = (bf16*) ((char*)d_ws + off); off = align(off + (size_t)wtelems * 2);
    bf16*  hbuf    = (bf16*) ((char*)d_ws + off); off = align(off + (size_t)n * 512 * 2);
    bf16*  abuf    = (bf16*) ((char*)d_ws + off); off = align(off + (size_t)n * 512 * 2);
    fp8*   f8buf   = (fp8*)  ((char*)d_ws + off); off = align(off + (size_t)n * 256);
    const int KCH = (20000 + 255) / 256;    // 79
    float* partial = (float*)((char*)d_ws + off); off = align(off + (size_t)KCH * 16384 * 4);

    // CSR build (1 atomic/edge)
    zero_fill_kernel<<<(total + 255) / 256, 256, 0, stream>>>(fill, total);
    passA_kernel<<<(EN + 255) / 256, 256, 0, stream>>>(ei, fill, locb, E, n, rsize);
    scan1_kernel<<<nscan, 256, 0, stream>>>(fill, blksum, total);
    scan2_kernel<<<1, 256, 0, stream>>>(blksum, row_ptr, nscan, total);
    scan3_kernel<<<nscan, 256, 0, stream>>>(fill, blksum, row_ptr, total);
    passB_kernel<<<(EN + 255) / 256, 256, 0, stream>>>(ei, ea, row_ptr, locb,
                                                       csr_src, csr_w, csr_col, E, n, rsize);
    degdinv_kernel<<<(n + 255) / 256, 256, 0, stream>>>(row_ptr, csr_w, dinv, n);
    normw_kernel<<<(EN + 255) / 256, 256, 0, stream>>>(dinv, csr_src, csr_col, csr_w, EN);

    // dtype prep
    cvt_kernel<<<(n * 128 + 255) / 256, 256, 0, stream>>>(x, hbuf, n * 128);
    for (int l = 0; l < 5; ++l) {
        int K = dims[l], N = dims[l + 1];
        wt_kernel<<<(K * N + 255) / 256, 256, 0, stream>>>(W[l], wtbuf + wtoff[l], K, N);
    }

    int ablocks = (n + 3) / 4;
    auto gemm_bf16 = [&](const bf16* A, int l, bf16* C, int mode) {
        int K = dims[l], N = dims[l + 1];
        dim3 gg((n + 63) / 64, N / 128);
        int bi = (l < 4) ? l : 0;
        mfma_gemm_kernel<bf16><<<gg, 256, 0, stream>>>(A, wtbuf + wtoff[l], C, n, K, N, mode,
                                                       bvec[l], g[bi], be[bi], mm[bi], vv[bi]);
    };
    auto gemm_fp8 = [&](const bf16* A, int l, fp8* C, int mode) {
        int K = dims[l], N = dims[l + 1];
        dim3 gg((n + 63) / 64, N / 128);
        int bi = (l < 4) ? l : 0;
        mfma_gemm_kernel<fp8><<<gg, 256, 0, stream>>>(A, wtbuf + wtoff[l], C, n, K, N, mode,
                                                      bvec[l], g[bi], be[bi], mm[bi], vv[bi]);
    };

    // L1 (128->256): agg-first bf16 128 (x), GEMM1 fused act -> fp8 h1
    agg_vec_kernel<2><<<ablocks, 256, 0, stream>>>(hbuf, row_ptr, csr_src, csr_w,
        bvec[0], bvec[0], bvec[0], bvec[0], bvec[0], abuf, n, 0);
    gemm_fp8(abuf, 0, f8buf, 1);
    // L2 (256->512): agg-first fp8 256 (h1) -> bf16, GEMM2 fused act -> bf16 h2 (512)
    agg_fp8_kernel<4><<<ablocks, 256, 0, stream>>>(f8buf, row_ptr, csr_src, csr_w,
        bvec[1], bvec[1], bvec[1], bvec[1], bvec[1], abuf, n, 0);
    gemm_bf16(abuf, 1, hbuf, 1);
    // L3 (512->256): GEMM3 raw -> fp8 hw3, agg-last fp8 256 + bias+BN+sigmoid -> bf16 h3
    gemm_fp8(hbuf, 2, f8buf, 0);
    agg_fp8_kernel<4><<<ablocks, 256, 0, stream>>>(f8buf, row_ptr, csr_src, csr_w,
        bvec[2], g[2], be[2], mm[2], vv[2], abuf, n, 1);
    // L4 (256->128): GEMM4 raw -> fp8 hw4, agg-last fp8 128 + bias+BN+sigmoid -> bf16 h4
    gemm_fp8(abuf, 3, f8buf, 0);
    agg_fp8_kernel<2><<<ablocks, 256, 0, stream>>>(f8buf, row_ptr, csr_src, csr_w,
        bvec[3], g[3], be[3], mm[3], vv[3], hbuf, n, 1);
    // L5 (128->128): GEMM5 raw -> fp8 hw5, agg-last fp8 128 + bias+sigmoid -> bf16 h5
    gemm_fp8(hbuf, 4, f8buf, 0);
    agg_fp8_kernel<2><<<ablocks, 256, 0, stream>>>(f8buf, row_ptr, csr_src, csr_w,
        bvec[4], bvec[4], bvec[4], bvec[4], bvec[4], abuf, n, 2);

    // final h^T h with zeroed diagonal (MFMA)
    htht_mfma_kernel<<<KCH, 256, 0, stream>>>(abuf, partial, n);
    reduce_kernel<<<16384 / 256, 256, 0, stream>>>(partial, (float*)d_out, KCH);
}

// Round 11
// 447.045 us; speedup vs baseline: 1.4036x; 1.0148x over previous
//
#include <hip/hip_runtime.h>
#include <hip/hip_bf16.h>
#include <hip/hip_fp8.h>
#include <cstdint>
#include <cstddef>

typedef __hip_bfloat16 bf16;
typedef unsigned char fp8;                                  // e4m3 storage
typedef __attribute__((ext_vector_type(8))) short short8;   // 8 bf16 (MFMA A/B frag)
typedef __attribute__((ext_vector_type(4))) float f32x4;    // MFMA C/D frag
typedef __attribute__((ext_vector_type(2))) float f32x2;

#define NSF 128
#define BN_EPS 1e-3f
#define NR 4            // src ranges per node
#define SCK 2048        // elements per scan block

// ---------------- CSR build: 1 atomic per edge ----------------

__global__ void zero_fill_kernel(int* __restrict__ fill, int total) {
    int i = blockIdx.x * blockDim.x + threadIdx.x;
    if (i < total) fill[i] = 0;
}

__global__ void passA_kernel(const int* __restrict__ ei, int* __restrict__ fill,
                             int* __restrict__ loc, int E, int n, int rsize) {
    int idx = blockIdx.x * blockDim.x + threadIdx.x;
    if (idx < E) {
        int r = ei[idx];
        int c = ei[E + idx];
        int slot = c * NR + r / rsize;
        loc[idx] = atomicAdd(&fill[slot], 1);
    } else if (idx < E + n) {
        int i = idx - E;
        int slot = i * NR + i / rsize;
        loc[idx] = atomicAdd(&fill[slot], 1);
    }
}

// ---- hierarchical exclusive scan of fill -> row_ptr ----

__global__ void scan1_kernel(const int* __restrict__ cnt, int* __restrict__ blksum, int total) {
    __shared__ int red[256];
    int base = blockIdx.x * SCK + threadIdx.x * 8;
    int s = 0;
    #pragma unroll
    for (int i = 0; i < 8; ++i) {
        int idx = base + i;
        if (idx < total) s += cnt[idx];
    }
    red[threadIdx.x] = s;
    __syncthreads();
    for (int off2 = 128; off2 > 0; off2 >>= 1) {
        if (threadIdx.x < off2) red[threadIdx.x] += red[threadIdx.x + off2];
        __syncthreads();
    }
    if (threadIdx.x == 0) blksum[blockIdx.x] = red[0];
}

__global__ void scan2_kernel(int* __restrict__ blksum, int* __restrict__ row_ptr,
                             int nblk, int total) {
    __shared__ int part[256];
    int tid = threadIdx.x;
    int v = (tid < nblk) ? blksum[tid] : 0;
    part[tid] = v;
    __syncthreads();
    for (int off2 = 1; off2 < 256; off2 <<= 1) {
        int t = (tid >= off2) ? part[tid - off2] : 0;
        __syncthreads();
        part[tid] += t;
        __syncthreads();
    }
    if (tid < nblk) blksum[tid] = part[tid] - v;
    if (tid == 255) row_ptr[total] = part[255];
}

__global__ void scan3_kernel(const int* __restrict__ cnt, const int* __restrict__ blkoff,
                             int* __restrict__ row_ptr, int total) {
    __shared__ int part[256];
    int tid = threadIdx.x;
    int base = blockIdx.x * SCK + tid * 8;
    int loc[8]; int s = 0;
    #pragma unroll
    for (int i = 0; i < 8; ++i) {
        int idx = base + i;
        loc[i] = (idx < total) ? cnt[idx] : 0;
        s += loc[i];
    }
    part[tid] = s;
    __syncthreads();
    for (int off2 = 1; off2 < 256; off2 <<= 1) {
        int t = (tid >= off2) ? part[tid - off2] : 0;
        __syncthreads();
        part[tid] += t;
        __syncthreads();
    }
    int run = blkoff[blockIdx.x] + part[tid] - s;
    #pragma unroll
    for (int i = 0; i < 8; ++i) {
        int idx = base + i;
        if (idx < total) { row_ptr[idx] = run; run += loc[i]; }
    }
}

__global__ void passB_kernel(const int* __restrict__ ei, const float* __restrict__ ea,
                             const int* __restrict__ row_ptr, const int* __restrict__ loc,
                             int* __restrict__ csr_src, float* __restrict__ csr_w,
                             int* __restrict__ csr_col, int E, int n, int rsize) {
    int idx = blockIdx.x * blockDim.x + threadIdx.x;
    if (idx < E) {
        int r = ei[idx];
        int c = ei[E + idx];
        int slot = c * NR + r / rsize;
        int p = row_ptr[slot] + loc[idx];
        csr_src[p] = r;
        csr_w[p] = ea[idx];
        csr_col[p] = c;
    } else if (idx < E + n) {
        int i = idx - E;
        int slot = i * NR + i / rsize;
        int p = row_ptr[slot] + loc[idx];
        csr_src[p] = i;
        csr_w[p] = 1.0f;
        csr_col[p] = i;
    }
}

__global__ void degdinv_kernel(const int* __restrict__ row_ptr, const float* __restrict__ csr_w,
                               float* __restrict__ dinv, int n) {
    int node = blockIdx.x * blockDim.x + threadIdx.x;
    if (node < n) {
        int s = row_ptr[node * NR], e = row_ptr[(node + 1) * NR];
        float d = 0.0f;
        for (int j = s; j < e; ++j) d += csr_w[j];
        dinv[node] = (d > 0.0f) ? rsqrtf(d) : 0.0f;
    }
}

__global__ void normw_kernel(const float* __restrict__ dinv, const int* __restrict__ csr_src,
                             const int* __restrict__ csr_col, float* __restrict__ csr_w,
                             int EN) {
    int p = blockIdx.x * blockDim.x + threadIdx.x;
    if (p < EN) csr_w[p] = dinv[csr_src[p]] * csr_w[p] * dinv[csr_col[p]];
}

// ---------------- dtype prep ----------------

__global__ void cvt_kernel(const float* __restrict__ x, bf16* __restrict__ y, int count) {
    int i = blockIdx.x * blockDim.x + threadIdx.x;
    if (i < count) y[i] = __float2bfloat16(x[i]);
}

__global__ void wt_kernel(const float* __restrict__ W, bf16* __restrict__ Wt, int K, int N) {
    int idx = blockIdx.x * blockDim.x + threadIdx.x;
    if (idx < K * N) {
        int nn = idx / K, kk = idx % K;
        Wt[idx] = __float2bfloat16(W[(size_t)kk * N + nn]);
    }
}

// ---------------- output-type helpers (HW fp8 cvt) ----------------

__device__ inline void store_val(bf16* C, size_t idx, float a) {
    C[idx] = __float2bfloat16(a);
}
__device__ inline void store_val(fp8* C, size_t idx, float a) {
    int packed = __builtin_amdgcn_cvt_pk_fp8_f32(a, a, 0, false);
    C[idx] = (fp8)(packed & 0xff);
}

// ---------------- MFMA GEMM: C[M,N] = A[M,K] @ Wt[N,K]^T, fused epilogue ----------------
// mode 0: raw store; mode 1: sigmoid(BN(acc+bias))
#define GPAD 8

template <typename OT>
__global__ __launch_bounds__(256) void mfma_gemm_kernel(
    const bf16* __restrict__ A, const bf16* __restrict__ Wt,
    OT* __restrict__ C, int M, int K, int N, int mode,
    const float* __restrict__ bias, const float* __restrict__ g,
    const float* __restrict__ be, const float* __restrict__ m,
    const float* __restrict__ v) {
    __shared__ bf16 As[64][32 + GPAD];
    __shared__ bf16 Bs[128][32 + GPAD];
    int m0 = blockIdx.x * 64;
    int n0 = blockIdx.y * 128;
    int tid = threadIdx.x;
    int wave = tid >> 6, lane = tid & 63;
    int lrow = lane & 15, quad = lane >> 4;

    f32x4 acc[8] = {};

    int r = tid >> 2;
    int seg = tid & 3;

    for (int k0 = 0; k0 < K; k0 += 32) {
        uint4 av; av.x = av.y = av.z = av.w = 0u;
        int gm = m0 + r;
        if (gm < M) av = *(const uint4*)(A + (size_t)gm * K + k0 + seg * 8);
        *(uint4*)(&As[r][seg * 8]) = av;
        *(uint4*)(&Bs[r][seg * 8]) =
            *(const uint4*)(Wt + (size_t)(n0 + r) * K + k0 + seg * 8);
        *(uint4*)(&Bs[r + 64][seg * 8]) =
            *(const uint4*)(Wt + (size_t)(n0 + r + 64) * K + k0 + seg * 8);
        __syncthreads();

        short8 afrag = *(const short8*)(&As[wave * 16 + lrow][quad * 8]);
        #pragma unroll
        for (int t = 0; t < 8; ++t) {
            short8 bfrag = *(const short8*)(&Bs[t * 16 + lrow][quad * 8]);
            acc[t] = __builtin_amdgcn_mfma_f32_16x16x32_bf16(afrag, bfrag, acc[t], 0, 0, 0);
        }
        __syncthreads();
    }
    #pragma unroll
    for (int t = 0; t < 8; ++t) {
        int gn = n0 + t * 16 + lrow;
        float bsc = 0.0f, scale = 1.0f, mean = 0.0f, beta = 0.0f;
        if (mode == 1) {
            bsc = bias[gn];
            scale = g[gn] * rsqrtf(v[gn] + BN_EPS);
            mean = m[gn];
            beta = be[gn];
        }
        #pragma unroll
        for (int rr = 0; rr < 4; ++rr) {
            int gm = m0 + wave * 16 + quad * 4 + rr;
            if (gm < M) {
                float a = acc[t][rr];
                if (mode == 1) {
                    a = (a + bsc - mean) * scale + beta;
                    a = 1.0f / (1.0f + __expf(-a));
                }
                store_val(C, (size_t)gm * N + gn, a);
            }
        }
    }
}

// ---------------- bf16 vectorized aggregation ----------------

__device__ inline float bfu(unsigned int u16) {
    union { unsigned int u; float f; } c; c.u = u16 << 16; return c.f;
}
__device__ inline void fma_unpack(unsigned int q, float w, float* acc) {
    acc[0] += w * bfu(q & 0xffffu);
    acc[1] += w * bfu(q >> 16);
}
__device__ inline void fma_unpack(uint2 q, float w, float* acc) {
    fma_unpack(q.x, w, acc); fma_unpack(q.y, w, acc + 2);
}

template <int VEC> struct UVec;
template <> struct UVec<2> { typedef unsigned int T; };
template <> struct UVec<4> { typedef uint2 T; };

template <int VEC>
__global__ __launch_bounds__(256) void agg_vec_kernel(
    const bf16* __restrict__ hw,
    const int* __restrict__ row_ptr,
    const int* __restrict__ csr_src, const float* __restrict__ csr_w,
    const float* __restrict__ bias,
    const float* __restrict__ g, const float* __restrict__ be,
    const float* __restrict__ m, const float* __restrict__ v,
    bf16* __restrict__ out, int n, int mode) {
    typedef typename UVec<VEC>::T T;
    const int dfeat = VEC * 64;
    int wave = threadIdx.x >> 6;
    int lane = threadIdx.x & 63;
    int node = blockIdx.x * 4 + wave;
    if (node >= n) return;
    int s = row_ptr[node * NR], e = row_ptr[(node + 1) * NR];
    float acc[VEC];
    #pragma unroll
    for (int i = 0; i < VEC; ++i) acc[i] = 0.0f;
    const size_t base = (size_t)lane * VEC;

    int j = s;
    for (; j + 3 < e; j += 4) {
        int s0 = csr_src[j],     s1 = csr_src[j + 1];
        int s2 = csr_src[j + 2], s3 = csr_src[j + 3];
        float w0 = csr_w[j],     w1 = csr_w[j + 1];
        float w2 = csr_w[j + 2], w3 = csr_w[j + 3];
        T q0 = *(const T*)(hw + (size_t)s0 * dfeat + base);
        T q1 = *(const T*)(hw + (size_t)s1 * dfeat + base);
        T q2 = *(const T*)(hw + (size_t)s2 * dfeat + base);
        T q3 = *(const T*)(hw + (size_t)s3 * dfeat + base);
        fma_unpack(q0, w0, acc);
        fma_unpack(q1, w1, acc);
        fma_unpack(q2, w2, acc);
        fma_unpack(q3, w3, acc);
    }
    for (; j < e; ++j) {
        int s0 = csr_src[j];
        float w0 = csr_w[j];
        T q0 = *(const T*)(hw + (size_t)s0 * dfeat + base);
        fma_unpack(q0, w0, acc);
    }

    #pragma unroll
    for (int i = 0; i < VEC; ++i) {
        int f = (int)base + i;
        float a = acc[i];
        if (mode != 0) {
            a += bias[f];
            if (mode == 1) {
                float scale = g[f] * rsqrtf(v[f] + BN_EPS);
                a = (a - m[f]) * scale + be[f];
            }
            a = 1.0f / (1.0f + __expf(-a));
        }
        out[(size_t)node * dfeat + f] = __float2bfloat16(a);
    }
}

// ---------------- fp8 aggregation with HW cvt: lane loads VEC fp8 ----------------

template <int VEC> struct F8Vec;
template <> struct F8Vec<2> { typedef unsigned short T; };
template <> struct F8Vec<4> { typedef unsigned int T; };

// 2 fp8 -> 2 f32 in one v_cvt_pk_f32_fp8
__device__ inline void fma_f8(unsigned short q, float w, float* acc) {
    f32x2 lo = __builtin_amdgcn_cvt_pk_f32_fp8((unsigned int)q, false);
    acc[0] += w * lo.x;
    acc[1] += w * lo.y;
}
__device__ inline void fma_f8(unsigned int q, float w, float* acc) {
    f32x2 lo = __builtin_amdgcn_cvt_pk_f32_fp8(q, false);
    f32x2 hi = __builtin_amdgcn_cvt_pk_f32_fp8(q, true);
    acc[0] += w * lo.x;
    acc[1] += w * lo.y;
    acc[2] += w * hi.x;
    acc[3] += w * hi.y;
}

template <int VEC>
__global__ __launch_bounds__(256) void agg_fp8_kernel(
    const fp8* __restrict__ hw,
    const int* __restrict__ row_ptr,
    const int* __restrict__ csr_src, const float* __restrict__ csr_w,
    const float* __restrict__ bias,
    const float* __restrict__ g, const float* __restrict__ be,
    const float* __restrict__ m, const float* __restrict__ v,
    bf16* __restrict__ out, int n, int mode) {
    typedef typename F8Vec<VEC>::T T;
    const int dfeat = VEC * 64;
    int wave = threadIdx.x >> 6;
    int lane = threadIdx.x & 63;
    int node = blockIdx.x * 4 + wave;
    if (node >= n) return;
    int s = row_ptr[node * NR], e = row_ptr[(node + 1) * NR];
    float acc[VEC];
    #pragma unroll
    for (int i = 0; i < VEC; ++i) acc[i] = 0.0f;
    const size_t base = (size_t)lane * VEC;

    int j = s;
    for (; j + 3 < e; j += 4) {
        int s0 = csr_src[j],     s1 = csr_src[j + 1];
        int s2 = csr_src[j + 2], s3 = csr_src[j + 3];
        float w0 = csr_w[j],     w1 = csr_w[j + 1];
        float w2 = csr_w[j + 2], w3 = csr_w[j + 3];
        T q0 = *(const T*)(hw + (size_t)s0 * dfeat + base);
        T q1 = *(const T*)(hw + (size_t)s1 * dfeat + base);
        T q2 = *(const T*)(hw + (size_t)s2 * dfeat + base);
        T q3 = *(const T*)(hw + (size_t)s3 * dfeat + base);
        fma_f8(q0, w0, acc);
        fma_f8(q1, w1, acc);
        fma_f8(q2, w2, acc);
        fma_f8(q3, w3, acc);
    }
    for (; j < e; ++j) {
        int s0 = csr_src[j];
        float w0 = csr_w[j];
        T q0 = *(const T*)(hw + (size_t)s0 * dfeat + base);
        fma_f8(q0, w0, acc);
    }

    #pragma unroll
    for (int i = 0; i < VEC; ++i) {
        int f = (int)base + i;
        float a = acc[i];
        if (mode != 0) {
            a += bias[f];
            if (mode == 1) {
                float scale = g[f] * rsqrtf(v[f] + BN_EPS);
                a = (a - m[f]) * scale + be[f];
            }
            a = 1.0f / (1.0f + __expf(-a));
        }
        out[(size_t)node * dfeat + f] = __float2bfloat16(a);
    }
}

// ---------------- final h^T h via MFMA ----------------
#define TPAD 8

__global__ __launch_bounds__(256) void htht_mfma_kernel(
    const bf16* __restrict__ h, float* __restrict__ partial, int n) {
    __shared__ bf16 hsT[128][32 + TPAD];
    int b = blockIdx.x;
    int tid = threadIdx.x;
    int wave = tid >> 6, lane = tid & 63;
    int lrow = lane & 15, quad = lane >> 4;

    f32x4 acc[2][8] = {};

    int kk = tid >> 3;
    int seg = tid & 7;

    for (int kt = 0; kt < 8; ++kt) {
        int k0 = b * 256 + kt * 32;
        #pragma unroll
        for (int s2 = 0; s2 < 2; ++s2) {
            int fs = (seg + s2 * 8) * 8;
            int gk = k0 + kk;
            uint4 q; q.x = q.y = q.z = q.w = 0u;
            if (gk < n) q = *(const uint4*)(h + (size_t)gk * 128 + fs);
            const unsigned short* u = (const unsigned short*)&q;
            #pragma unroll
            for (int i = 0; i < 8; ++i)
                *((unsigned short*)&hsT[fs + i][kk]) = u[i];
        }
        __syncthreads();
        short8 af0 = *(const short8*)(&hsT[wave * 32 + lrow][quad * 8]);
        short8 af1 = *(const short8*)(&hsT[wave * 32 + 16 + lrow][quad * 8]);
        #pragma unroll
        for (int t = 0; t < 8; ++t) {
            short8 bfrag = *(const short8*)(&hsT[t * 16 + lrow][quad * 8]);
            acc[0][t] = __builtin_amdgcn_mfma_f32_16x16x32_bf16(af0, bfrag, acc[0][t], 0, 0, 0);
            acc[1][t] = __builtin_amdgcn_mfma_f32_16x16x32_bf16(af1, bfrag, acc[1][t], 0, 0, 0);
        }
        __syncthreads();
    }
    float* p = partial + (size_t)b * 16384;
    #pragma unroll
    for (int a_ = 0; a_ < 2; ++a_) {
        #pragma unroll
        for (int t = 0; t < 8; ++t) {
            #pragma unroll
            for (int rr = 0; rr < 4; ++rr) {
                int gm = wave * 32 + a_ * 16 + quad * 4 + rr;
                int gn = t * 16 + lrow;
                p[gm * 128 + gn] = acc[a_][t][rr];
            }
        }
    }
}

__global__ void reduce_kernel(const float* __restrict__ partial, float* __restrict__ out, int nchunks) {
    int idx = blockIdx.x * blockDim.x + threadIdx.x;
    float s = 0.0f;
    for (int c = 0; c < nchunks; ++c) s += partial[(size_t)c * 16384 + idx];
    int i = idx / 128, j = idx % 128;
    out[idx] = (i == j) ? 0.0f : s;
}

// ---------------- launch ----------------
extern "C" void kernel_launch(void* const* d_in, const int* in_sizes, int n_in,
                              void* d_out, int out_size, void* d_ws, size_t ws_size,
                              hipStream_t stream) {
    const float* x  = (const float*)d_in[0];
    const int*   ei = (const int*)d_in[1];
    const float* ea = (const float*)d_in[2];
    const float* W[5];  const float* bvec[5];
    for (int l = 0; l < 5; ++l) { W[l] = (const float*)d_in[3 + 2 * l]; bvec[l] = (const float*)d_in[4 + 2 * l]; }
    const float* g[4]; const float* be[4]; const float* mm[4]; const float* vv[4];
    for (int l = 0; l < 4; ++l) {
        g[l]  = (const float*)d_in[13 + 4 * l];
        be[l] = (const float*)d_in[14 + 4 * l];
        mm[l] = (const float*)d_in[15 + 4 * l];
        vv[l] = (const float*)d_in[16 + 4 * l];
    }
    const int n = in_sizes[0] / NSF;        // 20000
    const int E = in_sizes[1] / 2;          // 500000
    const int EN = E + n;
    const int rsize = (n + NR - 1) / NR;
    const int total = n * NR;
    const int nscan = (total + SCK - 1) / SCK;
    const int dims[6] = {128, 256, 512, 256, 128, 128};
    const int wtoff[5] = {0, 32768, 163840, 294912, 327680};
    const int wtelems = 344064;

    // workspace layout (256B aligned); ~66 MB
    auto align = [](size_t o) { return (o + 255) & ~(size_t)255; };
    size_t off = 0;
    float* dinv    = (float*)((char*)d_ws + off); off = align(off + (size_t)n * 4);
    int*   fill    = (int*)  ((char*)d_ws + off); off = align(off + (size_t)total * 4);
    int*   row_ptr = (int*)  ((char*)d_ws + off); off = align(off + ((size_t)total + 1) * 4);
    int*   blksum  = (int*)  ((char*)d_ws + off); off = align(off + (size_t)256 * 4);
    int*   locb    = (int*)  ((char*)d_ws + off); off = align(off + (size_t)EN * 4);
    int*   csr_src = (int*)  ((char*)d_ws + off); off = align(off + (size_t)EN * 4);
    int*   csr_col = (int*)  ((char*)d_ws + off); off = align(off + (size_t)EN * 4);
    float* csr_w   = (float*)((char*)d_ws + off); off = align(off + (size_t)EN * 4);
    bf16*  wtbuf   = (bf16*) ((char*)d_ws + off); off = align(off + (size_t)wtelems * 2);
    bf16*  hbuf    = (bf16*) ((char*)d_ws + off); off = align(off + (size_t)n * 512 * 2);
    bf16*  abuf    = (bf16*) ((char*)d_ws + off); off = align(off + (size_t)n * 512 * 2);
    fp8*   f8buf   = (fp8*)  ((char*)d_ws + off); off = align(off + (size_t)n * 256);
    const int KCH = (20000 + 255) / 256;    // 79
    float* partial = (float*)((char*)d_ws + off); off = align(off + (size_t)KCH * 16384 * 4);

    // CSR build (1 atomic/edge)
    zero_fill_kernel<<<(total + 255) / 256, 256, 0, stream>>>(fill, total);
    passA_kernel<<<(EN + 255) / 256, 256, 0, stream>>>(ei, fill, locb, E, n, rsize);
    scan1_kernel<<<nscan, 256, 0, stream>>>(fill, blksum, total);
    scan2_kernel<<<1, 256, 0, stream>>>(blksum, row_ptr, nscan, total);
    scan3_kernel<<<nscan, 256, 0, stream>>>(fill, blksum, row_ptr, total);
    passB_kernel<<<(EN + 255) / 256, 256, 0, stream>>>(ei, ea, row_ptr, locb,
                                                       csr_src, csr_w, csr_col, E, n, rsize);
    degdinv_kernel<<<(n + 255) / 256, 256, 0, stream>>>(row_ptr, csr_w, dinv, n);
    normw_kernel<<<(EN + 255) / 256, 256, 0, stream>>>(dinv, csr_src, csr_col, csr_w, EN);

    // dtype prep
    cvt_kernel<<<(n * 128 + 255) / 256, 256, 0, stream>>>(x, hbuf, n * 128);
    for (int l = 0; l < 5; ++l) {
        int K = dims[l], N = dims[l + 1];
        wt_kernel<<<(K * N + 255) / 256, 256, 0, stream>>>(W[l], wtbuf + wtoff[l], K, N);
    }

    int ablocks = (n + 3) / 4;
    auto gemm_bf16 = [&](const bf16* A, int l, bf16* C, int mode) {
        int K = dims[l], N = dims[l + 1];
        dim3 gg((n + 63) / 64, N / 128);
        int bi = (l < 4) ? l : 0;
        mfma_gemm_kernel<bf16><<<gg, 256, 0, stream>>>(A, wtbuf + wtoff[l], C, n, K, N, mode,
                                                       bvec[l], g[bi], be[bi], mm[bi], vv[bi]);
    };
    auto gemm_fp8 = [&](const bf16* A, int l, fp8* C, int mode) {
        int K = dims[l], N = dims[l + 1];
        dim3 gg((n + 63) / 64, N / 128);
        int bi = (l < 4) ? l : 0;
        mfma_gemm_kernel<fp8><<<gg, 256, 0, stream>>>(A, wtbuf + wtoff[l], C, n, K, N, mode,
                                                      bvec[l], g[bi], be[bi], mm[bi], vv[bi]);
    };

    // L1 (128->256): agg-first bf16 128 (x), GEMM1 fused act -> fp8 h1
    agg_vec_kernel<2><<<ablocks, 256, 0, stream>>>(hbuf, row_ptr, csr_src, csr_w,
        bvec[0], bvec[0], bvec[0], bvec[0], bvec[0], abuf, n, 0);
    gemm_fp8(abuf, 0, f8buf, 1);
    // L2 (256->512): agg-first fp8 256 (h1) -> bf16, GEMM2 fused act -> bf16 h2 (512)
    agg_fp8_kernel<4><<<ablocks, 256, 0, stream>>>(f8buf, row_ptr, csr_src, csr_w,
        bvec[1], bvec[1], bvec[1], bvec[1], bvec[1], abuf, n, 0);
    gemm_bf16(abuf, 1, hbuf, 1);
    // L3 (512->256): GEMM3 raw -> fp8 hw3, agg-last fp8 256 + bias+BN+sigmoid -> bf16 h3
    gemm_fp8(hbuf, 2, f8buf, 0);
    agg_fp8_kernel<4><<<ablocks, 256, 0, stream>>>(f8buf, row_ptr, csr_src, csr_w,
        bvec[2], g[2], be[2], mm[2], vv[2], abuf, n, 1);
    // L4 (256->128): GEMM4 raw -> fp8 hw4, agg-last fp8 128 + bias+BN+sigmoid -> bf16 h4
    gemm_fp8(abuf, 3, f8buf, 0);
    agg_fp8_kernel<2><<<ablocks, 256, 0, stream>>>(f8buf, row_ptr, csr_src, csr_w,
        bvec[3], g[3], be[3], mm[3], vv[3], hbuf, n, 1);
    // L5 (128->128): GEMM5 raw -> fp8 hw5, agg-last fp8 128 + bias+sigmoid -> bf16 h5
    gemm_fp8(hbuf, 4, f8buf, 0);
    agg_fp8_kernel<2><<<ablocks, 256, 0, stream>>>(f8buf, row_ptr, csr_src, csr_w,
        bvec[4], bvec[4], bvec[4], bvec[4], bvec[4], abuf, n, 2);

    // final h^T h with zeroed diagonal (MFMA)
    htht_mfma_kernel<<<KCH, 256, 0, stream>>>(abuf, partial, n);
    reduce_kernel<<<16384 / 256, 256, 0, stream>>>(partial, (float*)d_out, KCH);
}

// Round 12
// 439.665 us; speedup vs baseline: 1.4271x; 1.0168x over previous
//
#include <hip/hip_runtime.h>
#include <hip/hip_bf16.h>
#include <hip/hip_fp8.h>
#include <cstdint>
#include <cstddef>

typedef __hip_bfloat16 bf16;
typedef unsigned char fp8;                                  // e4m3 storage
typedef __attribute__((ext_vector_type(8))) short short8;   // 8 bf16 (MFMA A/B frag)
typedef __attribute__((ext_vector_type(4))) float f32x4;    // MFMA C/D frag
typedef __attribute__((ext_vector_type(2))) float f32x2;

#define NSF 128
#define BN_EPS 1e-3f
#define NR 4            // src ranges per node
#define SCK 2048        // elements per scan block

// ---------------- CSR build: 1 atomic per edge ----------------

__global__ void zero_fill_kernel(int* __restrict__ fill, int total) {
    int i = blockIdx.x * blockDim.x + threadIdx.x;
    if (i < total) fill[i] = 0;
}

__global__ void passA_kernel(const int* __restrict__ ei, int* __restrict__ fill,
                             int* __restrict__ loc, int E, int n, int rsize) {
    int idx = blockIdx.x * blockDim.x + threadIdx.x;
    if (idx < E) {
        int r = ei[idx];
        int c = ei[E + idx];
        int slot = c * NR + r / rsize;
        loc[idx] = atomicAdd(&fill[slot], 1);
    } else if (idx < E + n) {
        int i = idx - E;
        int slot = i * NR + i / rsize;
        loc[idx] = atomicAdd(&fill[slot], 1);
    }
}

// ---- hierarchical exclusive scan of fill -> row_ptr ----

__global__ void scan1_kernel(const int* __restrict__ cnt, int* __restrict__ blksum, int total) {
    __shared__ int red[256];
    int base = blockIdx.x * SCK + threadIdx.x * 8;
    int s = 0;
    #pragma unroll
    for (int i = 0; i < 8; ++i) {
        int idx = base + i;
        if (idx < total) s += cnt[idx];
    }
    red[threadIdx.x] = s;
    __syncthreads();
    for (int off2 = 128; off2 > 0; off2 >>= 1) {
        if (threadIdx.x < off2) red[threadIdx.x] += red[threadIdx.x + off2];
        __syncthreads();
    }
    if (threadIdx.x == 0) blksum[blockIdx.x] = red[0];
}

__global__ void scan2_kernel(int* __restrict__ blksum, int* __restrict__ row_ptr,
                             int nblk, int total) {
    __shared__ int part[256];
    int tid = threadIdx.x;
    int v = (tid < nblk) ? blksum[tid] : 0;
    part[tid] = v;
    __syncthreads();
    for (int off2 = 1; off2 < 256; off2 <<= 1) {
        int t = (tid >= off2) ? part[tid - off2] : 0;
        __syncthreads();
        part[tid] += t;
        __syncthreads();
    }
    if (tid < nblk) blksum[tid] = part[tid] - v;
    if (tid == 255) row_ptr[total] = part[255];
}

__global__ void scan3_kernel(const int* __restrict__ cnt, const int* __restrict__ blkoff,
                             int* __restrict__ row_ptr, int total) {
    __shared__ int part[256];
    int tid = threadIdx.x;
    int base = blockIdx.x * SCK + tid * 8;
    int loc[8]; int s = 0;
    #pragma unroll
    for (int i = 0; i < 8; ++i) {
        int idx = base + i;
        loc[i] = (idx < total) ? cnt[idx] : 0;
        s += loc[i];
    }
    part[tid] = s;
    __syncthreads();
    for (int off2 = 1; off2 < 256; off2 <<= 1) {
        int t = (tid >= off2) ? part[tid - off2] : 0;
        __syncthreads();
        part[tid] += t;
        __syncthreads();
    }
    int run = blkoff[blockIdx.x] + part[tid] - s;
    #pragma unroll
    for (int i = 0; i < 8; ++i) {
        int idx = base + i;
        if (idx < total) { row_ptr[idx] = run; run += loc[i]; }
    }
}

// passB: scatter without atomics; packed edge record {src, w_bits}
__global__ void passB_kernel(const int* __restrict__ ei, const float* __restrict__ ea,
                             const int* __restrict__ row_ptr, const int* __restrict__ loc,
                             int2* __restrict__ e8, int* __restrict__ csr_col,
                             int E, int n, int rsize) {
    int idx = blockIdx.x * blockDim.x + threadIdx.x;
    if (idx < E) {
        int r = ei[idx];
        int c = ei[E + idx];
        int slot = c * NR + r / rsize;
        int p = row_ptr[slot] + loc[idx];
        int2 rec; rec.x = r; rec.y = __float_as_int(ea[idx]);
        e8[p] = rec;
        csr_col[p] = c;
    } else if (idx < E + n) {
        int i = idx - E;
        int slot = i * NR + i / rsize;
        int p = row_ptr[slot] + loc[idx];
        int2 rec; rec.x = i; rec.y = __float_as_int(1.0f);
        e8[p] = rec;
        csr_col[p] = i;
    }
}

__global__ void degdinv_kernel(const int* __restrict__ row_ptr, const int2* __restrict__ e8,
                               float* __restrict__ dinv, int n) {
    int node = blockIdx.x * blockDim.x + threadIdx.x;
    if (node < n) {
        int s = row_ptr[node * NR], e = row_ptr[(node + 1) * NR];
        float d = 0.0f;
        for (int j = s; j < e; ++j) d += __int_as_float(e8[j].y);
        dinv[node] = (d > 0.0f) ? rsqrtf(d) : 0.0f;
    }
}

__global__ void normw_kernel(const float* __restrict__ dinv, const int* __restrict__ csr_col,
                             int2* __restrict__ e8, int EN) {
    int p = blockIdx.x * blockDim.x + threadIdx.x;
    if (p < EN) {
        int2 rec = e8[p];
        float w = dinv[rec.x] * __int_as_float(rec.y) * dinv[csr_col[p]];
        ((int*)e8)[2 * p + 1] = __float_as_int(w);
    }
}

// ---------------- dtype prep ----------------

__global__ void cvt_kernel(const float* __restrict__ x, bf16* __restrict__ y, int count) {
    int i = blockIdx.x * blockDim.x + threadIdx.x;
    if (i < count) y[i] = __float2bfloat16(x[i]);
}

__global__ void wt_kernel(const float* __restrict__ W, bf16* __restrict__ Wt, int K, int N) {
    int idx = blockIdx.x * blockDim.x + threadIdx.x;
    if (idx < K * N) {
        int nn = idx / K, kk = idx % K;
        Wt[idx] = __float2bfloat16(W[(size_t)kk * N + nn]);
    }
}

// ---------------- output-type helpers (HW fp8 cvt) ----------------

__device__ inline void store_val(bf16* C, size_t idx, float a) {
    C[idx] = __float2bfloat16(a);
}
__device__ inline void store_val(fp8* C, size_t idx, float a) {
    int packed = __builtin_amdgcn_cvt_pk_fp8_f32(a, a, 0, false);
    C[idx] = (fp8)(packed & 0xff);
}

// ---------------- MFMA GEMM: C[M,N] = A[M,K] @ Wt[N,K]^T, fused epilogue ----------------
// mode 0: raw store; mode 1: sigmoid(BN(acc+bias))
#define GPAD 8

template <typename OT>
__global__ __launch_bounds__(256) void mfma_gemm_kernel(
    const bf16* __restrict__ A, const bf16* __restrict__ Wt,
    OT* __restrict__ C, int M, int K, int N, int mode,
    const float* __restrict__ bias, const float* __restrict__ g,
    const float* __restrict__ be, const float* __restrict__ m,
    const float* __restrict__ v) {
    __shared__ bf16 As[64][32 + GPAD];
    __shared__ bf16 Bs[128][32 + GPAD];
    int m0 = blockIdx.x * 64;
    int n0 = blockIdx.y * 128;
    int tid = threadIdx.x;
    int wave = tid >> 6, lane = tid & 63;
    int lrow = lane & 15, quad = lane >> 4;

    f32x4 acc[8] = {};

    int r = tid >> 2;
    int seg = tid & 3;

    for (int k0 = 0; k0 < K; k0 += 32) {
        uint4 av; av.x = av.y = av.z = av.w = 0u;
        int gm = m0 + r;
        if (gm < M) av = *(const uint4*)(A + (size_t)gm * K + k0 + seg * 8);
        *(uint4*)(&As[r][seg * 8]) = av;
        *(uint4*)(&Bs[r][seg * 8]) =
            *(const uint4*)(Wt + (size_t)(n0 + r) * K + k0 + seg * 8);
        *(uint4*)(&Bs[r + 64][seg * 8]) =
            *(const uint4*)(Wt + (size_t)(n0 + r + 64) * K + k0 + seg * 8);
        __syncthreads();

        short8 afrag = *(const short8*)(&As[wave * 16 + lrow][quad * 8]);
        #pragma unroll
        for (int t = 0; t < 8; ++t) {
            short8 bfrag = *(const short8*)(&Bs[t * 16 + lrow][quad * 8]);
            acc[t] = __builtin_amdgcn_mfma_f32_16x16x32_bf16(afrag, bfrag, acc[t], 0, 0, 0);
        }
        __syncthreads();
    }
    #pragma unroll
    for (int t = 0; t < 8; ++t) {
        int gn = n0 + t * 16 + lrow;
        float bsc = 0.0f, scale = 1.0f, mean = 0.0f, beta = 0.0f;
        if (mode == 1) {
            bsc = bias[gn];
            scale = g[gn] * rsqrtf(v[gn] + BN_EPS);
            mean = m[gn];
            beta = be[gn];
        }
        #pragma unroll
        for (int rr = 0; rr < 4; ++rr) {
            int gm = m0 + wave * 16 + quad * 4 + rr;
            if (gm < M) {
                float a = acc[t][rr];
                if (mode == 1) {
                    a = (a + bsc - mean) * scale + beta;
                    a = 1.0f / (1.0f + __expf(-a));
                }
                store_val(C, (size_t)gm * N + gn, a);
            }
        }
    }
}

// ---------------- bf16 vectorized aggregation (unroll-8 pipelined) ----------------

__device__ inline float bfu(unsigned int u16) {
    union { unsigned int u; float f; } c; c.u = u16 << 16; return c.f;
}
__device__ inline void fma_unpack(unsigned int q, float w, float* acc) {
    acc[0] += w * bfu(q & 0xffffu);
    acc[1] += w * bfu(q >> 16);
}
__device__ inline void fma_unpack(uint2 q, float w, float* acc) {
    fma_unpack(q.x, w, acc); fma_unpack(q.y, w, acc + 2);
}

template <int VEC> struct UVec;
template <> struct UVec<2> { typedef unsigned int T; };
template <> struct UVec<4> { typedef uint2 T; };

template <int VEC>
__global__ __launch_bounds__(256) void agg_vec_kernel(
    const bf16* __restrict__ hw,
    const int* __restrict__ row_ptr, const int2* __restrict__ e8,
    const float* __restrict__ bias,
    const float* __restrict__ g, const float* __restrict__ be,
    const float* __restrict__ m, const float* __restrict__ v,
    bf16* __restrict__ out, int n, int mode) {
    typedef typename UVec<VEC>::T T;
    const int dfeat = VEC * 64;
    int wave = threadIdx.x >> 6;
    int lane = threadIdx.x & 63;
    int node = blockIdx.x * 4 + wave;
    if (node >= n) return;
    int s = row_ptr[node * NR], e = row_ptr[(node + 1) * NR];
    float acc[VEC];
    #pragma unroll
    for (int i = 0; i < VEC; ++i) acc[i] = 0.0f;
    const size_t base = (size_t)lane * VEC;

    int j = s;
    for (; j + 7 < e; j += 8) {
        int2 ew[8];
        #pragma unroll
        for (int u = 0; u < 8; ++u) ew[u] = e8[j + u];
        T q[8];
        #pragma unroll
        for (int u = 0; u < 8; ++u)
            q[u] = *(const T*)(hw + (size_t)ew[u].x * dfeat + base);
        #pragma unroll
        for (int u = 0; u < 8; ++u)
            fma_unpack(q[u], __int_as_float(ew[u].y), acc);
    }
    for (; j < e; ++j) {
        int2 ew = e8[j];
        T q = *(const T*)(hw + (size_t)ew.x * dfeat + base);
        fma_unpack(q, __int_as_float(ew.y), acc);
    }

    #pragma unroll
    for (int i = 0; i < VEC; ++i) {
        int f = (int)base + i;
        float a = acc[i];
        if (mode != 0) {
            a += bias[f];
            if (mode == 1) {
                float scale = g[f] * rsqrtf(v[f] + BN_EPS);
                a = (a - m[f]) * scale + be[f];
            }
            a = 1.0f / (1.0f + __expf(-a));
        }
        out[(size_t)node * dfeat + f] = __float2bfloat16(a);
    }
}

// ---------------- fp8 aggregation with HW cvt (unroll-8 pipelined) ----------------

template <int VEC> struct F8Vec;
template <> struct F8Vec<2> { typedef unsigned short T; };
template <> struct F8Vec<4> { typedef unsigned int T; };

__device__ inline void fma_f8(unsigned short q, float w, float* acc) {
    f32x2 lo = __builtin_amdgcn_cvt_pk_f32_fp8((unsigned int)q, false);
    acc[0] += w * lo.x;
    acc[1] += w * lo.y;
}
__device__ inline void fma_f8(unsigned int q, float w, float* acc) {
    f32x2 lo = __builtin_amdgcn_cvt_pk_f32_fp8(q, false);
    f32x2 hi = __builtin_amdgcn_cvt_pk_f32_fp8(q, true);
    acc[0] += w * lo.x;
    acc[1] += w * lo.y;
    acc[2] += w * hi.x;
    acc[3] += w * hi.y;
}

template <int VEC>
__global__ __launch_bounds__(256) void agg_fp8_kernel(
    const fp8* __restrict__ hw,
    const int* __restrict__ row_ptr, const int2* __restrict__ e8,
    const float* __restrict__ bias,
    const float* __restrict__ g, const float* __restrict__ be,
    const float* __restrict__ m, const float* __restrict__ v,
    bf16* __restrict__ out, int n, int mode) {
    typedef typename F8Vec<VEC>::T T;
    const int dfeat = VEC * 64;
    int wave = threadIdx.x >> 6;
    int lane = threadIdx.x & 63;
    int node = blockIdx.x * 4 + wave;
    if (node >= n) return;
    int s = row_ptr[node * NR], e = row_ptr[(node + 1) * NR];
    float acc[VEC];
    #pragma unroll
    for (int i = 0; i < VEC; ++i) acc[i] = 0.0f;
    const size_t base = (size_t)lane * VEC;

    int j = s;
    for (; j + 7 < e; j += 8) {
        int2 ew[8];
        #pragma unroll
        for (int u = 0; u < 8; ++u) ew[u] = e8[j + u];
        T q[8];
        #pragma unroll
        for (int u = 0; u < 8; ++u)
            q[u] = *(const T*)(hw + (size_t)ew[u].x * dfeat + base);
        #pragma unroll
        for (int u = 0; u < 8; ++u)
            fma_f8(q[u], __int_as_float(ew[u].y), acc);
    }
    for (; j < e; ++j) {
        int2 ew = e8[j];
        T q = *(const T*)(hw + (size_t)ew.x * dfeat + base);
        fma_f8(q, __int_as_float(ew.y), acc);
    }

    #pragma unroll
    for (int i = 0; i < VEC; ++i) {
        int f = (int)base + i;
        float a = acc[i];
        if (mode != 0) {
            a += bias[f];
            if (mode == 1) {
                float scale = g[f] * rsqrtf(v[f] + BN_EPS);
                a = (a - m[f]) * scale + be[f];
            }
            a = 1.0f / (1.0f + __expf(-a));
        }
        out[(size_t)node * dfeat + f] = __float2bfloat16(a);
    }
}

// ---------------- final h^T h via MFMA ----------------
#define TPAD 8

__global__ __launch_bounds__(256) void htht_mfma_kernel(
    const bf16* __restrict__ h, float* __restrict__ partial, int n) {
    __shared__ bf16 hsT[128][32 + TPAD];
    int b = blockIdx.x;
    int tid = threadIdx.x;
    int wave = tid >> 6, lane = tid & 63;
    int lrow = lane & 15, quad = lane >> 4;

    f32x4 acc[2][8] = {};

    int kk = tid >> 3;
    int seg = tid & 7;

    for (int kt = 0; kt < 8; ++kt) {
        int k0 = b * 256 + kt * 32;
        #pragma unroll
        for (int s2 = 0; s2 < 2; ++s2) {
            int fs = (seg + s2 * 8) * 8;
            int gk = k0 + kk;
            uint4 q; q.x = q.y = q.z = q.w = 0u;
            if (gk < n) q = *(const uint4*)(h + (size_t)gk * 128 + fs);
            const unsigned short* u = (const unsigned short*)&q;
            #pragma unroll
            for (int i = 0; i < 8; ++i)
                *((unsigned short*)&hsT[fs + i][kk]) = u[i];
        }
        __syncthreads();
        short8 af0 = *(const short8*)(&hsT[wave * 32 + lrow][quad * 8]);
        short8 af1 = *(const short8*)(&hsT[wave * 32 + 16 + lrow][quad * 8]);
        #pragma unroll
        for (int t = 0; t < 8; ++t) {
            short8 bfrag = *(const short8*)(&hsT[t * 16 + lrow][quad * 8]);
            acc[0][t] = __builtin_amdgcn_mfma_f32_16x16x32_bf16(af0, bfrag, acc[0][t], 0, 0, 0);
            acc[1][t] = __builtin_amdgcn_mfma_f32_16x16x32_bf16(af1, bfrag, acc[1][t], 0, 0, 0);
        }
        __syncthreads();
    }
    float* p = partial + (size_t)b * 16384;
    #pragma unroll
    for (int a_ = 0; a_ < 2; ++a_) {
        #pragma unroll
        for (int t = 0; t < 8; ++t) {
            #pragma unroll
            for (int rr = 0; rr < 4; ++rr) {
                int gm = wave * 32 + a_ * 16 + quad * 4 + rr;
                int gn = t * 16 + lrow;
                p[gm * 128 + gn] = acc[a_][t][rr];
            }
        }
    }
}

__global__ void reduce_kernel(const float* __restrict__ partial, float* __restrict__ out, int nchunks) {
    int idx = blockIdx.x * blockDim.x + threadIdx.x;
    float s = 0.0f;
    for (int c = 0; c < nchunks; ++c) s += partial[(size_t)c * 16384 + idx];
    int i = idx / 128, j = idx % 128;
    out[idx] = (i == j) ? 0.0f : s;
}

// ---------------- launch ----------------
extern "C" void kernel_launch(void* const* d_in, const int* in_sizes, int n_in,
                              void* d_out, int out_size, void* d_ws, size_t ws_size,
                              hipStream_t stream) {
    const float* x  = (const float*)d_in[0];
    const int*   ei = (const int*)d_in[1];
    const float* ea = (const float*)d_in[2];
    const float* W[5];  const float* bvec[5];
    for (int l = 0; l < 5; ++l) { W[l] = (const float*)d_in[3 + 2 * l]; bvec[l] = (const float*)d_in[4 + 2 * l]; }
    const float* g[4]; const float* be[4]; const float* mm[4]; const float* vv[4];
    for (int l = 0; l < 4; ++l) {
        g[l]  = (const float*)d_in[13 + 4 * l];
        be[l] = (const float*)d_in[14 + 4 * l];
        mm[l] = (const float*)d_in[15 + 4 * l];
        vv[l] = (const float*)d_in[16 + 4 * l];
    }
    const int n = in_sizes[0] / NSF;        // 20000
    const int E = in_sizes[1] / 2;          // 500000
    const int EN = E + n;
    const int rsize = (n + NR - 1) / NR;
    const int total = n * NR;
    const int nscan = (total + SCK - 1) / SCK;
    const int dims[6] = {128, 256, 512, 256, 128, 128};
    const int wtoff[5] = {0, 32768, 163840, 294912, 327680};
    const int wtelems = 344064;

    // workspace layout (256B aligned); ~66 MB
    auto align = [](size_t o) { return (o + 255) & ~(size_t)255; };
    size_t off = 0;
    float* dinv    = (float*)((char*)d_ws + off); off = align(off + (size_t)n * 4);
    int*   fill    = (int*)  ((char*)d_ws + off); off = align(off + (size_t)total * 4);
    int*   row_ptr = (int*)  ((char*)d_ws + off); off = align(off + ((size_t)total + 1) * 4);
    int*   blksum  = (int*)  ((char*)d_ws + off); off = align(off + (size_t)256 * 4);
    int*   locb    = (int*)  ((char*)d_ws + off); off = align(off + (size_t)EN * 4);
    int2*  e8      = (int2*) ((char*)d_ws + off); off = align(off + (size_t)EN * 8);
    int*   csr_col = (int*)  ((char*)d_ws + off); off = align(off + (size_t)EN * 4);
    bf16*  wtbuf   = (bf16*) ((char*)d_ws + off); off = align(off + (size_t)wtelems * 2);
    bf16*  hbuf    = (bf16*) ((char*)d_ws + off); off = align(off + (size_t)n * 512 * 2);
    bf16*  abuf    = (bf16*) ((char*)d_ws + off); off = align(off + (size_t)n * 512 * 2);
    fp8*   f8buf   = (fp8*)  ((char*)d_ws + off); off = align(off + (size_t)n * 256);
    const int KCH = (20000 + 255) / 256;    // 79
    float* partial = (float*)((char*)d_ws + off); off = align(off + (size_t)KCH * 16384 * 4);

    // CSR build (1 atomic/edge, packed edge records)
    zero_fill_kernel<<<(total + 255) / 256, 256, 0, stream>>>(fill, total);
    passA_kernel<<<(EN + 255) / 256, 256, 0, stream>>>(ei, fill, locb, E, n, rsize);
    scan1_kernel<<<nscan, 256, 0, stream>>>(fill, blksum, total);
    scan2_kernel<<<1, 256, 0, stream>>>(blksum, row_ptr, nscan, total);
    scan3_kernel<<<nscan, 256, 0, stream>>>(fill, blksum, row_ptr, total);
    passB_kernel<<<(EN + 255) / 256, 256, 0, stream>>>(ei, ea, row_ptr, locb,
                                                       e8, csr_col, E, n, rsize);
    degdinv_kernel<<<(n + 255) / 256, 256, 0, stream>>>(row_ptr, e8, dinv, n);
    normw_kernel<<<(EN + 255) / 256, 256, 0, stream>>>(dinv, csr_col, e8, EN);

    // dtype prep
    cvt_kernel<<<(n * 128 + 255) / 256, 256, 0, stream>>>(x, hbuf, n * 128);
    for (int l = 0; l < 5; ++l) {
        int K = dims[l], N = dims[l + 1];
        wt_kernel<<<(K * N + 255) / 256, 256, 0, stream>>>(W[l], wtbuf + wtoff[l], K, N);
    }

    int ablocks = (n + 3) / 4;
    auto gemm_bf16 = [&](const bf16* A, int l, bf16* C, int mode) {
        int K = dims[l], N = dims[l + 1];
        dim3 gg((n + 63) / 64, N / 128);
        int bi = (l < 4) ? l : 0;
        mfma_gemm_kernel<bf16><<<gg, 256, 0, stream>>>(A, wtbuf + wtoff[l], C, n, K, N, mode,
                                                       bvec[l], g[bi], be[bi], mm[bi], vv[bi]);
    };
    auto gemm_fp8 = [&](const bf16* A, int l, fp8* C, int mode) {
        int K = dims[l], N = dims[l + 1];
        dim3 gg((n + 63) / 64, N / 128);
        int bi = (l < 4) ? l : 0;
        mfma_gemm_kernel<fp8><<<gg, 256, 0, stream>>>(A, wtbuf + wtoff[l], C, n, K, N, mode,
                                                      bvec[l], g[bi], be[bi], mm[bi], vv[bi]);
    };

    // L1 (128->256): agg-first bf16 128 (x), GEMM1 fused act -> fp8 h1
    agg_vec_kernel<2><<<ablocks, 256, 0, stream>>>(hbuf, row_ptr, e8,
        bvec[0], bvec[0], bvec[0], bvec[0], bvec[0], abuf, n, 0);
    gemm_fp8(abuf, 0, f8buf, 1);
    // L2 (256->512): agg-first fp8 256 (h1) -> bf16, GEMM2 fused act -> bf16 h2 (512)
    agg_fp8_kernel<4><<<ablocks, 256, 0, stream>>>(f8buf, row_ptr, e8,
        bvec[1], bvec[1], bvec[1], bvec[1], bvec[1], abuf, n, 0);
    gemm_bf16(abuf, 1, hbuf, 1);
    // L3 (512->256): GEMM3 raw -> fp8 hw3, agg-last fp8 256 + bias+BN+sigmoid -> bf16 h3
    gemm_fp8(hbuf, 2, f8buf, 0);
    agg_fp8_kernel<4><<<ablocks, 256, 0, stream>>>(f8buf, row_ptr, e8,
        bvec[2], g[2], be[2], mm[2], vv[2], abuf, n, 1);
    // L4 (256->128): GEMM4 raw -> fp8 hw4, agg-last fp8 128 + bias+BN+sigmoid -> bf16 h4
    gemm_fp8(abuf, 3, f8buf, 0);
    agg_fp8_kernel<2><<<ablocks, 256, 0, stream>>>(f8buf, row_ptr, e8,
        bvec[3], g[3], be[3], mm[3], vv[3], hbuf, n, 1);
    // L5 (128->128): GEMM5 raw -> fp8 hw5, agg-last fp8 128 + bias+sigmoid -> bf16 h5
    gemm_fp8(hbuf, 4, f8buf, 0);
    agg_fp8_kernel<2><<<ablocks, 256, 0, stream>>>(f8buf, row_ptr, e8,
        bvec[4], bvec[4], bvec[4], bvec[4], bvec[4], abuf, n, 2);

    // final h^T h with zeroed diagonal (MFMA)
    htht_mfma_kernel<<<KCH, 256, 0, stream>>>(abuf, partial, n);
    reduce_kernel<<<16384 / 256, 256, 0, stream>>>(partial, (float*)d_out, KCH);
}

// Round 13
// 422.645 us; speedup vs baseline: 1.4846x; 1.0403x over previous
//
#include <hip/hip_runtime.h>
#include <hip/hip_bf16.h>
#include <hip/hip_fp8.h>
#include <cstdint>
#include <cstddef>

typedef __hip_bfloat16 bf16;
typedef unsigned char fp8;                                  // e4m3 storage
typedef __attribute__((ext_vector_type(8))) short short8;   // 8 bf16 (MFMA A/B frag)
typedef __attribute__((ext_vector_type(4))) float f32x4;    // MFMA C/D frag
typedef __attribute__((ext_vector_type(2))) float f32x2;

#define NSF 128
#define BN_EPS 1e-3f
#define NR 4            // src ranges per node
#define SCK 2048        // elements per scan block

// ---------------- CSR build: 1 atomic per edge ----------------

__global__ void zero_fill_kernel(int* __restrict__ fill, int total) {
    int i = blockIdx.x * blockDim.x + threadIdx.x;
    if (i < total) fill[i] = 0;
}

__global__ void passA_kernel(const int* __restrict__ ei, int* __restrict__ fill,
                             int* __restrict__ loc, int E, int n, int rsize) {
    int idx = blockIdx.x * blockDim.x + threadIdx.x;
    if (idx < E) {
        int r = ei[idx];
        int c = ei[E + idx];
        int slot = c * NR + r / rsize;
        loc[idx] = atomicAdd(&fill[slot], 1);
    } else if (idx < E + n) {
        int i = idx - E;
        int slot = i * NR + i / rsize;
        loc[idx] = atomicAdd(&fill[slot], 1);
    }
}

// ---- hierarchical exclusive scan of fill -> row_ptr ----

__global__ void scan1_kernel(const int* __restrict__ cnt, int* __restrict__ blksum, int total) {
    __shared__ int red[256];
    int base = blockIdx.x * SCK + threadIdx.x * 8;
    int s = 0;
    #pragma unroll
    for (int i = 0; i < 8; ++i) {
        int idx = base + i;
        if (idx < total) s += cnt[idx];
    }
    red[threadIdx.x] = s;
    __syncthreads();
    for (int off2 = 128; off2 > 0; off2 >>= 1) {
        if (threadIdx.x < off2) red[threadIdx.x] += red[threadIdx.x + off2];
        __syncthreads();
    }
    if (threadIdx.x == 0) blksum[blockIdx.x] = red[0];
}

__global__ void scan2_kernel(int* __restrict__ blksum, int* __restrict__ row_ptr,
                             int nblk, int total) {
    __shared__ int part[256];
    int tid = threadIdx.x;
    int v = (tid < nblk) ? blksum[tid] : 0;
    part[tid] = v;
    __syncthreads();
    for (int off2 = 1; off2 < 256; off2 <<= 1) {
        int t = (tid >= off2) ? part[tid - off2] : 0;
        __syncthreads();
        part[tid] += t;
        __syncthreads();
    }
    if (tid < nblk) blksum[tid] = part[tid] - v;
    if (tid == 255) row_ptr[total] = part[255];
}

__global__ void scan3_kernel(const int* __restrict__ cnt, const int* __restrict__ blkoff,
                             int* __restrict__ row_ptr, int total) {
    __shared__ int part[256];
    int tid = threadIdx.x;
    int base = blockIdx.x * SCK + tid * 8;
    int loc[8]; int s = 0;
    #pragma unroll
    for (int i = 0; i < 8; ++i) {
        int idx = base + i;
        loc[i] = (idx < total) ? cnt[idx] : 0;
        s += loc[i];
    }
    part[tid] = s;
    __syncthreads();
    for (int off2 = 1; off2 < 256; off2 <<= 1) {
        int t = (tid >= off2) ? part[tid - off2] : 0;
        __syncthreads();
        part[tid] += t;
        __syncthreads();
    }
    int run = blkoff[blockIdx.x] + part[tid] - s;
    #pragma unroll
    for (int i = 0; i < 8; ++i) {
        int idx = base + i;
        if (idx < total) { row_ptr[idx] = run; run += loc[i]; }
    }
}

// passB: scatter without atomics; packed edge record {src, w_bits}
__global__ void passB_kernel(const int* __restrict__ ei, const float* __restrict__ ea,
                             const int* __restrict__ row_ptr, const int* __restrict__ loc,
                             int2* __restrict__ e8, int* __restrict__ csr_col,
                             int E, int n, int rsize) {
    int idx = blockIdx.x * blockDim.x + threadIdx.x;
    if (idx < E) {
        int r = ei[idx];
        int c = ei[E + idx];
        int slot = c * NR + r / rsize;
        int p = row_ptr[slot] + loc[idx];
        int2 rec; rec.x = r; rec.y = __float_as_int(ea[idx]);
        e8[p] = rec;
        csr_col[p] = c;
    } else if (idx < E + n) {
        int i = idx - E;
        int slot = i * NR + i / rsize;
        int p = row_ptr[slot] + loc[idx];
        int2 rec; rec.x = i; rec.y = __float_as_int(1.0f);
        e8[p] = rec;
        csr_col[p] = i;
    }
}

__global__ void degdinv_kernel(const int* __restrict__ row_ptr, const int2* __restrict__ e8,
                               float* __restrict__ dinv, int n) {
    int node = blockIdx.x * blockDim.x + threadIdx.x;
    if (node < n) {
        int s = row_ptr[node * NR], e = row_ptr[(node + 1) * NR];
        float d = 0.0f;
        for (int j = s; j < e; ++j) d += __int_as_float(e8[j].y);
        dinv[node] = (d > 0.0f) ? rsqrtf(d) : 0.0f;
    }
}

__global__ void normw_kernel(const float* __restrict__ dinv, const int* __restrict__ csr_col,
                             int2* __restrict__ e8, int EN) {
    int p = blockIdx.x * blockDim.x + threadIdx.x;
    if (p < EN) {
        int2 rec = e8[p];
        float w = dinv[rec.x] * __int_as_float(rec.y) * dinv[csr_col[p]];
        ((int*)e8)[2 * p + 1] = __float_as_int(w);
    }
}

// ---------------- dtype prep ----------------

__global__ void cvt_kernel(const float* __restrict__ x, bf16* __restrict__ y, int count) {
    int i = blockIdx.x * blockDim.x + threadIdx.x;
    if (i < count) y[i] = __float2bfloat16(x[i]);
}

__global__ void wt_kernel(const float* __restrict__ W, bf16* __restrict__ Wt, int K, int N) {
    int idx = blockIdx.x * blockDim.x + threadIdx.x;
    if (idx < K * N) {
        int nn = idx / K, kk = idx % K;
        Wt[idx] = __float2bfloat16(W[(size_t)kk * N + nn]);
    }
}

// ---------------- output-type helpers (HW fp8 cvt) ----------------

__device__ inline void store_val(bf16* C, size_t idx, float a) {
    C[idx] = __float2bfloat16(a);
}
__device__ inline void store_val(fp8* C, size_t idx, float a) {
    int packed = __builtin_amdgcn_cvt_pk_fp8_f32(a, a, 0, false);
    C[idx] = (fp8)(packed & 0xff);
}

// ---------------- direct global->LDS 16B staging ----------------

__device__ inline void gl_lds16(const bf16* g, bf16* l) {
    __builtin_amdgcn_global_load_lds(
        (const __attribute__((address_space(1))) void*)g,
        (__attribute__((address_space(3))) void*)l,
        16, 0, 0);
}

// ---------------- MFMA GEMM: C[M,N] = A[M,K] @ Wt[N,K]^T, fused epilogue ----------------
// mode 0: raw store; mode 1: sigmoid(BN(acc+bias))
// Staging via global_load_lds width=16: LDS tiles UNPADDED, lane-contiguous
// (wave-uniform base + lane*16 per m97/m104).

template <typename OT>
__global__ __launch_bounds__(256) void mfma_gemm_kernel(
    const bf16* __restrict__ A, const bf16* __restrict__ Wt,
    OT* __restrict__ C, int M, int K, int N, int mode,
    const float* __restrict__ bias, const float* __restrict__ g,
    const float* __restrict__ be, const float* __restrict__ m,
    const float* __restrict__ v) {
    __shared__ bf16 As[64][32];     // 4 KB
    __shared__ bf16 Bs[128][32];    // 8 KB
    int m0 = blockIdx.x * 64;
    int n0 = blockIdx.y * 128;
    int tid = threadIdx.x;
    int wave = tid >> 6, lane = tid & 63;
    int lrow = lane & 15, quad = lane >> 4;

    f32x4 acc[8] = {};

    // staging map: lane l covers row base + (l>>2), 16B seg l&3 (lane-contiguous in LDS)
    int srow = lane >> 2;       // 0..15
    int sseg = lane & 3;        // 0..3
    int am = wave * 16 + srow;  // A row within tile (wave w stages rows w*16..+16)
    int bn = wave * 32 + srow;  // B rows: wave w stages w*32..+16 and +16..+32
    bool aok = (m0 + am) < M;

    for (int k0 = 0; k0 < K; k0 += 32) {
        if (aok)
            gl_lds16(A + (size_t)(m0 + am) * K + k0 + sseg * 8, &As[am][sseg * 8]);
        gl_lds16(Wt + (size_t)(n0 + bn) * K + k0 + sseg * 8, &Bs[bn][sseg * 8]);
        gl_lds16(Wt + (size_t)(n0 + bn + 16) * K + k0 + sseg * 8, &Bs[bn + 16][sseg * 8]);
        __syncthreads();

        short8 afrag = *(const short8*)(&As[wave * 16 + lrow][quad * 8]);
        #pragma unroll
        for (int t = 0; t < 8; ++t) {
            short8 bfrag = *(const short8*)(&Bs[t * 16 + lrow][quad * 8]);
            acc[t] = __builtin_amdgcn_mfma_f32_16x16x32_bf16(afrag, bfrag, acc[t], 0, 0, 0);
        }
        __syncthreads();
    }
    // C/D: col = lane&15, row = quad*4 + reg
    #pragma unroll
    for (int t = 0; t < 8; ++t) {
        int gn = n0 + t * 16 + lrow;
        float bsc = 0.0f, scale = 1.0f, mean = 0.0f, beta = 0.0f;
        if (mode == 1) {
            bsc = bias[gn];
            scale = g[gn] * rsqrtf(v[gn] + BN_EPS);
            mean = m[gn];
            beta = be[gn];
        }
        #pragma unroll
        for (int rr = 0; rr < 4; ++rr) {
            int gm = m0 + wave * 16 + quad * 4 + rr;
            if (gm < M) {
                float a = acc[t][rr];
                if (mode == 1) {
                    a = (a + bsc - mean) * scale + beta;
                    a = 1.0f / (1.0f + __expf(-a));
                }
                store_val(C, (size_t)gm * N + gn, a);
            }
        }
    }
}

// ---------------- bf16 vectorized aggregation (unroll-8 + 4 + tail) ----------------

__device__ inline float bfu(unsigned int u16) {
    union { unsigned int u; float f; } c; c.u = u16 << 16; return c.f;
}
__device__ inline void fma_unpack(unsigned int q, float w, float* acc) {
    acc[0] += w * bfu(q & 0xffffu);
    acc[1] += w * bfu(q >> 16);
}
__device__ inline void fma_unpack(uint2 q, float w, float* acc) {
    fma_unpack(q.x, w, acc); fma_unpack(q.y, w, acc + 2);
}

template <int VEC> struct UVec;
template <> struct UVec<2> { typedef unsigned int T; };
template <> struct UVec<4> { typedef uint2 T; };

template <int VEC>
__global__ __launch_bounds__(256) void agg_vec_kernel(
    const bf16* __restrict__ hw,
    const int* __restrict__ row_ptr, const int2* __restrict__ e8,
    const float* __restrict__ bias,
    const float* __restrict__ g, const float* __restrict__ be,
    const float* __restrict__ m, const float* __restrict__ v,
    bf16* __restrict__ out, int n, int mode) {
    typedef typename UVec<VEC>::T T;
    const int dfeat = VEC * 64;
    int wave = threadIdx.x >> 6;
    int lane = threadIdx.x & 63;
    int node = blockIdx.x * 4 + wave;
    if (node >= n) return;
    int s = row_ptr[node * NR], e = row_ptr[(node + 1) * NR];
    float acc[VEC];
    #pragma unroll
    for (int i = 0; i < VEC; ++i) acc[i] = 0.0f;
    const size_t base = (size_t)lane * VEC;

    int j = s;
    for (; j + 7 < e; j += 8) {
        int2 ew[8];
        #pragma unroll
        for (int u = 0; u < 8; ++u) ew[u] = e8[j + u];
        T q[8];
        #pragma unroll
        for (int u = 0; u < 8; ++u)
            q[u] = *(const T*)(hw + (size_t)ew[u].x * dfeat + base);
        #pragma unroll
        for (int u = 0; u < 8; ++u)
            fma_unpack(q[u], __int_as_float(ew[u].y), acc);
    }
    for (; j + 3 < e; j += 4) {
        int2 ew[4];
        #pragma unroll
        for (int u = 0; u < 4; ++u) ew[u] = e8[j + u];
        T q[4];
        #pragma unroll
        for (int u = 0; u < 4; ++u)
            q[u] = *(const T*)(hw + (size_t)ew[u].x * dfeat + base);
        #pragma unroll
        for (int u = 0; u < 4; ++u)
            fma_unpack(q[u], __int_as_float(ew[u].y), acc);
    }
    for (; j < e; ++j) {
        int2 ew = e8[j];
        T q = *(const T*)(hw + (size_t)ew.x * dfeat + base);
        fma_unpack(q, __int_as_float(ew.y), acc);
    }

    #pragma unroll
    for (int i = 0; i < VEC; ++i) {
        int f = (int)base + i;
        float a = acc[i];
        if (mode != 0) {
            a += bias[f];
            if (mode == 1) {
                float scale = g[f] * rsqrtf(v[f] + BN_EPS);
                a = (a - m[f]) * scale + be[f];
            }
            a = 1.0f / (1.0f + __expf(-a));
        }
        out[(size_t)node * dfeat + f] = __float2bfloat16(a);
    }
}

// ---------------- fp8 aggregation with HW cvt (unroll-8 + 4 + tail) ----------------

template <int VEC> struct F8Vec;
template <> struct F8Vec<2> { typedef unsigned short T; };
template <> struct F8Vec<4> { typedef unsigned int T; };

__device__ inline void fma_f8(unsigned short q, float w, float* acc) {
    f32x2 lo = __builtin_amdgcn_cvt_pk_f32_fp8((unsigned int)q, false);
    acc[0] += w * lo.x;
    acc[1] += w * lo.y;
}
__device__ inline void fma_f8(unsigned int q, float w, float* acc) {
    f32x2 lo = __builtin_amdgcn_cvt_pk_f32_fp8(q, false);
    f32x2 hi = __builtin_amdgcn_cvt_pk_f32_fp8(q, true);
    acc[0] += w * lo.x;
    acc[1] += w * lo.y;
    acc[2] += w * hi.x;
    acc[3] += w * hi.y;
}

template <int VEC>
__global__ __launch_bounds__(256) void agg_fp8_kernel(
    const fp8* __restrict__ hw,
    const int* __restrict__ row_ptr, const int2* __restrict__ e8,
    const float* __restrict__ bias,
    const float* __restrict__ g, const float* __restrict__ be,
    const float* __restrict__ m, const float* __restrict__ v,
    bf16* __restrict__ out, int n, int mode) {
    typedef typename F8Vec<VEC>::T T;
    const int dfeat = VEC * 64;
    int wave = threadIdx.x >> 6;
    int lane = threadIdx.x & 63;
    int node = blockIdx.x * 4 + wave;
    if (node >= n) return;
    int s = row_ptr[node * NR], e = row_ptr[(node + 1) * NR];
    float acc[VEC];
    #pragma unroll
    for (int i = 0; i < VEC; ++i) acc[i] = 0.0f;
    const size_t base = (size_t)lane * VEC;

    int j = s;
    for (; j + 7 < e; j += 8) {
        int2 ew[8];
        #pragma unroll
        for (int u = 0; u < 8; ++u) ew[u] = e8[j + u];
        T q[8];
        #pragma unroll
        for (int u = 0; u < 8; ++u)
            q[u] = *(const T*)(hw + (size_t)ew[u].x * dfeat + base);
        #pragma unroll
        for (int u = 0; u < 8; ++u)
            fma_f8(q[u], __int_as_float(ew[u].y), acc);
    }
    for (; j + 3 < e; j += 4) {
        int2 ew[4];
        #pragma unroll
        for (int u = 0; u < 4; ++u) ew[u] = e8[j + u];
        T q[4];
        #pragma unroll
        for (int u = 0; u < 4; ++u)
            q[u] = *(const T*)(hw + (size_t)ew[u].x * dfeat + base);
        #pragma unroll
        for (int u = 0; u < 4; ++u)
            fma_f8(q[u], __int_as_float(ew[u].y), acc);
    }
    for (; j < e; ++j) {
        int2 ew = e8[j];
        T q = *(const T*)(hw + (size_t)ew.x * dfeat + base);
        fma_f8(q, __int_as_float(ew.y), acc);
    }

    #pragma unroll
    for (int i = 0; i < VEC; ++i) {
        int f = (int)base + i;
        float a = acc[i];
        if (mode != 0) {
            a += bias[f];
            if (mode == 1) {
                float scale = g[f] * rsqrtf(v[f] + BN_EPS);
                a = (a - m[f]) * scale + be[f];
            }
            a = 1.0f / (1.0f + __expf(-a));
        }
        out[(size_t)node * dfeat + f] = __float2bfloat16(a);
    }
}

// ---------------- final h^T h via MFMA ----------------
#define TPAD 8

__global__ __launch_bounds__(256) void htht_mfma_kernel(
    const bf16* __restrict__ h, float* __restrict__ partial, int n) {
    __shared__ bf16 hsT[128][32 + TPAD];
    int b = blockIdx.x;
    int tid = threadIdx.x;
    int wave = tid >> 6, lane = tid & 63;
    int lrow = lane & 15, quad = lane >> 4;

    f32x4 acc[2][8] = {};

    int kk = tid >> 3;
    int seg = tid & 7;

    for (int kt = 0; kt < 8; ++kt) {
        int k0 = b * 256 + kt * 32;
        #pragma unroll
        for (int s2 = 0; s2 < 2; ++s2) {
            int fs = (seg + s2 * 8) * 8;
            int gk = k0 + kk;
            uint4 q; q.x = q.y = q.z = q.w = 0u;
            if (gk < n) q = *(const uint4*)(h + (size_t)gk * 128 + fs);
            const unsigned short* u = (const unsigned short*)&q;
            #pragma unroll
            for (int i = 0; i < 8; ++i)
                *((unsigned short*)&hsT[fs + i][kk]) = u[i];
        }
        __syncthreads();
        short8 af0 = *(const short8*)(&hsT[wave * 32 + lrow][quad * 8]);
        short8 af1 = *(const short8*)(&hsT[wave * 32 + 16 + lrow][quad * 8]);
        #pragma unroll
        for (int t = 0; t < 8; ++t) {
            short8 bfrag = *(const short8*)(&hsT[t * 16 + lrow][quad * 8]);
            acc[0][t] = __builtin_amdgcn_mfma_f32_16x16x32_bf16(af0, bfrag, acc[0][t], 0, 0, 0);
            acc[1][t] = __builtin_amdgcn_mfma_f32_16x16x32_bf16(af1, bfrag, acc[1][t], 0, 0, 0);
        }
        __syncthreads();
    }
    float* p = partial + (size_t)b * 16384;
    #pragma unroll
    for (int a_ = 0; a_ < 2; ++a_) {
        #pragma unroll
        for (int t = 0; t < 8; ++t) {
            #pragma unroll
            for (int rr = 0; rr < 4; ++rr) {
                int gm = wave * 32 + a_ * 16 + quad * 4 + rr;
                int gn = t * 16 + lrow;
                p[gm * 128 + gn] = acc[a_][t][rr];
            }
        }
    }
}

__global__ void reduce_kernel(const float* __restrict__ partial, float* __restrict__ out, int nchunks) {
    int idx = blockIdx.x * blockDim.x + threadIdx.x;
    float s = 0.0f;
    for (int c = 0; c < nchunks; ++c) s += partial[(size_t)c * 16384 + idx];
    int i = idx / 128, j = idx % 128;
    out[idx] = (i == j) ? 0.0f : s;
}

// ---------------- launch ----------------
extern "C" void kernel_launch(void* const* d_in, const int* in_sizes, int n_in,
                              void* d_out, int out_size, void* d_ws, size_t ws_size,
                              hipStream_t stream) {
    const float* x  = (const float*)d_in[0];
    const int*   ei = (const int*)d_in[1];
    const float* ea = (const float*)d_in[2];
    const float* W[5];  const float* bvec[5];
    for (int l = 0; l < 5; ++l) { W[l] = (const float*)d_in[3 + 2 * l]; bvec[l] = (const float*)d_in[4 + 2 * l]; }
    const float* g[4]; const float* be[4]; const float* mm[4]; const float* vv[4];
    for (int l = 0; l < 4; ++l) {
        g[l]  = (const float*)d_in[13 + 4 * l];
        be[l] = (const float*)d_in[14 + 4 * l];
        mm[l] = (const float*)d_in[15 + 4 * l];
        vv[l] = (const float*)d_in[16 + 4 * l];
    }
    const int n = in_sizes[0] / NSF;        // 20000
    const int E = in_sizes[1] / 2;          // 500000
    const int EN = E + n;
    const int rsize = (n + NR - 1) / NR;
    const int total = n * NR;
    const int nscan = (total + SCK - 1) / SCK;
    const int dims[6] = {128, 256, 512, 256, 128, 128};
    const int wtoff[5] = {0, 32768, 163840, 294912, 327680};
    const int wtelems = 344064;

    // workspace layout (256B aligned); ~66 MB
    auto align = [](size_t o) { return (o + 255) & ~(size_t)255; };
    size_t off = 0;
    float* dinv    = (float*)((char*)d_ws + off); off = align(off + (size_t)n * 4);
    int*   fill    = (int*)  ((char*)d_ws + off); off = align(off + (size_t)total * 4);
    int*   row_ptr = (int*)  ((char*)d_ws + off); off = align(off + ((size_t)total + 1) * 4);
    int*   blksum  = (int*)  ((char*)d_ws + off); off = align(off + (size_t)256 * 4);
    int*   locb    = (int*)  ((char*)d_ws + off); off = align(off + (size_t)EN * 4);
    int2*  e8      = (int2*) ((char*)d_ws + off); off = align(off + (size_t)EN * 8);
    int*   csr_col = (int*)  ((char*)d_ws + off); off = align(off + (size_t)EN * 4);
    bf16*  wtbuf   = (bf16*) ((char*)d_ws + off); off = align(off + (size_t)wtelems * 2);
    bf16*  hbuf    = (bf16*) ((char*)d_ws + off); off = align(off + (size_t)n * 512 * 2);
    bf16*  abuf    = (bf16*) ((char*)d_ws + off); off = align(off + (size_t)n * 512 * 2);
    fp8*   f8buf   = (fp8*)  ((char*)d_ws + off); off = align(off + (size_t)n * 256);
    const int KCH = (20000 + 255) / 256;    // 79
    float* partial = (float*)((char*)d_ws + off); off = align(off + (size_t)KCH * 16384 * 4);

    // CSR build (1 atomic/edge, packed edge records)
    zero_fill_kernel<<<(total + 255) / 256, 256, 0, stream>>>(fill, total);
    passA_kernel<<<(EN + 255) / 256, 256, 0, stream>>>(ei, fill, locb, E, n, rsize);
    scan1_kernel<<<nscan, 256, 0, stream>>>(fill, blksum, total);
    scan2_kernel<<<1, 256, 0, stream>>>(blksum, row_ptr, nscan, total);
    scan3_kernel<<<nscan, 256, 0, stream>>>(fill, blksum, row_ptr, total);
    passB_kernel<<<(EN + 255) / 256, 256, 0, stream>>>(ei, ea, row_ptr, locb,
                                                       e8, csr_col, E, n, rsize);
    degdinv_kernel<<<(n + 255) / 256, 256, 0, stream>>>(row_ptr, e8, dinv, n);
    normw_kernel<<<(EN + 255) / 256, 256, 0, stream>>>(dinv, csr_col, e8, EN);

    // dtype prep
    cvt_kernel<<<(n * 128 + 255) / 256, 256, 0, stream>>>(x, hbuf, n * 128);
    for (int l = 0; l < 5; ++l) {
        int K = dims[l], N = dims[l + 1];
        wt_kernel<<<(K * N + 255) / 256, 256, 0, stream>>>(W[l], wtbuf + wtoff[l], K, N);
    }

    int ablocks = (n + 3) / 4;
    auto gemm_bf16 = [&](const bf16* A, int l, bf16* C, int mode) {
        int K = dims[l], N = dims[l + 1];
        dim3 gg((n + 63) / 64, N / 128);
        int bi = (l < 4) ? l : 0;
        mfma_gemm_kernel<bf16><<<gg, 256, 0, stream>>>(A, wtbuf + wtoff[l], C, n, K, N, mode,
                                                       bvec[l], g[bi], be[bi], mm[bi], vv[bi]);
    };
    auto gemm_fp8 = [&](const bf16* A, int l, fp8* C, int mode) {
        int K = dims[l], N = dims[l + 1];
        dim3 gg((n + 63) / 64, N / 128);
        int bi = (l < 4) ? l : 0;
        mfma_gemm_kernel<fp8><<<gg, 256, 0, stream>>>(A, wtbuf + wtoff[l], C, n, K, N, mode,
                                                      bvec[l], g[bi], be[bi], mm[bi], vv[bi]);
    };

    // L1 (128->256): agg-first bf16 128 (x), GEMM1 fused act -> fp8 h1
    agg_vec_kernel<2><<<ablocks, 256, 0, stream>>>(hbuf, row_ptr, e8,
        bvec[0], bvec[0], bvec[0], bvec[0], bvec[0], abuf, n, 0);
    gemm_fp8(abuf, 0, f8buf, 1);
    // L2 (256->512): agg-first fp8 256 (h1) -> bf16, GEMM2 fused act -> bf16 h2 (512)
    agg_fp8_kernel<4><<<ablocks, 256, 0, stream>>>(f8buf, row_ptr, e8,
        bvec[1], bvec[1], bvec[1], bvec[1], bvec[1], abuf, n, 0);
    gemm_bf16(abuf, 1, hbuf, 1);
    // L3 (512->256): GEMM3 raw -> fp8 hw3, agg-last fp8 256 + bias+BN+sigmoid -> bf16 h3
    gemm_fp8(hbuf, 2, f8buf, 0);
    agg_fp8_kernel<4><<<ablocks, 256, 0, stream>>>(f8buf, row_ptr, e8,
        bvec[2], g[2], be[2], mm[2], vv[2], abuf, n, 1);
    // L4 (256->128): GEMM4 raw -> fp8 hw4, agg-last fp8 128 + bias+BN+sigmoid -> bf16 h4
    gemm_fp8(abuf, 3, f8buf, 0);
    agg_fp8_kernel<2><<<ablocks, 256, 0, stream>>>(f8buf, row_ptr, e8,
        bvec[3], g[3], be[3], mm[3], vv[3], hbuf, n, 1);
    // L5 (128->128): GEMM5 raw -> fp8 hw5, agg-last fp8 128 + bias+sigmoid -> bf16 h5
    gemm_fp8(hbuf, 4, f8buf, 0);
    agg_fp8_kernel<2><<<ablocks, 256, 0, stream>>>(f8buf, row_ptr, e8,
        bvec[4], bvec[4], bvec[4], bvec[4], bvec[4], abuf, n, 2);

    // final h^T h with zeroed diagonal (MFMA)
    htht_mfma_kernel<<<KCH, 256, 0, stream>>>(abuf, partial, n);
    reduce_kernel<<<16384 / 256, 256, 0, stream>>>(partial, (float*)d_out, KCH);
}

// Round 14
// 408.097 us; speedup vs baseline: 1.5375x; 1.0356x over previous
//
#include <hip/hip_runtime.h>
#include <hip/hip_bf16.h>
#include <hip/hip_fp8.h>
#include <cstdint>
#include <cstddef>

typedef __hip_bfloat16 bf16;
typedef unsigned char fp8;                                  // e4m3 storage
typedef __attribute__((ext_vector_type(8))) short short8;   // 8 bf16 (MFMA A/B frag)
typedef __attribute__((ext_vector_type(4))) float f32x4;    // MFMA C/D frag
typedef __attribute__((ext_vector_type(2))) float f32x2;

#define NSF 128
#define BN_EPS 1e-3f
#define NR 4            // src ranges per node
#define SCK 2048        // elements per scan block

// ---------------- CSR build: 1 atomic per edge ----------------

__global__ void zero_fill_kernel(int* __restrict__ fill, int total) {
    int i = blockIdx.x * blockDim.x + threadIdx.x;
    if (i < total) fill[i] = 0;
}

__global__ void passA_kernel(const int* __restrict__ ei, int* __restrict__ fill,
                             int* __restrict__ loc, int E, int n, int rsize) {
    int idx = blockIdx.x * blockDim.x + threadIdx.x;
    if (idx < E) {
        int r = ei[idx];
        int c = ei[E + idx];
        int slot = c * NR + r / rsize;
        loc[idx] = atomicAdd(&fill[slot], 1);
    } else if (idx < E + n) {
        int i = idx - E;
        int slot = i * NR + i / rsize;
        loc[idx] = atomicAdd(&fill[slot], 1);
    }
}

// ---- hierarchical exclusive scan of fill -> row_ptr ----

__global__ void scan1_kernel(const int* __restrict__ cnt, int* __restrict__ blksum, int total) {
    __shared__ int red[256];
    int base = blockIdx.x * SCK + threadIdx.x * 8;
    int s = 0;
    #pragma unroll
    for (int i = 0; i < 8; ++i) {
        int idx = base + i;
        if (idx < total) s += cnt[idx];
    }
    red[threadIdx.x] = s;
    __syncthreads();
    for (int off2 = 128; off2 > 0; off2 >>= 1) {
        if (threadIdx.x < off2) red[threadIdx.x] += red[threadIdx.x + off2];
        __syncthreads();
    }
    if (threadIdx.x == 0) blksum[blockIdx.x] = red[0];
}

__global__ void scan2_kernel(int* __restrict__ blksum, int* __restrict__ row_ptr,
                             int nblk, int total) {
    __shared__ int part[256];
    int tid = threadIdx.x;
    int v = (tid < nblk) ? blksum[tid] : 0;
    part[tid] = v;
    __syncthreads();
    for (int off2 = 1; off2 < 256; off2 <<= 1) {
        int t = (tid >= off2) ? part[tid - off2] : 0;
        __syncthreads();
        part[tid] += t;
        __syncthreads();
    }
    if (tid < nblk) blksum[tid] = part[tid] - v;
    if (tid == 255) row_ptr[total] = part[255];
}

__global__ void scan3_kernel(const int* __restrict__ cnt, const int* __restrict__ blkoff,
                             int* __restrict__ row_ptr, int total) {
    __shared__ int part[256];
    int tid = threadIdx.x;
    int base = blockIdx.x * SCK + tid * 8;
    int loc[8]; int s = 0;
    #pragma unroll
    for (int i = 0; i < 8; ++i) {
        int idx = base + i;
        loc[i] = (idx < total) ? cnt[idx] : 0;
        s += loc[i];
    }
    part[tid] = s;
    __syncthreads();
    for (int off2 = 1; off2 < 256; off2 <<= 1) {
        int t = (tid >= off2) ? part[tid - off2] : 0;
        __syncthreads();
        part[tid] += t;
        __syncthreads();
    }
    int run = blkoff[blockIdx.x] + part[tid] - s;
    #pragma unroll
    for (int i = 0; i < 8; ++i) {
        int idx = base + i;
        if (idx < total) { row_ptr[idx] = run; run += loc[i]; }
    }
}

// passB: scatter without atomics; packed edge record {src, w_bits}
__global__ void passB_kernel(const int* __restrict__ ei, const float* __restrict__ ea,
                             const int* __restrict__ row_ptr, const int* __restrict__ loc,
                             int2* __restrict__ e8, int* __restrict__ csr_col,
                             int E, int n, int rsize) {
    int idx = blockIdx.x * blockDim.x + threadIdx.x;
    if (idx < E) {
        int r = ei[idx];
        int c = ei[E + idx];
        int slot = c * NR + r / rsize;
        int p = row_ptr[slot] + loc[idx];
        int2 rec; rec.x = r; rec.y = __float_as_int(ea[idx]);
        e8[p] = rec;
        csr_col[p] = c;
    } else if (idx < E + n) {
        int i = idx - E;
        int slot = i * NR + i / rsize;
        int p = row_ptr[slot] + loc[idx];
        int2 rec; rec.x = i; rec.y = __float_as_int(1.0f);
        e8[p] = rec;
        csr_col[p] = i;
    }
}

__global__ void degdinv_kernel(const int* __restrict__ row_ptr, const int2* __restrict__ e8,
                               float* __restrict__ dinv, int n) {
    int node = blockIdx.x * blockDim.x + threadIdx.x;
    if (node < n) {
        int s = row_ptr[node * NR], e = row_ptr[(node + 1) * NR];
        float d = 0.0f;
        for (int j = s; j < e; ++j) d += __int_as_float(e8[j].y);
        dinv[node] = (d > 0.0f) ? rsqrtf(d) : 0.0f;
    }
}

__global__ void normw_kernel(const float* __restrict__ dinv, const int* __restrict__ csr_col,
                             int2* __restrict__ e8, int EN) {
    int p = blockIdx.x * blockDim.x + threadIdx.x;
    if (p < EN) {
        int2 rec = e8[p];
        float w = dinv[rec.x] * __int_as_float(rec.y) * dinv[csr_col[p]];
        ((int*)e8)[2 * p + 1] = __float_as_int(w);
    }
}

// ---------------- output-type helpers (HW fp8 cvt) ----------------

__device__ inline void store_val(bf16* C, size_t idx, float a) {
    C[idx] = __float2bfloat16(a);
}
__device__ inline void store_val(fp8* C, size_t idx, float a) {
    int packed = __builtin_amdgcn_cvt_pk_fp8_f32(a, a, 0, false);
    C[idx] = (fp8)(packed & 0xff);
}

// ---------------- fused dtype prep: x->fp8 and all W->Wt(bf16) in one launch ----------------
// region [0, xcnt): xq[i] = fp8(x[i])
// region [xcnt, xcnt+wtelems): Wt conversion; layer found by offset compare.
__global__ void prep_kernel(const float* __restrict__ x, fp8* __restrict__ xq, int xcnt,
                            const float* __restrict__ W0, const float* __restrict__ W1,
                            const float* __restrict__ W2, const float* __restrict__ W3,
                            const float* __restrict__ W4,
                            bf16* __restrict__ wtbuf, int wtelems) {
    int idx = blockIdx.x * blockDim.x + threadIdx.x;
    if (idx < xcnt) {
        store_val(xq, idx, x[idx]);
        return;
    }
    int widx = idx - xcnt;
    if (widx >= wtelems) return;
    // layer boundaries (cumulative K*N): 32768, 163840, 294912, 327680, 344064
    const float* W; int K, N, off;
    if (widx < 32768)       { W = W0; K = 128; N = 256; off = 0; }
    else if (widx < 163840) { W = W1; K = 256; N = 512; off = 32768; }
    else if (widx < 294912) { W = W2; K = 512; N = 256; off = 163840; }
    else if (widx < 327680) { W = W3; K = 256; N = 128; off = 294912; }
    else                    { W = W4; K = 128; N = 128; off = 327680; }
    int l = widx - off;
    int nn = l / K, kk = l % K;
    wtbuf[widx] = __float2bfloat16(W[(size_t)kk * N + nn]);
}

// ---------------- direct global->LDS 16B staging ----------------

__device__ inline void gl_lds16(const bf16* g, bf16* l) {
    __builtin_amdgcn_global_load_lds(
        (const __attribute__((address_space(1))) void*)g,
        (__attribute__((address_space(3))) void*)l,
        16, 0, 0);
}

// ---------------- MFMA GEMM: C[M,N] = A[M,K] @ Wt[N,K]^T, fused epilogue ----------------
// mode 0: raw store; mode 1: sigmoid(BN(acc+bias))

template <typename OT>
__global__ __launch_bounds__(256) void mfma_gemm_kernel(
    const bf16* __restrict__ A, const bf16* __restrict__ Wt,
    OT* __restrict__ C, int M, int K, int N, int mode,
    const float* __restrict__ bias, const float* __restrict__ g,
    const float* __restrict__ be, const float* __restrict__ m,
    const float* __restrict__ v) {
    __shared__ bf16 As[64][32];
    __shared__ bf16 Bs[128][32];
    int m0 = blockIdx.x * 64;
    int n0 = blockIdx.y * 128;
    int tid = threadIdx.x;
    int wave = tid >> 6, lane = tid & 63;
    int lrow = lane & 15, quad = lane >> 4;

    f32x4 acc[8] = {};

    int srow = lane >> 2;
    int sseg = lane & 3;
    int am = wave * 16 + srow;
    int bn = wave * 32 + srow;
    bool aok = (m0 + am) < M;

    for (int k0 = 0; k0 < K; k0 += 32) {
        if (aok)
            gl_lds16(A + (size_t)(m0 + am) * K + k0 + sseg * 8, &As[am][sseg * 8]);
        gl_lds16(Wt + (size_t)(n0 + bn) * K + k0 + sseg * 8, &Bs[bn][sseg * 8]);
        gl_lds16(Wt + (size_t)(n0 + bn + 16) * K + k0 + sseg * 8, &Bs[bn + 16][sseg * 8]);
        __syncthreads();

        short8 afrag = *(const short8*)(&As[wave * 16 + lrow][quad * 8]);
        #pragma unroll
        for (int t = 0; t < 8; ++t) {
            short8 bfrag = *(const short8*)(&Bs[t * 16 + lrow][quad * 8]);
            acc[t] = __builtin_amdgcn_mfma_f32_16x16x32_bf16(afrag, bfrag, acc[t], 0, 0, 0);
        }
        __syncthreads();
    }
    #pragma unroll
    for (int t = 0; t < 8; ++t) {
        int gn = n0 + t * 16 + lrow;
        float bsc = 0.0f, scale = 1.0f, mean = 0.0f, beta = 0.0f;
        if (mode == 1) {
            bsc = bias[gn];
            scale = g[gn] * rsqrtf(v[gn] + BN_EPS);
            mean = m[gn];
            beta = be[gn];
        }
        #pragma unroll
        for (int rr = 0; rr < 4; ++rr) {
            int gm = m0 + wave * 16 + quad * 4 + rr;
            if (gm < M) {
                float a = acc[t][rr];
                if (mode == 1) {
                    a = (a + bsc - mean) * scale + beta;
                    a = 1.0f / (1.0f + __expf(-a));
                }
                store_val(C, (size_t)gm * N + gn, a);
            }
        }
    }
}

// ---------------- fp8 aggregation with HW cvt (unroll-8 + 4 + tail) ----------------

template <int VEC> struct F8Vec;
template <> struct F8Vec<2> { typedef unsigned short T; };
template <> struct F8Vec<4> { typedef unsigned int T; };

__device__ inline void fma_f8(unsigned short q, float w, float* acc) {
    f32x2 lo = __builtin_amdgcn_cvt_pk_f32_fp8((unsigned int)q, false);
    acc[0] += w * lo.x;
    acc[1] += w * lo.y;
}
__device__ inline void fma_f8(unsigned int q, float w, float* acc) {
    f32x2 lo = __builtin_amdgcn_cvt_pk_f32_fp8(q, false);
    f32x2 hi = __builtin_amdgcn_cvt_pk_f32_fp8(q, true);
    acc[0] += w * lo.x;
    acc[1] += w * lo.y;
    acc[2] += w * hi.x;
    acc[3] += w * hi.y;
}

template <int VEC>
__global__ __launch_bounds__(256) void agg_fp8_kernel(
    const fp8* __restrict__ hw,
    const int* __restrict__ row_ptr, const int2* __restrict__ e8,
    const float* __restrict__ bias,
    const float* __restrict__ g, const float* __restrict__ be,
    const float* __restrict__ m, const float* __restrict__ v,
    bf16* __restrict__ out, int n, int mode) {
    typedef typename F8Vec<VEC>::T T;
    const int dfeat = VEC * 64;
    int wave = threadIdx.x >> 6;
    int lane = threadIdx.x & 63;
    int node = blockIdx.x * 4 + wave;
    if (node >= n) return;
    int s = row_ptr[node * NR], e = row_ptr[(node + 1) * NR];
    float acc[VEC];
    #pragma unroll
    for (int i = 0; i < VEC; ++i) acc[i] = 0.0f;
    const size_t base = (size_t)lane * VEC;

    int j = s;
    for (; j + 7 < e; j += 8) {
        int2 ew[8];
        #pragma unroll
        for (int u = 0; u < 8; ++u) ew[u] = e8[j + u];
        T q[8];
        #pragma unroll
        for (int u = 0; u < 8; ++u)
            q[u] = *(const T*)(hw + (size_t)ew[u].x * dfeat + base);
        #pragma unroll
        for (int u = 0; u < 8; ++u)
            fma_f8(q[u], __int_as_float(ew[u].y), acc);
    }
    for (; j + 3 < e; j += 4) {
        int2 ew[4];
        #pragma unroll
        for (int u = 0; u < 4; ++u) ew[u] = e8[j + u];
        T q[4];
        #pragma unroll
        for (int u = 0; u < 4; ++u)
            q[u] = *(const T*)(hw + (size_t)ew[u].x * dfeat + base);
        #pragma unroll
        for (int u = 0; u < 4; ++u)
            fma_f8(q[u], __int_as_float(ew[u].y), acc);
    }
    for (; j < e; ++j) {
        int2 ew = e8[j];
        T q = *(const T*)(hw + (size_t)ew.x * dfeat + base);
        fma_f8(q, __int_as_float(ew.y), acc);
    }

    #pragma unroll
    for (int i = 0; i < VEC; ++i) {
        int f = (int)base + i;
        float a = acc[i];
        if (mode != 0) {
            a += bias[f];
            if (mode == 1) {
                float scale = g[f] * rsqrtf(v[f] + BN_EPS);
                a = (a - m[f]) * scale + be[f];
            }
            a = 1.0f / (1.0f + __expf(-a));
        }
        out[(size_t)node * dfeat + f] = __float2bfloat16(a);
    }
}

// ---------------- final h^T h via MFMA ----------------
#define TPAD 8

__global__ __launch_bounds__(256) void htht_mfma_kernel(
    const bf16* __restrict__ h, float* __restrict__ partial, int n) {
    __shared__ bf16 hsT[128][32 + TPAD];
    int b = blockIdx.x;
    int tid = threadIdx.x;
    int wave = tid >> 6, lane = tid & 63;
    int lrow = lane & 15, quad = lane >> 4;

    f32x4 acc[2][8] = {};

    int kk = tid >> 3;
    int seg = tid & 7;

    for (int kt = 0; kt < 8; ++kt) {
        int k0 = b * 256 + kt * 32;
        #pragma unroll
        for (int s2 = 0; s2 < 2; ++s2) {
            int fs = (seg + s2 * 8) * 8;
            int gk = k0 + kk;
            uint4 q; q.x = q.y = q.z = q.w = 0u;
            if (gk < n) q = *(const uint4*)(h + (size_t)gk * 128 + fs);
            const unsigned short* u = (const unsigned short*)&q;
            #pragma unroll
            for (int i = 0; i < 8; ++i)
                *((unsigned short*)&hsT[fs + i][kk]) = u[i];
        }
        __syncthreads();
        short8 af0 = *(const short8*)(&hsT[wave * 32 + lrow][quad * 8]);
        short8 af1 = *(const short8*)(&hsT[wave * 32 + 16 + lrow][quad * 8]);
        #pragma unroll
        for (int t = 0; t < 8; ++t) {
            short8 bfrag = *(const short8*)(&hsT[t * 16 + lrow][quad * 8]);
            acc[0][t] = __builtin_amdgcn_mfma_f32_16x16x32_bf16(af0, bfrag, acc[0][t], 0, 0, 0);
            acc[1][t] = __builtin_amdgcn_mfma_f32_16x16x32_bf16(af1, bfrag, acc[1][t], 0, 0, 0);
        }
        __syncthreads();
    }
    float* p = partial + (size_t)b * 16384;
    #pragma unroll
    for (int a_ = 0; a_ < 2; ++a_) {
        #pragma unroll
        for (int t = 0; t < 8; ++t) {
            #pragma unroll
            for (int rr = 0; rr < 4; ++rr) {
                int gm = wave * 32 + a_ * 16 + quad * 4 + rr;
                int gn = t * 16 + lrow;
                p[gm * 128 + gn] = acc[a_][t][rr];
            }
        }
    }
}

__global__ void reduce_kernel(const float* __restrict__ partial, float* __restrict__ out, int nchunks) {
    int idx = blockIdx.x * blockDim.x + threadIdx.x;
    float s = 0.0f;
    for (int c = 0; c < nchunks; ++c) s += partial[(size_t)c * 16384 + idx];
    int i = idx / 128, j = idx % 128;
    out[idx] = (i == j) ? 0.0f : s;
}

// ---------------- launch ----------------
extern "C" void kernel_launch(void* const* d_in, const int* in_sizes, int n_in,
                              void* d_out, int out_size, void* d_ws, size_t ws_size,
                              hipStream_t stream) {
    const float* x  = (const float*)d_in[0];
    const int*   ei = (const int*)d_in[1];
    const float* ea = (const float*)d_in[2];
    const float* W[5];  const float* bvec[5];
    for (int l = 0; l < 5; ++l) { W[l] = (const float*)d_in[3 + 2 * l]; bvec[l] = (const float*)d_in[4 + 2 * l]; }
    const float* g[4]; const float* be[4]; const float* mm[4]; const float* vv[4];
    for (int l = 0; l < 4; ++l) {
        g[l]  = (const float*)d_in[13 + 4 * l];
        be[l] = (const float*)d_in[14 + 4 * l];
        mm[l] = (const float*)d_in[15 + 4 * l];
        vv[l] = (const float*)d_in[16 + 4 * l];
    }
    const int n = in_sizes[0] / NSF;        // 20000
    const int E = in_sizes[1] / 2;          // 500000
    const int EN = E + n;
    const int rsize = (n + NR - 1) / NR;
    const int total = n * NR;
    const int nscan = (total + SCK - 1) / SCK;
    const int dims[6] = {128, 256, 512, 256, 128, 128};
    const int wtoff[5] = {0, 32768, 163840, 294912, 327680};
    const int wtelems = 344064;

    // workspace layout (256B aligned); ~69 MB
    auto align = [](size_t o) { return (o + 255) & ~(size_t)255; };
    size_t off = 0;
    float* dinv    = (float*)((char*)d_ws + off); off = align(off + (size_t)n * 4);
    int*   fill    = (int*)  ((char*)d_ws + off); off = align(off + (size_t)total * 4);
    int*   row_ptr = (int*)  ((char*)d_ws + off); off = align(off + ((size_t)total + 1) * 4);
    int*   blksum  = (int*)  ((char*)d_ws + off); off = align(off + (size_t)256 * 4);
    int*   locb    = (int*)  ((char*)d_ws + off); off = align(off + (size_t)EN * 4);
    int2*  e8      = (int2*) ((char*)d_ws + off); off = align(off + (size_t)EN * 8);
    int*   csr_col = (int*)  ((char*)d_ws + off); off = align(off + (size_t)EN * 4);
    bf16*  wtbuf   = (bf16*) ((char*)d_ws + off); off = align(off + (size_t)wtelems * 2);
    fp8*   xq      = (fp8*)  ((char*)d_ws + off); off = align(off + (size_t)n * 128);
    bf16*  hbuf    = (bf16*) ((char*)d_ws + off); off = align(off + (size_t)n * 512 * 2);
    bf16*  abuf    = (bf16*) ((char*)d_ws + off); off = align(off + (size_t)n * 512 * 2);
    fp8*   f8buf   = (fp8*)  ((char*)d_ws + off); off = align(off + (size_t)n * 256);
    const int KCH = (20000 + 255) / 256;    // 79
    float* partial = (float*)((char*)d_ws + off); off = align(off + (size_t)KCH * 16384 * 4);

    // CSR build (1 atomic/edge, packed edge records)
    zero_fill_kernel<<<(total + 255) / 256, 256, 0, stream>>>(fill, total);
    passA_kernel<<<(EN + 255) / 256, 256, 0, stream>>>(ei, fill, locb, E, n, rsize);
    scan1_kernel<<<nscan, 256, 0, stream>>>(fill, blksum, total);
    scan2_kernel<<<1, 256, 0, stream>>>(blksum, row_ptr, nscan, total);
    scan3_kernel<<<nscan, 256, 0, stream>>>(fill, blksum, row_ptr, total);
    passB_kernel<<<(EN + 255) / 256, 256, 0, stream>>>(ei, ea, row_ptr, locb,
                                                       e8, csr_col, E, n, rsize);
    degdinv_kernel<<<(n + 255) / 256, 256, 0, stream>>>(row_ptr, e8, dinv, n);
    normw_kernel<<<(EN + 255) / 256, 256, 0, stream>>>(dinv, csr_col, e8, EN);

    // fused dtype prep: x->fp8 + all W->Wt
    {
        int xcnt = n * 128;
        int items = xcnt + wtelems;
        prep_kernel<<<(items + 255) / 256, 256, 0, stream>>>(x, xq, xcnt,
            W[0], W[1], W[2], W[3], W[4], wtbuf, wtelems);
    }

    int ablocks = (n + 3) / 4;
    auto gemm_bf16 = [&](const bf16* A, int l, bf16* C, int mode) {
        int K = dims[l], N = dims[l + 1];
        dim3 gg((n + 63) / 64, N / 128);
        int bi = (l < 4) ? l : 0;
        mfma_gemm_kernel<bf16><<<gg, 256, 0, stream>>>(A, wtbuf + wtoff[l], C, n, K, N, mode,
                                                       bvec[l], g[bi], be[bi], mm[bi], vv[bi]);
    };
    auto gemm_fp8 = [&](const bf16* A, int l, fp8* C, int mode) {
        int K = dims[l], N = dims[l + 1];
        dim3 gg((n + 63) / 64, N / 128);
        int bi = (l < 4) ? l : 0;
        mfma_gemm_kernel<fp8><<<gg, 256, 0, stream>>>(A, wtbuf + wtoff[l], C, n, K, N, mode,
                                                      bvec[l], g[bi], be[bi], mm[bi], vv[bi]);
    };

    // L1 (128->256): agg-first fp8 128 (xq), GEMM1 fused act -> fp8 h1
    agg_fp8_kernel<2><<<ablocks, 256, 0, stream>>>(xq, row_ptr, e8,
        bvec[0], bvec[0], bvec[0], bvec[0], bvec[0], abuf, n, 0);
    gemm_fp8(abuf, 0, f8buf, 1);
    // L2 (256->512): agg-first fp8 256 (h1) -> bf16, GEMM2 fused act -> bf16 h2 (512)
    agg_fp8_kernel<4><<<ablocks, 256, 0, stream>>>(f8buf, row_ptr, e8,
        bvec[1], bvec[1], bvec[1], bvec[1], bvec[1], abuf, n, 0);
    gemm_bf16(abuf, 1, hbuf, 1);
    // L3 (512->256): GEMM3 raw -> fp8 hw3, agg-last fp8 256 + bias+BN+sigmoid -> bf16 h3
    gemm_fp8(hbuf, 2, f8buf, 0);
    agg_fp8_kernel<4><<<ablocks, 256, 0, stream>>>(f8buf, row_ptr, e8,
        bvec[2], g[2], be[2], mm[2], vv[2], abuf, n, 1);
    // L4 (256->128): GEMM4 raw -> fp8 hw4, agg-last fp8 128 + bias+BN+sigmoid -> bf16 h4
    gemm_fp8(abuf, 3, f8buf, 0);
    agg_fp8_kernel<2><<<ablocks, 256, 0, stream>>>(f8buf, row_ptr, e8,
        bvec[3], g[3], be[3], mm[3], vv[3], hbuf, n, 1);
    // L5 (128->128): GEMM5 raw -> fp8 hw5, agg-last fp8 128 + bias+sigmoid -> bf16 h5
    gemm_fp8(hbuf, 4, f8buf, 0);
    agg_fp8_kernel<2><<<ablocks, 256, 0, stream>>>(f8buf, row_ptr, e8,
        bvec[4], bvec[4], bvec[4], bvec[4], bvec[4], abuf, n, 2);

    // final h^T h with zeroed diagonal (MFMA)
    htht_mfma_kernel<<<KCH, 256, 0, stream>>>(abuf, partial, n);
    reduce_kernel<<<16384 / 256, 256, 0, stream>>>(partial, (float*)d_out, KCH);
}

// Round 15
// 400.448 us; speedup vs baseline: 1.5669x; 1.0191x over previous
//
#include <hip/hip_runtime.h>
#include <hip/hip_bf16.h>
#include <hip/hip_fp8.h>
#include <cstdint>
#include <cstddef>

typedef __hip_bfloat16 bf16;
typedef unsigned char fp8;                                  // e4m3 storage
typedef __attribute__((ext_vector_type(8))) short short8;   // 8 bf16 (MFMA A/B frag)
typedef __attribute__((ext_vector_type(4))) float f32x4;    // MFMA C/D frag
typedef __attribute__((ext_vector_type(2))) float f32x2;

#define NSF 128
#define BN_EPS 1e-3f
#define NR 4            // src ranges per node
#define SCK 2048        // elements per scan block

// ---------------- CSR build: 1 atomic per edge ----------------

__global__ void passA_kernel(const int* __restrict__ ei, int* __restrict__ fill,
                             int* __restrict__ loc, int E, int n, int rsize) {
    int idx = blockIdx.x * blockDim.x + threadIdx.x;
    if (idx < E) {
        int r = ei[idx];
        int c = ei[E + idx];
        int slot = c * NR + r / rsize;
        loc[idx] = atomicAdd(&fill[slot], 1);
    } else if (idx < E + n) {
        int i = idx - E;
        int slot = i * NR + i / rsize;
        loc[idx] = atomicAdd(&fill[slot], 1);
    }
}

// ---- hierarchical exclusive scan of fill -> row_ptr ----

__global__ void scan1_kernel(const int* __restrict__ cnt, int* __restrict__ blksum, int total) {
    __shared__ int red[256];
    int base = blockIdx.x * SCK + threadIdx.x * 8;
    int s = 0;
    #pragma unroll
    for (int i = 0; i < 8; ++i) {
        int idx = base + i;
        if (idx < total) s += cnt[idx];
    }
    red[threadIdx.x] = s;
    __syncthreads();
    for (int off2 = 128; off2 > 0; off2 >>= 1) {
        if (threadIdx.x < off2) red[threadIdx.x] += red[threadIdx.x + off2];
        __syncthreads();
    }
    if (threadIdx.x == 0) blksum[blockIdx.x] = red[0];
}

__global__ void scan2_kernel(int* __restrict__ blksum, int* __restrict__ row_ptr,
                             int nblk, int total) {
    __shared__ int part[256];
    int tid = threadIdx.x;
    int v = (tid < nblk) ? blksum[tid] : 0;
    part[tid] = v;
    __syncthreads();
    for (int off2 = 1; off2 < 256; off2 <<= 1) {
        int t = (tid >= off2) ? part[tid - off2] : 0;
        __syncthreads();
        part[tid] += t;
        __syncthreads();
    }
    if (tid < nblk) blksum[tid] = part[tid] - v;
    if (tid == 255) row_ptr[total] = part[255];
}

__global__ void scan3_kernel(const int* __restrict__ cnt, const int* __restrict__ blkoff,
                             int* __restrict__ row_ptr, int total) {
    __shared__ int part[256];
    int tid = threadIdx.x;
    int base = blockIdx.x * SCK + tid * 8;
    int loc[8]; int s = 0;
    #pragma unroll
    for (int i = 0; i < 8; ++i) {
        int idx = base + i;
        loc[i] = (idx < total) ? cnt[idx] : 0;
        s += loc[i];
    }
    part[tid] = s;
    __syncthreads();
    for (int off2 = 1; off2 < 256; off2 <<= 1) {
        int t = (tid >= off2) ? part[tid - off2] : 0;
        __syncthreads();
        part[tid] += t;
        __syncthreads();
    }
    int run = blkoff[blockIdx.x] + part[tid] - s;
    #pragma unroll
    for (int i = 0; i < 8; ++i) {
        int idx = base + i;
        if (idx < total) { row_ptr[idx] = run; run += loc[i]; }
    }
}

// passB: scatter without atomics; packed edge record {src, w_bits}
__global__ void passB_kernel(const int* __restrict__ ei, const float* __restrict__ ea,
                             const int* __restrict__ row_ptr, const int* __restrict__ loc,
                             int2* __restrict__ e8, int* __restrict__ csr_col,
                             int E, int n, int rsize) {
    int idx = blockIdx.x * blockDim.x + threadIdx.x;
    if (idx < E) {
        int r = ei[idx];
        int c = ei[E + idx];
        int slot = c * NR + r / rsize;
        int p = row_ptr[slot] + loc[idx];
        int2 rec; rec.x = r; rec.y = __float_as_int(ea[idx]);
        e8[p] = rec;
        csr_col[p] = c;
    } else if (idx < E + n) {
        int i = idx - E;
        int slot = i * NR + i / rsize;
        int p = row_ptr[slot] + loc[idx];
        int2 rec; rec.x = i; rec.y = __float_as_int(1.0f);
        e8[p] = rec;
        csr_col[p] = i;
    }
}

__global__ void degdinv_kernel(const int* __restrict__ row_ptr, const int2* __restrict__ e8,
                               float* __restrict__ dinv, int n) {
    int node = blockIdx.x * blockDim.x + threadIdx.x;
    if (node < n) {
        int s = row_ptr[node * NR], e = row_ptr[(node + 1) * NR];
        float d = 0.0f;
        for (int j = s; j < e; ++j) d += __int_as_float(e8[j].y);
        dinv[node] = (d > 0.0f) ? rsqrtf(d) : 0.0f;
    }
}

__global__ void normw_kernel(const float* __restrict__ dinv, const int* __restrict__ csr_col,
                             int2* __restrict__ e8, int EN) {
    int p = blockIdx.x * blockDim.x + threadIdx.x;
    if (p < EN) {
        int2 rec = e8[p];
        float w = dinv[rec.x] * __int_as_float(rec.y) * dinv[csr_col[p]];
        ((int*)e8)[2 * p + 1] = __float_as_int(w);
    }
}

// ---------------- output-type helpers (HW fp8 cvt) ----------------

__device__ inline void store_val(bf16* C, size_t idx, float a) {
    C[idx] = __float2bfloat16(a);
}
__device__ inline void store_val(fp8* C, size_t idx, float a) {
    int packed = __builtin_amdgcn_cvt_pk_fp8_f32(a, a, 0, false);
    C[idx] = (fp8)(packed & 0xff);
}

// ---------------- fused prep: zero fill[] + x->fp8 + all W->Wt(bf16), one launch ----------------
__global__ void prep_kernel(int* __restrict__ fill, int total,
                            const float* __restrict__ x, fp8* __restrict__ xq, int xcnt,
                            const float* __restrict__ W0, const float* __restrict__ W1,
                            const float* __restrict__ W2, const float* __restrict__ W3,
                            const float* __restrict__ W4,
                            bf16* __restrict__ wtbuf, int wtelems) {
    int idx = blockIdx.x * blockDim.x + threadIdx.x;
    if (idx < total) { fill[idx] = 0; return; }
    idx -= total;
    if (idx < xcnt) {
        store_val(xq, idx, x[idx]);
        return;
    }
    int widx = idx - xcnt;
    if (widx >= wtelems) return;
    // layer boundaries (cumulative K*N): 32768, 163840, 294912, 327680, 344064
    const float* W; int K, off;
    if (widx < 32768)       { W = W0; K = 128; off = 0; }
    else if (widx < 163840) { W = W1; K = 256; off = 32768; }
    else if (widx < 294912) { W = W2; K = 512; off = 163840; }
    else if (widx < 327680) { W = W3; K = 256; off = 294912; }
    else                    { W = W4; K = 128; off = 327680; }
    int N2;
    if (widx < 32768) N2 = 256; else if (widx < 163840) N2 = 512;
    else if (widx < 294912) N2 = 256; else N2 = 128;
    int l = widx - off;
    int nn = l / K, kk = l % K;
    wtbuf[widx] = __float2bfloat16(W[(size_t)kk * N2 + nn]);
}

// ---------------- direct global->LDS 16B staging ----------------

__device__ inline void gl_lds16(const bf16* g, bf16* l) {
    __builtin_amdgcn_global_load_lds(
        (const __attribute__((address_space(1))) void*)g,
        (__attribute__((address_space(3))) void*)l,
        16, 0, 0);
}

// ---------------- MFMA GEMM: C[M,N] = A[M,K] @ Wt[N,K]^T, fused epilogue ----------------
// mode 0: raw store; mode 1: sigmoid(BN(acc+bias))
// Wave->tile remap (round 15): wave w computes ALL 64 rows x cols [w*32, w*32+32):
// 4 afrags + 2 bfrags = 6 ds_read_b128 per 32-K (was 9), same 8 MFMAs. Staging unchanged.

template <typename OT>
__global__ __launch_bounds__(256) void mfma_gemm_kernel(
    const bf16* __restrict__ A, const bf16* __restrict__ Wt,
    OT* __restrict__ C, int M, int K, int N, int mode,
    const float* __restrict__ bias, const float* __restrict__ g,
    const float* __restrict__ be, const float* __restrict__ m,
    const float* __restrict__ v) {
    __shared__ bf16 As[64][32];
    __shared__ bf16 Bs[128][32];
    int m0 = blockIdx.x * 64;
    int n0 = blockIdx.y * 128;
    int tid = threadIdx.x;
    int wave = tid >> 6, lane = tid & 63;
    int lrow = lane & 15, quad = lane >> 4;

    f32x4 acc[4][2] = {};   // [m-tile][n-tile]

    int srow = lane >> 2;
    int sseg = lane & 3;
    int am = wave * 16 + srow;
    int bn = wave * 32 + srow;
    bool aok = (m0 + am) < M;

    for (int k0 = 0; k0 < K; k0 += 32) {
        if (aok)
            gl_lds16(A + (size_t)(m0 + am) * K + k0 + sseg * 8, &As[am][sseg * 8]);
        gl_lds16(Wt + (size_t)(n0 + bn) * K + k0 + sseg * 8, &Bs[bn][sseg * 8]);
        gl_lds16(Wt + (size_t)(n0 + bn + 16) * K + k0 + sseg * 8, &Bs[bn + 16][sseg * 8]);
        __syncthreads();

        short8 afrag[4], bfrag[2];
        #pragma unroll
        for (int mt = 0; mt < 4; ++mt)
            afrag[mt] = *(const short8*)(&As[mt * 16 + lrow][quad * 8]);
        #pragma unroll
        for (int nt = 0; nt < 2; ++nt)
            bfrag[nt] = *(const short8*)(&Bs[wave * 32 + nt * 16 + lrow][quad * 8]);
        #pragma unroll
        for (int mt = 0; mt < 4; ++mt)
            #pragma unroll
            for (int nt = 0; nt < 2; ++nt)
                acc[mt][nt] = __builtin_amdgcn_mfma_f32_16x16x32_bf16(
                    afrag[mt], bfrag[nt], acc[mt][nt], 0, 0, 0);
        __syncthreads();
    }
    // C/D: col = lane&15, row = quad*4 + reg
    #pragma unroll
    for (int nt = 0; nt < 2; ++nt) {
        int gn = n0 + wave * 32 + nt * 16 + lrow;
        float bsc = 0.0f, scale = 1.0f, mean = 0.0f, beta = 0.0f;
        if (mode == 1) {
            bsc = bias[gn];
            scale = g[gn] * rsqrtf(v[gn] + BN_EPS);
            mean = m[gn];
            beta = be[gn];
        }
        #pragma unroll
        for (int mt = 0; mt < 4; ++mt) {
            #pragma unroll
            for (int rr = 0; rr < 4; ++rr) {
                int gm = m0 + mt * 16 + quad * 4 + rr;
                if (gm < M) {
                    float a = acc[mt][nt][rr];
                    if (mode == 1) {
                        a = (a + bsc - mean) * scale + beta;
                        a = 1.0f / (1.0f + __expf(-a));
                    }
                    store_val(C, (size_t)gm * N + gn, a);
                }
            }
        }
    }
}

// ---------------- fp8 aggregation with HW cvt (unroll-8 + 4 + tail) ----------------

template <int VEC> struct F8Vec;
template <> struct F8Vec<2> { typedef unsigned short T; };
template <> struct F8Vec<4> { typedef unsigned int T; };

__device__ inline void fma_f8(unsigned short q, float w, float* acc) {
    f32x2 lo = __builtin_amdgcn_cvt_pk_f32_fp8((unsigned int)q, false);
    acc[0] += w * lo.x;
    acc[1] += w * lo.y;
}
__device__ inline void fma_f8(unsigned int q, float w, float* acc) {
    f32x2 lo = __builtin_amdgcn_cvt_pk_f32_fp8(q, false);
    f32x2 hi = __builtin_amdgcn_cvt_pk_f32_fp8(q, true);
    acc[0] += w * lo.x;
    acc[1] += w * lo.y;
    acc[2] += w * hi.x;
    acc[3] += w * hi.y;
}

template <int VEC>
__global__ __launch_bounds__(256) void agg_fp8_kernel(
    const fp8* __restrict__ hw,
    const int* __restrict__ row_ptr, const int2* __restrict__ e8,
    const float* __restrict__ bias,
    const float* __restrict__ g, const float* __restrict__ be,
    const float* __restrict__ m, const float* __restrict__ v,
    bf16* __restrict__ out, int n, int mode) {
    typedef typename F8Vec<VEC>::T T;
    const int dfeat = VEC * 64;
    int wave = threadIdx.x >> 6;
    int lane = threadIdx.x & 63;
    int node = blockIdx.x * 4 + wave;
    if (node >= n) return;
    int s = row_ptr[node * NR], e = row_ptr[(node + 1) * NR];
    float acc[VEC];
    #pragma unroll
    for (int i = 0; i < VEC; ++i) acc[i] = 0.0f;
    const size_t base = (size_t)lane * VEC;

    int j = s;
    for (; j + 7 < e; j += 8) {
        int2 ew[8];
        #pragma unroll
        for (int u = 0; u < 8; ++u) ew[u] = e8[j + u];
        T q[8];
        #pragma unroll
        for (int u = 0; u < 8; ++u)
            q[u] = *(const T*)(hw + (size_t)ew[u].x * dfeat + base);
        #pragma unroll
        for (int u = 0; u < 8; ++u)
            fma_f8(q[u], __int_as_float(ew[u].y), acc);
    }
    for (; j + 3 < e; j += 4) {
        int2 ew[4];
        #pragma unroll
        for (int u = 0; u < 4; ++u) ew[u] = e8[j + u];
        T q[4];
        #pragma unroll
        for (int u = 0; u < 4; ++u)
            q[u] = *(const T*)(hw + (size_t)ew[u].x * dfeat + base);
        #pragma unroll
        for (int u = 0; u < 4; ++u)
            fma_f8(q[u], __int_as_float(ew[u].y), acc);
    }
    for (; j < e; ++j) {
        int2 ew = e8[j];
        T q = *(const T*)(hw + (size_t)ew.x * dfeat + base);
        fma_f8(q, __int_as_float(ew.y), acc);
    }

    #pragma unroll
    for (int i = 0; i < VEC; ++i) {
        int f = (int)base + i;
        float a = acc[i];
        if (mode != 0) {
            a += bias[f];
            if (mode == 1) {
                float scale = g[f] * rsqrtf(v[f] + BN_EPS);
                a = (a - m[f]) * scale + be[f];
            }
            a = 1.0f / (1.0f + __expf(-a));
        }
        out[(size_t)node * dfeat + f] = __float2bfloat16(a);
    }
}

// ---------------- final h^T h via MFMA ----------------
#define TPAD 8

__global__ __launch_bounds__(256) void htht_mfma_kernel(
    const bf16* __restrict__ h, float* __restrict__ partial, int n) {
    __shared__ bf16 hsT[128][32 + TPAD];
    int b = blockIdx.x;
    int tid = threadIdx.x;
    int wave = tid >> 6, lane = tid & 63;
    int lrow = lane & 15, quad = lane >> 4;

    f32x4 acc[2][8] = {};

    int kk = tid >> 3;
    int seg = tid & 7;

    for (int kt = 0; kt < 8; ++kt) {
        int k0 = b * 256 + kt * 32;
        #pragma unroll
        for (int s2 = 0; s2 < 2; ++s2) {
            int fs = (seg + s2 * 8) * 8;
            int gk = k0 + kk;
            uint4 q; q.x = q.y = q.z = q.w = 0u;
            if (gk < n) q = *(const uint4*)(h + (size_t)gk * 128 + fs);
            const unsigned short* u = (const unsigned short*)&q;
            #pragma unroll
            for (int i = 0; i < 8; ++i)
                *((unsigned short*)&hsT[fs + i][kk]) = u[i];
        }
        __syncthreads();
        short8 af0 = *(const short8*)(&hsT[wave * 32 + lrow][quad * 8]);
        short8 af1 = *(const short8*)(&hsT[wave * 32 + 16 + lrow][quad * 8]);
        #pragma unroll
        for (int t = 0; t < 8; ++t) {
            short8 bfrag = *(const short8*)(&hsT[t * 16 + lrow][quad * 8]);
            acc[0][t] = __builtin_amdgcn_mfma_f32_16x16x32_bf16(af0, bfrag, acc[0][t], 0, 0, 0);
            acc[1][t] = __builtin_amdgcn_mfma_f32_16x16x32_bf16(af1, bfrag, acc[1][t], 0, 0, 0);
        }
        __syncthreads();
    }
    float* p = partial + (size_t)b * 16384;
    #pragma unroll
    for (int a_ = 0; a_ < 2; ++a_) {
        #pragma unroll
        for (int t = 0; t < 8; ++t) {
            #pragma unroll
            for (int rr = 0; rr < 4; ++rr) {
                int gm = wave * 32 + a_ * 16 + quad * 4 + rr;
                int gn = t * 16 + lrow;
                p[gm * 128 + gn] = acc[a_][t][rr];
            }
        }
    }
}

__global__ void reduce_kernel(const float* __restrict__ partial, float* __restrict__ out, int nchunks) {
    int idx = blockIdx.x * blockDim.x + threadIdx.x;
    float s = 0.0f;
    for (int c = 0; c < nchunks; ++c) s += partial[(size_t)c * 16384 + idx];
    int i = idx / 128, j = idx % 128;
    out[idx] = (i == j) ? 0.0f : s;
}

// ---------------- launch ----------------
extern "C" void kernel_launch(void* const* d_in, const int* in_sizes, int n_in,
                              void* d_out, int out_size, void* d_ws, size_t ws_size,
                              hipStream_t stream) {
    const float* x  = (const float*)d_in[0];
    const int*   ei = (const int*)d_in[1];
    const float* ea = (const float*)d_in[2];
    const float* W[5];  const float* bvec[5];
    for (int l = 0; l < 5; ++l) { W[l] = (const float*)d_in[3 + 2 * l]; bvec[l] = (const float*)d_in[4 + 2 * l]; }
    const float* g[4]; const float* be[4]; const float* mm[4]; const float* vv[4];
    for (int l = 0; l < 4; ++l) {
        g[l]  = (const float*)d_in[13 + 4 * l];
        be[l] = (const float*)d_in[14 + 4 * l];
        mm[l] = (const float*)d_in[15 + 4 * l];
        vv[l] = (const float*)d_in[16 + 4 * l];
    }
    const int n = in_sizes[0] / NSF;        // 20000
    const int E = in_sizes[1] / 2;          // 500000
    const int EN = E + n;
    const int rsize = (n + NR - 1) / NR;
    const int total = n * NR;
    const int nscan = (total + SCK - 1) / SCK;
    const int dims[6] = {128, 256, 512, 256, 128, 128};
    const int wtoff[5] = {0, 32768, 163840, 294912, 327680};
    const int wtelems = 344064;

    // workspace layout (256B aligned); ~69 MB
    auto align = [](size_t o) { return (o + 255) & ~(size_t)255; };
    size_t off = 0;
    float* dinv    = (float*)((char*)d_ws + off); off = align(off + (size_t)n * 4);
    int*   fill    = (int*)  ((char*)d_ws + off); off = align(off + (size_t)total * 4);
    int*   row_ptr = (int*)  ((char*)d_ws + off); off = align(off + ((size_t)total + 1) * 4);
    int*   blksum  = (int*)  ((char*)d_ws + off); off = align(off + (size_t)256 * 4);
    int*   locb    = (int*)  ((char*)d_ws + off); off = align(off + (size_t)EN * 4);
    int2*  e8      = (int2*) ((char*)d_ws + off); off = align(off + (size_t)EN * 8);
    int*   csr_col = (int*)  ((char*)d_ws + off); off = align(off + (size_t)EN * 4);
    bf16*  wtbuf   = (bf16*) ((char*)d_ws + off); off = align(off + (size_t)wtelems * 2);
    fp8*   xq      = (fp8*)  ((char*)d_ws + off); off = align(off + (size_t)n * 128);
    bf16*  hbuf    = (bf16*) ((char*)d_ws + off); off = align(off + (size_t)n * 512 * 2);
    bf16*  abuf    = (bf16*) ((char*)d_ws + off); off = align(off + (size_t)n * 512 * 2);
    fp8*   f8buf   = (fp8*)  ((char*)d_ws + off); off = align(off + (size_t)n * 256);
    const int KCH = (20000 + 255) / 256;    // 79
    float* partial = (float*)((char*)d_ws + off); off = align(off + (size_t)KCH * 16384 * 4);

    // fused prep: zero fill + x->fp8 + W->Wt (one launch, independent of edges)
    {
        int xcnt = n * 128;
        int items = total + xcnt + wtelems;
        prep_kernel<<<(items + 255) / 256, 256, 0, stream>>>(fill, total, x, xq, xcnt,
            W[0], W[1], W[2], W[3], W[4], wtbuf, wtelems);
    }

    // CSR build (1 atomic/edge, packed edge records)
    passA_kernel<<<(EN + 255) / 256, 256, 0, stream>>>(ei, fill, locb, E, n, rsize);
    scan1_kernel<<<nscan, 256, 0, stream>>>(fill, blksum, total);
    scan2_kernel<<<1, 256, 0, stream>>>(blksum, row_ptr, nscan, total);
    scan3_kernel<<<nscan, 256, 0, stream>>>(fill, blksum, row_ptr, total);
    passB_kernel<<<(EN + 255) / 256, 256, 0, stream>>>(ei, ea, row_ptr, locb,
                                                       e8, csr_col, E, n, rsize);
    degdinv_kernel<<<(n + 255) / 256, 256, 0, stream>>>(row_ptr, e8, dinv, n);
    normw_kernel<<<(EN + 255) / 256, 256, 0, stream>>>(dinv, csr_col, e8, EN);

    int ablocks = (n + 3) / 4;
    auto gemm_bf16 = [&](const bf16* A, int l, bf16* C, int mode) {
        int K = dims[l], N = dims[l + 1];
        dim3 gg((n + 63) / 64, N / 128);
        int bi = (l < 4) ? l : 0;
        mfma_gemm_kernel<bf16><<<gg, 256, 0, stream>>>(A, wtbuf + wtoff[l], C, n, K, N, mode,
                                                       bvec[l], g[bi], be[bi], mm[bi], vv[bi]);
    };
    auto gemm_fp8 = [&](const bf16* A, int l, fp8* C, int mode) {
        int K = dims[l], N = dims[l + 1];
        dim3 gg((n + 63) / 64, N / 128);
        int bi = (l < 4) ? l : 0;
        mfma_gemm_kernel<fp8><<<gg, 256, 0, stream>>>(A, wtbuf + wtoff[l], C, n, K, N, mode,
                                                      bvec[l], g[bi], be[bi], mm[bi], vv[bi]);
    };

    // L1 (128->256): agg-first fp8 128 (xq), GEMM1 fused act -> fp8 h1
    agg_fp8_kernel<2><<<ablocks, 256, 0, stream>>>(xq, row_ptr, e8,
        bvec[0], bvec[0], bvec[0], bvec[0], bvec[0], abuf, n, 0);
    gemm_fp8(abuf, 0, f8buf, 1);
    // L2 (256->512): agg-first fp8 256 (h1) -> bf16, GEMM2 fused act -> bf16 h2 (512)
    agg_fp8_kernel<4><<<ablocks, 256, 0, stream>>>(f8buf, row_ptr, e8,
        bvec[1], bvec[1], bvec[1], bvec[1], bvec[1], abuf, n, 0);
    gemm_bf16(abuf, 1, hbuf, 1);
    // L3 (512->256): GEMM3 raw -> fp8 hw3, agg-last fp8 256 + bias+BN+sigmoid -> bf16 h3
    gemm_fp8(hbuf, 2, f8buf, 0);
    agg_fp8_kernel<4><<<ablocks, 256, 0, stream>>>(f8buf, row_ptr, e8,
        bvec[2], g[2], be[2], mm[2], vv[2], abuf, n, 1);
    // L4 (256->128): GEMM4 raw -> fp8 hw4, agg-last fp8 128 + bias+BN+sigmoid -> bf16 h4
    gemm_fp8(abuf, 3, f8buf, 0);
    agg_fp8_kernel<2><<<ablocks, 256, 0, stream>>>(f8buf, row_ptr, e8,
        bvec[3], g[3], be[3], mm[3], vv[3], hbuf, n, 1);
    // L5 (128->128): GEMM5 raw -> fp8 hw5, agg-last fp8 128 + bias+sigmoid -> bf16 h5
    gemm_fp8(hbuf, 4, f8buf, 0);
    agg_fp8_kernel<2><<<ablocks, 256, 0, stream>>>(f8buf, row_ptr, e8,
        bvec[4], bvec[4], bvec[4], bvec[4], bvec[4], abuf, n, 2);

    // final h^T h with zeroed diagonal (MFMA)
    htht_mfma_kernel<<<KCH, 256, 0, stream>>>(abuf, partial, n);
    reduce_kernel<<<16384 / 256, 256, 0, stream>>>(partial, (float*)d_out, KCH);
}